// Round 1
// 436.409 us; speedup vs baseline: 1.0359x; 1.0359x over previous
//
#include <hip/hip_runtime.h>
#include <hip/hip_bf16.h>

#define L_SEQ 4096
#define HID 1024
#define NH 4
#define DH 256
#define CK 64
#define BL_TOT 8192   // B*L

typedef short v8s __attribute__((ext_vector_type(8)));
typedef unsigned short v8u __attribute__((ext_vector_type(8)));
typedef float v4f __attribute__((ext_vector_type(4)));

__device__ __forceinline__ void storev(float* p, float v) { *p = v; }
__device__ __forceinline__ void storev(__hip_bfloat16* p, float v) { *p = __float2bfloat16(v); }

__device__ __forceinline__ unsigned short f2bu(float f) {
    __hip_bfloat16 h = __float2bfloat16(f);
    return *(unsigned short*)&h;
}
__device__ __forceinline__ float bu2f(unsigned short u) {
    __hip_bfloat16 h = *(__hip_bfloat16*)&u;
    return __bfloat162float(h);
}

// ---------------- all-weights f32 -> bf16 in one dispatch ----------------
__global__ __launch_bounds__(256) void wcvt_kernel(const float* __restrict__ s0, const float* __restrict__ s1,
                                                   const float* __restrict__ s2, const float* __restrict__ s3,
                                                   unsigned short* __restrict__ d0, unsigned short* __restrict__ d1,
                                                   unsigned short* __restrict__ d2, unsigned short* __restrict__ d3) {
    const float* s = blockIdx.y == 0 ? s0 : blockIdx.y == 1 ? s1 : blockIdx.y == 2 ? s2 : s3;
    unsigned short* d = blockIdx.y == 0 ? d0 : blockIdx.y == 1 ? d1 : blockIdx.y == 2 ? d2 : d3;
    int i = blockIdx.x * 256 + threadIdx.x;
    int stride = gridDim.x * 256;
    for (; i < HID * HID; i += stride) d[i] = f2bu(s[i]);
}

// ---------------- MFMA bf16 GEMM: C[M,N] = A[M,K] * B[N,K]^T  (f32 out) ----------------
__global__ __launch_bounds__(256) void gemm_mfma(const unsigned short* __restrict__ Ah,
                                                 const unsigned short* __restrict__ Bh,
                                                 float* __restrict__ C, int M, int N, int K) {
    __shared__ unsigned short AsH[128 * 40];
    __shared__ unsigned short BsH[128 * 40];
    const int tid = threadIdx.x;
    const int wave = tid >> 6, lane = tid & 63;
    const int quad = lane >> 4, l16 = lane & 15;
    const int m0 = blockIdx.x * 128, n0 = blockIdx.y * 128;
    const int wm = (wave >> 1) * 64, wn = (wave & 1) * 64;
    const int r0 = tid >> 2;
    const int kk = (tid & 3) * 8;

    v4f acc[4][4];
#pragma unroll
    for (int a = 0; a < 4; ++a)
#pragma unroll
        for (int b = 0; b < 4; ++b) { v4f z = {0.f, 0.f, 0.f, 0.f}; acc[a][b] = z; }

    for (int k0 = 0; k0 < K; k0 += 32) {
        v8u ah0 = *(const v8u*)(Ah + (size_t)(m0 + r0) * K + k0 + kk);
        v8u ah1 = *(const v8u*)(Ah + (size_t)(m0 + r0 + 64) * K + k0 + kk);
        v8u bh0 = *(const v8u*)(Bh + (size_t)(n0 + r0) * K + k0 + kk);
        v8u bh1 = *(const v8u*)(Bh + (size_t)(n0 + r0 + 64) * K + k0 + kk);
        __syncthreads();
        *(v8u*)&AsH[r0 * 40 + kk] = ah0;
        *(v8u*)&AsH[(r0 + 64) * 40 + kk] = ah1;
        *(v8u*)&BsH[r0 * 40 + kk] = bh0;
        *(v8u*)&BsH[(r0 + 64) * 40 + kk] = bh1;
        __syncthreads();
        v8s afh[4], bfh[4];
#pragma unroll
        for (int mt = 0; mt < 4; ++mt) afh[mt] = *(const v8s*)&AsH[(wm + mt * 16 + l16) * 40 + quad * 8];
#pragma unroll
        for (int nt = 0; nt < 4; ++nt) bfh[nt] = *(const v8s*)&BsH[(wn + nt * 16 + l16) * 40 + quad * 8];
#pragma unroll
        for (int mt = 0; mt < 4; ++mt)
#pragma unroll
            for (int nt = 0; nt < 4; ++nt)
                acc[mt][nt] = __builtin_amdgcn_mfma_f32_16x16x32_bf16(afh[mt], bfh[nt], acc[mt][nt], 0, 0, 0);
    }
#pragma unroll
    for (int mt = 0; mt < 4; ++mt)
#pragma unroll
        for (int nt = 0; nt < 4; ++nt) {
            int row = m0 + wm + mt * 16 + quad * 4;
            int col = n0 + wn + nt * 16 + l16;
#pragma unroll
            for (int r = 0; r < 4; ++r)
                C[(size_t)(row + r) * N + col] = acc[mt][nt][r];
        }
}

// ---------------- beta = sigmoid(x @ Wbeta^T); fused x -> bf16 ----------------
__global__ __launch_bounds__(256) void beta_kernel(const float* __restrict__ x,
                                                   const float* __restrict__ Wb,
                                                   float* __restrict__ betaB,
                                                   unsigned short* __restrict__ xh) {
    const int t = blockIdx.x;
    const int tid = threadIdx.x;
    const int wave = tid >> 6, lane = tid & 63;
    const float* xr = x + (size_t)t * HID;
    float s[4] = {0.f, 0.f, 0.f, 0.f};
    for (int i = tid; i < HID; i += 256) {
        float xv = xr[i];
        xh[(size_t)t * HID + i] = f2bu(xv);
        s[0] += xv * Wb[i];
        s[1] += xv * Wb[HID + i];
        s[2] += xv * Wb[2 * HID + i];
        s[3] += xv * Wb[3 * HID + i];
    }
#pragma unroll
    for (int off = 32; off; off >>= 1)
#pragma unroll
        for (int h = 0; h < 4; ++h) s[h] += __shfl_down(s[h], off);
    __shared__ float red[4][4];
    if (lane == 0)
#pragma unroll
        for (int h = 0; h < 4; ++h) red[wave][h] = s[h];
    __syncthreads();
    if (tid < 4) {
        float tot = red[0][tid] + red[1][tid] + red[2][tid] + red[3][tid];
        betaB[(size_t)t * 4 + tid] = 1.f / (1.f + expf(-tot));
    }
}

// ---------------- causal depthwise conv (KS=4) + silu + silu (+ per-head l2norm) ----------------
template <typename OUT>
__global__ __launch_bounds__(256) void conv_kernel(const float* __restrict__ G,
                                                   const float* __restrict__ w,  // [HID][KS]
                                                   OUT* __restrict__ out, int do_norm,
                                                   unsigned short* __restrict__ hi,
                                                   unsigned short* __restrict__ lo) {
    const int bl = blockIdx.x;
    const int l = bl & (L_SEQ - 1);
    const int tid = threadIdx.x;
    const int wave = tid >> 6, lane = tid & 63;
    float vals[4];
#pragma unroll
    for (int h = 0; h < 4; ++h) {
        const int c = tid + 256 * h;
        float acc = 0.f;
#pragma unroll
        for (int j = 0; j < 4; ++j) {
            int ls = l - 3 + j;
            float xv = 0.f;
            if (ls >= 0) xv = G[(size_t)(bl - 3 + j) * HID + c];
            acc += xv * w[c * 4 + j];
        }
        float s1 = acc / (1.f + expf(-acc));
        float s2 = s1 / (1.f + expf(-s1));
        vals[h] = s2;
    }
    if (do_norm) {
        float sq[4];
#pragma unroll
        for (int h = 0; h < 4; ++h) sq[h] = vals[h] * vals[h];
#pragma unroll
        for (int off = 32; off; off >>= 1)
#pragma unroll
            for (int h = 0; h < 4; ++h) sq[h] += __shfl_down(sq[h], off);
        __shared__ float red[4][4];
        __shared__ float nrm[4];
        if (lane == 0)
#pragma unroll
            for (int h = 0; h < 4; ++h) red[wave][h] = sq[h];
        __syncthreads();
        if (tid < 4) {
            float tot = red[0][tid] + red[1][tid] + red[2][tid] + red[3][tid];
            nrm[tid] = 1.f / fmaxf(sqrtf(tot), 1e-12f);
        }
        __syncthreads();
#pragma unroll
        for (int h = 0; h < 4; ++h) vals[h] *= nrm[h];
    }
#pragma unroll
    for (int h = 0; h < 4; ++h) {
        const int c = tid + 256 * h;
        if (out) storev(&out[(size_t)bl * HID + c], vals[h]);
        if (hi) {
            unsigned short hv = f2bu(vals[h]);
            hi[(size_t)bl * HID + c] = hv;
            lo[(size_t)bl * HID + c] = f2bu(vals[h] - bu2f(hv));
        }
    }
}

// ---------------- per-chunk per-head gram: G_h = K_h * K_h^T (split-bf16 MFMA) ----------------
__global__ __launch_bounds__(256) void gram_kernel(const unsigned short* __restrict__ Khi,
                                                   const unsigned short* __restrict__ Klo,
                                                   float* __restrict__ Gg) {
    const int chunk = blockIdx.x;
    const int h = blockIdx.y;
    const int tid = threadIdx.x;
    const int wave = tid >> 6, lane = tid & 63;
    const int quad = lane >> 4, l16 = lane & 15;
    __shared__ unsigned short Hs[64 * 264];
    __shared__ unsigned short Ls[64 * 264];
    const int l0 = chunk * 64;
    const int cb = h * 256;
#pragma unroll
    for (int p = 0; p < 8; ++p) {
        int row = p * 8 + (tid >> 5);
        int col = (tid & 31) * 8;
        v8u hv = *(const v8u*)(Khi + (size_t)(l0 + row) * HID + cb + col);
        v8u lv = *(const v8u*)(Klo + (size_t)(l0 + row) * HID + cb + col);
        *(v8u*)&Hs[row * 264 + col] = hv;
        *(v8u*)&Ls[row * 264 + col] = lv;
    }
    __syncthreads();
    const int wm = wave * 16;
    v4f acc[4];
#pragma unroll
    for (int nt = 0; nt < 4; ++nt) { v4f z = {0.f, 0.f, 0.f, 0.f}; acc[nt] = z; }
#pragma unroll
    for (int ks = 0; ks < 8; ++ks) {
        v8s ah = *(const v8s*)&Hs[(wm + l16) * 264 + ks * 32 + quad * 8];
        v8s al = *(const v8s*)&Ls[(wm + l16) * 264 + ks * 32 + quad * 8];
#pragma unroll
        for (int nt = 0; nt < 4; ++nt) {
            v8s bh = *(const v8s*)&Hs[(nt * 16 + l16) * 264 + ks * 32 + quad * 8];
            v8s bl = *(const v8s*)&Ls[(nt * 16 + l16) * 264 + ks * 32 + quad * 8];
            acc[nt] = __builtin_amdgcn_mfma_f32_16x16x32_bf16(ah, bh, acc[nt], 0, 0, 0);
            acc[nt] = __builtin_amdgcn_mfma_f32_16x16x32_bf16(ah, bl, acc[nt], 0, 0, 0);
            acc[nt] = __builtin_amdgcn_mfma_f32_16x16x32_bf16(al, bh, acc[nt], 0, 0, 0);
        }
    }
    float* og = Gg + ((size_t)chunk * 4 + h) * 4096;
#pragma unroll
    for (int nt = 0; nt < 4; ++nt)
#pragma unroll
        for (int r = 0; r < 4; ++r)
            og[(wm + quad * 4 + r) * 64 + nt * 16 + l16] = acc[nt][r];
}

// ---------------- T recurrence per chunk via nilpotent doubling + MFMA ----------------
// Reference recurrence == T_final = 3*(I-A)^{-1} - 2I, A = -tril(beta*gram, -1).
// (I-A)^{-1} = prod_{k=0..5} (I + A^(2^k)) since A^64 = 0.
// 6 stages, each from OLD state: accP = P*B (seeded with P), accB = B*B; split-bf16 MFMA.
__global__ __launch_bounds__(256) void trec_kernel(const float* __restrict__ Gg,
                                                   const float* __restrict__ betaB,
                                                   float* __restrict__ Tg) {
    const int chunk = blockIdx.x;
    const int tid = threadIdx.x;
    const int wave = tid >> 6, lane = tid & 63;
    const int quad = lane >> 4, l16 = lane & 15;
    const int wm = wave * 16;
    __shared__ unsigned short BhR[64 * 72], BlR[64 * 72];  // B rows   [i][j]
    __shared__ unsigned short BhT[64 * 72], BlT[64 * 72];  // B^T rows [j][i]
    __shared__ unsigned short PhR[64 * 72], PlR[64 * 72];  // P rows   [i][j]
    __shared__ float Pf[64 * 73];                          // P master copy (f32)
    __shared__ float betS[256];
    betS[tid] = betaB[(size_t)chunk * 256 + tid];
    __syncthreads();
    const float* gg = Gg + (size_t)chunk * 4 * 4096;
    // setup: B = A (strictly lower), P = I
#pragma unroll
    for (int s = 0; s < 16; ++s) {
        int idx = tid + 256 * s;
        int i = idx >> 6, j = idx & 63;
        float a = 0.f;
        if (i > j) {
            a = -(betS[i * 4 + 0] * gg[idx] + betS[i * 4 + 1] * gg[4096 + idx] +
                  betS[i * 4 + 2] * gg[2 * 4096 + idx] + betS[i * 4 + 3] * gg[3 * 4096 + idx]);
        }
        unsigned short ah = f2bu(a);
        unsigned short al = f2bu(a - bu2f(ah));
        BhR[i * 72 + j] = ah;
        BlR[i * 72 + j] = al;
        BhT[j * 72 + i] = ah;
        BlT[j * 72 + i] = al;
        float p = (i == j) ? 1.f : 0.f;
        Pf[i * 73 + j] = p;
        PhR[i * 72 + j] = f2bu(p);
        PlR[i * 72 + j] = 0;
    }
    __syncthreads();

    for (int st = 0; st < 6; ++st) {
        // load all fragments from OLD state (each wave owns rows [wm, wm+16))
        v8s aBh[2], aBl[2], aPh[2], aPl[2];
        v8s bTh[2][4], bTl[2][4];
#pragma unroll
        for (int kk = 0; kk < 2; ++kk) {
            aBh[kk] = *(const v8s*)&BhR[(wm + l16) * 72 + kk * 32 + quad * 8];
            aBl[kk] = *(const v8s*)&BlR[(wm + l16) * 72 + kk * 32 + quad * 8];
            aPh[kk] = *(const v8s*)&PhR[(wm + l16) * 72 + kk * 32 + quad * 8];
            aPl[kk] = *(const v8s*)&PlR[(wm + l16) * 72 + kk * 32 + quad * 8];
#pragma unroll
            for (int nt = 0; nt < 4; ++nt) {
                bTh[kk][nt] = *(const v8s*)&BhT[(nt * 16 + l16) * 72 + kk * 32 + quad * 8];
                bTl[kk][nt] = *(const v8s*)&BlT[(nt * 16 + l16) * 72 + kk * 32 + quad * 8];
            }
        }
        v4f accP[4], accB[4];
#pragma unroll
        for (int nt = 0; nt < 4; ++nt) {
#pragma unroll
            for (int r = 0; r < 4; ++r)
                accP[nt][r] = Pf[(wm + quad * 4 + r) * 73 + nt * 16 + l16];
            v4f z = {0.f, 0.f, 0.f, 0.f};
            accB[nt] = z;
        }
        __syncthreads();  // all reads done before anyone writes
        // P' = P + P*B (split-bf16: hi*hi + hi*lo + lo*hi)
#pragma unroll
        for (int kk = 0; kk < 2; ++kk)
#pragma unroll
            for (int nt = 0; nt < 4; ++nt) {
                accP[nt] = __builtin_amdgcn_mfma_f32_16x16x32_bf16(aPh[kk], bTh[kk][nt], accP[nt], 0, 0, 0);
                accP[nt] = __builtin_amdgcn_mfma_f32_16x16x32_bf16(aPh[kk], bTl[kk][nt], accP[nt], 0, 0, 0);
                accP[nt] = __builtin_amdgcn_mfma_f32_16x16x32_bf16(aPl[kk], bTh[kk][nt], accP[nt], 0, 0, 0);
            }
        if (st < 5) {
            // B' = B*B (last stage would be A^64 = 0 -> skip)
#pragma unroll
            for (int kk = 0; kk < 2; ++kk)
#pragma unroll
                for (int nt = 0; nt < 4; ++nt) {
                    accB[nt] = __builtin_amdgcn_mfma_f32_16x16x32_bf16(aBh[kk], bTh[kk][nt], accB[nt], 0, 0, 0);
                    accB[nt] = __builtin_amdgcn_mfma_f32_16x16x32_bf16(aBh[kk], bTl[kk][nt], accB[nt], 0, 0, 0);
                    accB[nt] = __builtin_amdgcn_mfma_f32_16x16x32_bf16(aBl[kk], bTh[kk][nt], accB[nt], 0, 0, 0);
                }
        }
        // write back new state
#pragma unroll
        for (int nt = 0; nt < 4; ++nt)
#pragma unroll
            for (int r = 0; r < 4; ++r) {
                int row = wm + quad * 4 + r;
                int col = nt * 16 + l16;
                float pv = accP[nt][r];
                Pf[row * 73 + col] = pv;
                unsigned short ph = f2bu(pv);
                PhR[row * 72 + col] = ph;
                PlR[row * 72 + col] = f2bu(pv - bu2f(ph));
                if (st < 5) {
                    float bv = accB[nt][r];
                    unsigned short bh2 = f2bu(bv);
                    unsigned short bl2 = f2bu(bv - bu2f(bh2));
                    BhR[row * 72 + col] = bh2;
                    BlR[row * 72 + col] = bl2;
                    BhT[col * 72 + row] = bh2;
                    BlT[col * 72 + row] = bl2;
                }
            }
        __syncthreads();
    }
    // T = 3P - 2I
#pragma unroll
    for (int s = 0; s < 16; ++s) {
        int idx = tid + 256 * s;
        int i = idx >> 6, j = idx & 63;
        float t = (i == j) ? 1.f : 3.f * Pf[i * 73 + j];
        Tg[(size_t)chunk * 4096 + idx] = t;
    }
}

// ---------------- W = T'·K, U = T'·V via MFMA (T' = T·diag(beta)); fused kw/ku ----------------
__global__ __launch_bounds__(256) void wu_mfma_kernel(const float* __restrict__ Tg,
                                                      const unsigned short* __restrict__ Khi,
                                                      const unsigned short* __restrict__ Vhi,
                                                      const float* __restrict__ betaB,
                                                      unsigned short* __restrict__ Wb,
                                                      unsigned short* __restrict__ Ub,
                                                      float* __restrict__ kw, float* __restrict__ ku) {
    const int chunk = blockIdx.x;  // 128
    const int h = blockIdx.y;      // 4
    const int half = blockIdx.z;   // 2
    const int tid = threadIdx.x;
    const int wave = tid >> 6, lane = tid & 63;
    const int quad = lane >> 4, l16 = lane & 15;
    const size_t l0 = (size_t)chunk * 64;
    const int f0 = h * 256 + half * 128;
    __shared__ unsigned short Th[64 * 72], Tl[64 * 72];
    __shared__ unsigned short KT[128 * 72], VT[128 * 72];
    __shared__ float betS[64];
    if (tid < 64) betS[tid] = betaB[(l0 + tid) * 4 + h];
    __syncthreads();
#pragma unroll
    for (int s = 0; s < 16; ++s) {
        int idx = tid + 256 * s;
        int c = idx >> 6, j = idx & 63;
        float v = Tg[(size_t)chunk * 4096 + idx] * betS[j];
        unsigned short hv = f2bu(v);
        Th[c * 72 + j] = hv;
        Tl[c * 72 + j] = f2bu(v - bu2f(hv));
    }
#pragma unroll
    for (int pass = 0; pass < 4; ++pass) {
        int j = pass * 16 + (tid >> 4);
        int fc = (tid & 15) * 8;
        v8u kv = *(const v8u*)(Khi + (l0 + j) * HID + f0 + fc);
        v8u vv = *(const v8u*)(Vhi + (l0 + j) * HID + f0 + fc);
#pragma unroll
        for (int i = 0; i < 8; ++i) {
            KT[(fc + i) * 72 + j] = kv[i];
            VT[(fc + i) * 72 + j] = vv[i];
        }
    }
    __syncthreads();

    const int nf = wave * 32;
    const int bb = chunk >> 6, nn = chunk & 63;
    const size_t obase = (((size_t)bb * 4 + h) * 64 + nn) * 256 + half * 128;

#pragma unroll
    for (int phase = 0; phase < 2; ++phase) {
        const unsigned short* BT = phase ? VT : KT;
        v4f acc[4][2];
#pragma unroll
        for (int mt = 0; mt < 4; ++mt)
#pragma unroll
            for (int nt = 0; nt < 2; ++nt) { v4f z = {0.f, 0.f, 0.f, 0.f}; acc[mt][nt] = z; }
#pragma unroll
        for (int k0 = 0; k0 < 64; k0 += 32) {
            v8s ah[4], al[4], bf[2];
#pragma unroll
            for (int mt = 0; mt < 4; ++mt) {
                ah[mt] = *(const v8s*)&Th[(mt * 16 + l16) * 72 + k0 + quad * 8];
                al[mt] = *(const v8s*)&Tl[(mt * 16 + l16) * 72 + k0 + quad * 8];
            }
#pragma unroll
            for (int nt = 0; nt < 2; ++nt)
                bf[nt] = *(const v8s*)&BT[(nf + nt * 16 + l16) * 72 + k0 + quad * 8];
#pragma unroll
            for (int mt = 0; mt < 4; ++mt)
#pragma unroll
                for (int nt = 0; nt < 2; ++nt) {
                    acc[mt][nt] = __builtin_amdgcn_mfma_f32_16x16x32_bf16(ah[mt], bf[nt], acc[mt][nt], 0, 0, 0);
                    acc[mt][nt] = __builtin_amdgcn_mfma_f32_16x16x32_bf16(al[mt], bf[nt], acc[mt][nt], 0, 0, 0);
                }
        }
        unsigned short* Out = phase ? Ub : Wb;
        float* kk = phase ? ku : kw;
#pragma unroll
        for (int nt = 0; nt < 2; ++nt) {
            const int fl = nf + nt * 16 + l16;
            float dot = 0.f;
#pragma unroll
            for (int mt = 0; mt < 4; ++mt)
#pragma unroll
                for (int r = 0; r < 4; ++r) {
                    const int c = mt * 16 + quad * 4 + r;
                    float wv = acc[mt][nt][r];
                    Out[(l0 + c) * HID + f0 + fl] = f2bu(wv);
                    dot += bu2f(KT[fl * 72 + c]) * wv;
                }
            dot += __shfl_xor(dot, 16);
            dot += __shfl_xor(dot, 32);
            if (quad == 0) kk[obase + fl] = dot;
        }
    }
}

// ---------------- diagonal scan over chunks ----------------
__global__ __launch_bounds__(256) void scan_kernel(const float* __restrict__ kw,
                                                   const float* __restrict__ ku,
                                                   float* __restrict__ dsA) {
    const int bh = blockIdx.x;
    const int e = threadIdx.x;
    float ds = 0.f;
    for (int n = 0; n < 64; ++n) {
        size_t idx = ((size_t)bh * 64 + n) * 256 + e;
        dsA[idx] = ds;
        ds = ds * (1.f - kw[idx]) + ku[idx];
    }
}

__device__ __forceinline__ float block_sum(float v, float* red) {
#pragma unroll
    for (int off = 32; off; off >>= 1) v += __shfl_down(v, off);
    const int wave = threadIdx.x >> 6;
    if ((threadIdx.x & 63) == 0) red[wave] = v;
    __syncthreads();
    float t = red[0] + red[1] + red[2] + red[3];
    __syncthreads();
    return t;
}

// ---------------- o = q*ds + [c<=b]*A*(u - w*ds); fused RMSNorm + bf16 cast ----------------
__global__ __launch_bounds__(256) void o_kernel(const __hip_bfloat16* __restrict__ Qb,
                                                const unsigned short* __restrict__ Khi,
                                                const unsigned short* __restrict__ Wb,
                                                const unsigned short* __restrict__ Ub,
                                                const float* __restrict__ dsA,
                                                const float* __restrict__ rmsw,
                                                __hip_bfloat16* __restrict__ ob,
                                                unsigned short* __restrict__ ub) {
    const int bl = blockIdx.x;
    const int b = bl >> 12, l = bl & (L_SEQ - 1);
    const int n = l >> 6, cpos = l & 63;
    const int tid = threadIdx.x;
    __shared__ float red[4];
    const size_t rowb = (size_t)bl * HID;
    float dsv[4], qv[4], ov[4];
#pragma unroll
    for (int h = 0; h < 4; ++h) {
        dsv[h] = dsA[(((size_t)b * 4 + h) * 64 + n) * 256 + tid];
        qv[h] = __bfloat162float(Qb[rowb + tid + 256 * h]);
    }
    const bool doA = (cpos <= b);
    float Aval = 0.f;
    if (doA) {
        float s = 0.f;
#pragma unroll
        for (int h = 0; h < 4; ++h) s += qv[h] * bu2f(Khi[rowb + tid + 256 * h]);
        Aval = block_sum(s, red);
    }
    float ss = 0.f;
#pragma unroll
    for (int h = 0; h < 4; ++h) {
        int c = tid + 256 * h;
        float u = bu2f(Ub[rowb + c]) - bu2f(Wb[rowb + c]) * dsv[h];
        ub[rowb + c] = f2bu(u);
        float o = qv[h] * dsv[h];
        if (doA) o += Aval * u;
        ov[h] = o;
        ss += o * o;
    }
    float tot = block_sum(ss, red);
    float scale = rsqrtf(tot * (1.f / 1024.f) + 1e-5f);
#pragma unroll
    for (int h = 0; h < 4; ++h) {
        int c = tid + 256 * h;
        ob[rowb + c] = __float2bfloat16(ov[h] * scale * rmsw[c]);
    }
}

// ---------------- state S = K^T u'  via MFMA (n-split partials) ----------------
#define SNS 16
__global__ __launch_bounds__(256) void s_mfma_kernel(const unsigned short* __restrict__ Khi,
                                                     const unsigned short* __restrict__ Ub,
                                                     float* __restrict__ Spart) {
    const int bh = blockIdx.x;
    const int b = bh >> 2, h = bh & 3;
    const int dt = blockIdx.y;
    const int et = blockIdx.z & 1;
    const int ns = blockIdx.z >> 1;
    const int tid = threadIdx.x;
    const int wave = tid >> 6, lane = tid & 63;
    const int quad = lane >> 4, l16 = lane & 15;
    const int wm = (wave >> 1) * 64, wn = (wave & 1) * 64;
    __shared__ unsigned short Kt[128 * 40];
    __shared__ unsigned short Ut[128 * 40];
    const int cc = tid >> 3;
    const int dcol = (tid & 7) * 16;
    const size_t rowbase = (size_t)b * 4096 + (size_t)ns * 256;
    const int ck = h * 256 + dt * 128;
    const int ce = h * 256 + et * 128;
    v4f acc[4][4];
#pragma unroll
    for (int a = 0; a < 4; ++a)
#pragma unroll
        for (int c2 = 0; c2 < 4; ++c2) { v4f z = {0.f, 0.f, 0.f, 0.f}; acc[a][c2] = z; }

    for (int kt = 0; kt < 8; ++kt) {
        size_t row = rowbase + kt * 32 + cc;
        v8u k0 = *(const v8u*)(Khi + row * HID + ck + dcol);
        v8u k1 = *(const v8u*)(Khi + row * HID + ck + dcol + 8);
        v8u u0 = *(const v8u*)(Ub + row * HID + ce + dcol);
        v8u u1 = *(const v8u*)(Ub + row * HID + ce + dcol + 8);
        __syncthreads();
#pragma unroll
        for (int j = 0; j < 8; ++j) {
            Kt[(dcol + j) * 40 + cc] = k0[j];
            Kt[(dcol + 8 + j) * 40 + cc] = k1[j];
            Ut[(dcol + j) * 40 + cc] = u0[j];
            Ut[(dcol + 8 + j) * 40 + cc] = u1[j];
        }
        __syncthreads();
        v8s af[4], bf[4];
#pragma unroll
        for (int mt = 0; mt < 4; ++mt) af[mt] = *(const v8s*)&Kt[(wm + mt * 16 + l16) * 40 + quad * 8];
#pragma unroll
        for (int nt = 0; nt < 4; ++nt) bf[nt] = *(const v8s*)&Ut[(wn + nt * 16 + l16) * 40 + quad * 8];
#pragma unroll
        for (int mt = 0; mt < 4; ++mt)
#pragma unroll
            for (int nt = 0; nt < 4; ++nt)
                acc[mt][nt] = __builtin_amdgcn_mfma_f32_16x16x32_bf16(af[mt], bf[nt], acc[mt][nt], 0, 0, 0);
    }
    float* out = Spart + (size_t)ns * (8 * 256 * 256);
#pragma unroll
    for (int mt = 0; mt < 4; ++mt)
#pragma unroll
        for (int nt = 0; nt < 4; ++nt) {
            int row = dt * 128 + wm + mt * 16 + quad * 4;
            int col = et * 128 + wn + nt * 16 + l16;
#pragma unroll
            for (int r = 0; r < 4; ++r)
                out[((size_t)bh * 256 + row + r) * 256 + col] = acc[mt][nt][r];
        }
}

// ---------------- reduce SNS partials -> out1 ----------------
__global__ __launch_bounds__(256) void sreduce_kernel(const float* __restrict__ Spart,
                                                      float* __restrict__ out) {
    int i = blockIdx.x * 256 + threadIdx.x;
    float s = 0.f;
#pragma unroll
    for (int ns = 0; ns < SNS; ++ns) s += Spart[(size_t)ns * (8 * 256 * 256) + i];
    out[i] = s;
}

extern "C" void kernel_launch(void* const* d_in, const int* in_sizes, int n_in,
                              void* d_out, int out_size, void* d_ws, size_t ws_size,
                              hipStream_t stream) {
    const float* x     = (const float*)d_in[0];
    const float* Wq    = (const float*)d_in[1];
    const float* Wk    = (const float*)d_in[2];
    const float* Wv    = (const float*)d_in[3];
    const float* convq = (const float*)d_in[4];
    const float* convk = (const float*)d_in[5];
    const float* convv = (const float*)d_in[6];
    const float* Wbeta = (const float*)d_in[7];
    const float* rmsw  = (const float*)d_in[8];
    const float* Wo    = (const float*)d_in[9];

    // ---- workspace map (~130 MiB; aliases documented) ----
    char* ws = (char*)d_ws;
    size_t off = 0;
    auto alloc = [&](size_t bytes) {
        char* p = ws + off;
        off += (bytes + 255) & ~(size_t)255;
        return (void*)p;
    };
    unsigned short* xhi  = (unsigned short*)alloc((size_t)BL_TOT * HID * 2);  // later Qm/ob
    unsigned short* Khi  = (unsigned short*)alloc((size_t)BL_TOT * HID * 2);  // conv_k -> s_mfma
    unsigned short* wbV  = (unsigned short*)alloc((size_t)HID * HID * 2);
    unsigned short* wbK  = (unsigned short*)alloc((size_t)HID * HID * 2);
    unsigned short* wbQ  = (unsigned short*)alloc((size_t)HID * HID * 2);
    unsigned short* wbO  = (unsigned short*)alloc((size_t)HID * HID * 2);
    float*          Gt   = (float*)alloc((size_t)BL_TOT * HID * 4);  // gemm out; later Spart
    unsigned short* Vhi  = (unsigned short*)alloc((size_t)BL_TOT * HID * 2);
    unsigned short* Wb16 = (unsigned short*)alloc((size_t)BL_TOT * HID * 2);
    unsigned short* Ub16 = (unsigned short*)alloc((size_t)BL_TOT * HID * 2);
    float* Tg    = (float*)alloc((size_t)128 * 4096 * 4);
    float* betaB = (float*)alloc((size_t)BL_TOT * 4 * 4);
    float* kwB   = (float*)alloc((size_t)8 * 64 * 256 * 4);
    float* kuB   = (float*)alloc((size_t)8 * 64 * 256 * 4);
    float* dsA   = (float*)alloc((size_t)8 * 64 * 256 * 4);
    __hip_bfloat16* Qm = (__hip_bfloat16*)xhi;  // xhi dead after Q GEMM (last x-GEMM)
    __hip_bfloat16* ob = Qm;                    // q dead after o_kernel reads its own row
    float* Spart = Gt;                          // Gt dead after conv_q

    float* out0 = (float*)d_out;
    float* out1 = out0 + (size_t)BL_TOT * HID;
    // d_out as pre-final scratch (validated only after launch):
    unsigned short* Klo = (unsigned short*)out0;            // bytes 0..16.78M
    unsigned short* ubf = (unsigned short*)out0 + 8388608;  // bytes 16.78M..33.55M
    float* Gg = out0 + (size_t)4400000;                     // gram scratch; dead before o_kernel

    dim3 blk(256);
    dim3 ggrid(BL_TOT / 128, HID / 128);

    wcvt_kernel<<<dim3(256, 4), blk, 0, stream>>>(Wv, Wk, Wq, Wo, wbV, wbK, wbQ, wbO);
    beta_kernel<<<BL_TOT, blk, 0, stream>>>(x, Wbeta, betaB, xhi);

    // V path (plain bf16)
    gemm_mfma<<<ggrid, blk, 0, stream>>>(xhi, wbV, Gt, BL_TOT, HID, HID);
    conv_kernel<__hip_bfloat16><<<BL_TOT, blk, 0, stream>>>(Gt, convv, (__hip_bfloat16*)Vhi, 0, nullptr, nullptr);
    // K path (plain bf16 GEMM; conv emits bf16 hi/lo — gram stays faithful to the K actually used)
    gemm_mfma<<<ggrid, blk, 0, stream>>>(xhi, wbK, Gt, BL_TOT, HID, HID);
    conv_kernel<float><<<BL_TOT, blk, 0, stream>>>(Gt, convk, (float*)nullptr, 1, Khi, Klo);
    // gram + T recurrence
    gram_kernel<<<dim3(128, 4), blk, 0, stream>>>(Khi, Klo, Gg);
    trec_kernel<<<128, blk, 0, stream>>>(Gg, betaB, Tg);
    // Q path (plain bf16). Last x-GEMM: frees xhi.
    gemm_mfma<<<ggrid, blk, 0, stream>>>(xhi, wbQ, Gt, BL_TOT, HID, HID);
    conv_kernel<__hip_bfloat16><<<BL_TOT, blk, 0, stream>>>(Gt, convq, Qm, 1, nullptr, nullptr);

    // chunked delta rule
    wu_mfma_kernel<<<dim3(128, 4, 2), blk, 0, stream>>>(Tg, Khi, Vhi, betaB, Wb16, Ub16, kwB, kuB);
    scan_kernel<<<8, blk, 0, stream>>>(kwB, kuB, dsA);
    o_kernel<<<BL_TOT, blk, 0, stream>>>(Qm, Khi, Wb16, Ub16, dsA, rmsw, ob, ubf);
    s_mfma_kernel<<<dim3(8, 2, 2 * SNS), blk, 0, stream>>>(Khi, ubf, Spart);
    sreduce_kernel<<<2048, blk, 0, stream>>>(Spart, out1);

    // final projection: o(bf16) @ Wo^T -> f32 out0 (overwrites Klo/ubf scratch)
    gemm_mfma<<<ggrid, blk, 0, stream>>>((const unsigned short*)ob, wbO, out0, BL_TOT, HID, HID);
}

// Round 2
// 429.842 us; speedup vs baseline: 1.0517x; 1.0153x over previous
//
#include <hip/hip_runtime.h>
#include <hip/hip_bf16.h>

#define L_SEQ 4096
#define HID 1024
#define NH 4
#define DH 256
#define CK 64
#define BL_TOT 8192   // B*L

typedef short v8s __attribute__((ext_vector_type(8)));
typedef unsigned short v8u __attribute__((ext_vector_type(8)));
typedef float v4f __attribute__((ext_vector_type(4)));

typedef __attribute__((address_space(1))) const void* as1cv;
typedef __attribute__((address_space(3))) void* as3v;

__device__ __forceinline__ void storev(float* p, float v) { *p = v; }
__device__ __forceinline__ void storev(__hip_bfloat16* p, float v) { *p = __float2bfloat16(v); }

__device__ __forceinline__ unsigned short f2bu(float f) {
    __hip_bfloat16 h = __float2bfloat16(f);
    return *(unsigned short*)&h;
}
__device__ __forceinline__ float bu2f(unsigned short u) {
    __hip_bfloat16 h = *(__hip_bfloat16*)&u;
    return __bfloat162float(h);
}

// ---------------- all-weights f32 -> bf16 in one dispatch ----------------
__global__ __launch_bounds__(256) void wcvt_kernel(const float* __restrict__ s0, const float* __restrict__ s1,
                                                   const float* __restrict__ s2, const float* __restrict__ s3,
                                                   unsigned short* __restrict__ d0, unsigned short* __restrict__ d1,
                                                   unsigned short* __restrict__ d2, unsigned short* __restrict__ d3) {
    const float* s = blockIdx.y == 0 ? s0 : blockIdx.y == 1 ? s1 : blockIdx.y == 2 ? s2 : s3;
    unsigned short* d = blockIdx.y == 0 ? d0 : blockIdx.y == 1 ? d1 : blockIdx.y == 2 ? d2 : d3;
    int i = blockIdx.x * 256 + threadIdx.x;
    int stride = gridDim.x * 256;
    for (; i < HID * HID; i += stride) d[i] = f2bu(s[i]);
}

// ---------------- MFMA bf16 GEMM: C[M,N] = A[M,K] * B[N,K]^T  (f32 out) ----------------
// m97-structure: global_load_lds width=16 direct staging, linear [128][32] LDS tiles.
__global__ __launch_bounds__(256) void gemm_mfma(const unsigned short* __restrict__ Ah,
                                                 const unsigned short* __restrict__ Bh,
                                                 float* __restrict__ C, int M, int N, int K) {
    __shared__ unsigned short AsH[128 * 32];
    __shared__ unsigned short BsH[128 * 32];
    const int tid = threadIdx.x;
    const int wave = tid >> 6, lane = tid & 63;
    const int quad = lane >> 4, l16 = lane & 15;
    const int m0 = blockIdx.x * 128, n0 = blockIdx.y * 128;
    const int wm = (wave >> 1) * 64, wn = (wave & 1) * 64;

    // staging geometry: one issue = 256 thr * 16B = 4 KB = 64 rows * 64 B
    // wave w writes LDS bytes [w*1024,(w+1)*1024) = rows [w*16,(w+1)*16); HW adds lane*16
    const int srow = wave * 16 + (lane >> 2);  // 0..63
    const int scol = (lane & 3) * 8;           // shorts (16 B)
    const unsigned short* Ag = Ah + (size_t)(m0 + srow) * K + scol;
    const unsigned short* Bg = Bh + (size_t)(n0 + srow) * K + scol;
    char* lA = (char*)AsH;
    char* lB = (char*)BsH;
    const int lbase = wave * 1024;

    v4f acc[4][4];
#pragma unroll
    for (int a = 0; a < 4; ++a)
#pragma unroll
        for (int b = 0; b < 4; ++b) { v4f z = {0.f, 0.f, 0.f, 0.f}; acc[a][b] = z; }

    for (int k0 = 0; k0 < K; k0 += 32) {
        __syncthreads();  // previous tile's ds_reads complete
        __builtin_amdgcn_global_load_lds((as1cv)(Ag + k0), (as3v)(lA + lbase), 16, 0, 0);
        __builtin_amdgcn_global_load_lds((as1cv)(Ag + (size_t)64 * K + k0), (as3v)(lA + 4096 + lbase), 16, 0, 0);
        __builtin_amdgcn_global_load_lds((as1cv)(Bg + k0), (as3v)(lB + lbase), 16, 0, 0);
        __builtin_amdgcn_global_load_lds((as1cv)(Bg + (size_t)64 * K + k0), (as3v)(lB + 4096 + lbase), 16, 0, 0);
        __syncthreads();  // drains vmcnt -> LDS tile ready
        v8s afh[4], bfh[4];
#pragma unroll
        for (int mt = 0; mt < 4; ++mt) afh[mt] = *(const v8s*)&AsH[(wm + mt * 16 + l16) * 32 + quad * 8];
#pragma unroll
        for (int nt = 0; nt < 4; ++nt) bfh[nt] = *(const v8s*)&BsH[(wn + nt * 16 + l16) * 32 + quad * 8];
#pragma unroll
        for (int mt = 0; mt < 4; ++mt)
#pragma unroll
            for (int nt = 0; nt < 4; ++nt)
                acc[mt][nt] = __builtin_amdgcn_mfma_f32_16x16x32_bf16(afh[mt], bfh[nt], acc[mt][nt], 0, 0, 0);
    }
#pragma unroll
    for (int mt = 0; mt < 4; ++mt)
#pragma unroll
        for (int nt = 0; nt < 4; ++nt) {
            int row = m0 + wm + mt * 16 + quad * 4;
            int col = n0 + wn + nt * 16 + l16;
#pragma unroll
            for (int r = 0; r < 4; ++r)
                C[(size_t)(row + r) * N + col] = acc[mt][nt][r];
        }
}

// ---------------- beta = sigmoid(x @ Wbeta^T); fused x -> bf16 ----------------
__global__ __launch_bounds__(256) void beta_kernel(const float* __restrict__ x,
                                                   const float* __restrict__ Wb,
                                                   float* __restrict__ betaB,
                                                   unsigned short* __restrict__ xh) {
    const int t = blockIdx.x;
    const int tid = threadIdx.x;
    const int wave = tid >> 6, lane = tid & 63;
    const float* xr = x + (size_t)t * HID;
    float s[4] = {0.f, 0.f, 0.f, 0.f};
    for (int i = tid; i < HID; i += 256) {
        float xv = xr[i];
        xh[(size_t)t * HID + i] = f2bu(xv);
        s[0] += xv * Wb[i];
        s[1] += xv * Wb[HID + i];
        s[2] += xv * Wb[2 * HID + i];
        s[3] += xv * Wb[3 * HID + i];
    }
#pragma unroll
    for (int off = 32; off; off >>= 1)
#pragma unroll
        for (int h = 0; h < 4; ++h) s[h] += __shfl_down(s[h], off);
    __shared__ float red[4][4];
    if (lane == 0)
#pragma unroll
        for (int h = 0; h < 4; ++h) red[wave][h] = s[h];
    __syncthreads();
    if (tid < 4) {
        float tot = red[0][tid] + red[1][tid] + red[2][tid] + red[3][tid];
        betaB[(size_t)t * 4 + tid] = 1.f / (1.f + expf(-tot));
    }
}

// ---------------- causal depthwise conv (KS=4) + silu + silu (+ per-head l2norm) ----------------
template <typename OUT>
__global__ __launch_bounds__(256) void conv_kernel(const float* __restrict__ G,
                                                   const float* __restrict__ w,  // [HID][KS]
                                                   OUT* __restrict__ out, int do_norm,
                                                   unsigned short* __restrict__ hi,
                                                   unsigned short* __restrict__ lo) {
    const int bl = blockIdx.x;
    const int l = bl & (L_SEQ - 1);
    const int tid = threadIdx.x;
    const int wave = tid >> 6, lane = tid & 63;
    float vals[4];
#pragma unroll
    for (int h = 0; h < 4; ++h) {
        const int c = tid + 256 * h;
        float acc = 0.f;
#pragma unroll
        for (int j = 0; j < 4; ++j) {
            int ls = l - 3 + j;
            float xv = 0.f;
            if (ls >= 0) xv = G[(size_t)(bl - 3 + j) * HID + c];
            acc += xv * w[c * 4 + j];
        }
        float s1 = acc / (1.f + expf(-acc));
        float s2 = s1 / (1.f + expf(-s1));
        vals[h] = s2;
    }
    if (do_norm) {
        float sq[4];
#pragma unroll
        for (int h = 0; h < 4; ++h) sq[h] = vals[h] * vals[h];
#pragma unroll
        for (int off = 32; off; off >>= 1)
#pragma unroll
            for (int h = 0; h < 4; ++h) sq[h] += __shfl_down(sq[h], off);
        __shared__ float red[4][4];
        __shared__ float nrm[4];
        if (lane == 0)
#pragma unroll
            for (int h = 0; h < 4; ++h) red[wave][h] = sq[h];
        __syncthreads();
        if (tid < 4) {
            float tot = red[0][tid] + red[1][tid] + red[2][tid] + red[3][tid];
            nrm[tid] = 1.f / fmaxf(sqrtf(tot), 1e-12f);
        }
        __syncthreads();
#pragma unroll
        for (int h = 0; h < 4; ++h) vals[h] *= nrm[h];
    }
#pragma unroll
    for (int h = 0; h < 4; ++h) {
        const int c = tid + 256 * h;
        if (out) storev(&out[(size_t)bl * HID + c], vals[h]);
        if (hi) {
            unsigned short hv = f2bu(vals[h]);
            hi[(size_t)bl * HID + c] = hv;
            lo[(size_t)bl * HID + c] = f2bu(vals[h] - bu2f(hv));
        }
    }
}

// ---------------- per-chunk per-head gram: G_h = K_h * K_h^T (split-bf16 MFMA) ----------------
__global__ __launch_bounds__(256) void gram_kernel(const unsigned short* __restrict__ Khi,
                                                   const unsigned short* __restrict__ Klo,
                                                   float* __restrict__ Gg) {
    const int chunk = blockIdx.x;
    const int h = blockIdx.y;
    const int tid = threadIdx.x;
    const int wave = tid >> 6, lane = tid & 63;
    const int quad = lane >> 4, l16 = lane & 15;
    __shared__ unsigned short Hs[64 * 264];
    __shared__ unsigned short Ls[64 * 264];
    const int l0 = chunk * 64;
    const int cb = h * 256;
#pragma unroll
    for (int p = 0; p < 8; ++p) {
        int row = p * 8 + (tid >> 5);
        int col = (tid & 31) * 8;
        v8u hv = *(const v8u*)(Khi + (size_t)(l0 + row) * HID + cb + col);
        v8u lv = *(const v8u*)(Klo + (size_t)(l0 + row) * HID + cb + col);
        *(v8u*)&Hs[row * 264 + col] = hv;
        *(v8u*)&Ls[row * 264 + col] = lv;
    }
    __syncthreads();
    const int wm = wave * 16;
    v4f acc[4];
#pragma unroll
    for (int nt = 0; nt < 4; ++nt) { v4f z = {0.f, 0.f, 0.f, 0.f}; acc[nt] = z; }
#pragma unroll
    for (int ks = 0; ks < 8; ++ks) {
        v8s ah = *(const v8s*)&Hs[(wm + l16) * 264 + ks * 32 + quad * 8];
        v8s al = *(const v8s*)&Ls[(wm + l16) * 264 + ks * 32 + quad * 8];
#pragma unroll
        for (int nt = 0; nt < 4; ++nt) {
            v8s bh = *(const v8s*)&Hs[(nt * 16 + l16) * 264 + ks * 32 + quad * 8];
            v8s bl = *(const v8s*)&Ls[(nt * 16 + l16) * 264 + ks * 32 + quad * 8];
            acc[nt] = __builtin_amdgcn_mfma_f32_16x16x32_bf16(ah, bh, acc[nt], 0, 0, 0);
            acc[nt] = __builtin_amdgcn_mfma_f32_16x16x32_bf16(ah, bl, acc[nt], 0, 0, 0);
            acc[nt] = __builtin_amdgcn_mfma_f32_16x16x32_bf16(al, bh, acc[nt], 0, 0, 0);
        }
    }
    float* og = Gg + ((size_t)chunk * 4 + h) * 4096;
#pragma unroll
    for (int nt = 0; nt < 4; ++nt)
#pragma unroll
        for (int r = 0; r < 4; ++r)
            og[(wm + quad * 4 + r) * 64 + nt * 16 + l16] = acc[nt][r];
}

// ---------------- T recurrence per chunk via nilpotent doubling + MFMA ----------------
// Reference recurrence == T_final = 3*(I-A)^{-1} - 2I, A = -tril(beta*gram, -1).
// (I-A)^{-1} = prod_{k=0..5} (I + A^(2^k)) since A^64 = 0.
// 6 stages, each from OLD state: accP = P*B (seeded with P), accB = B*B; split-bf16 MFMA.
__global__ __launch_bounds__(256) void trec_kernel(const float* __restrict__ Gg,
                                                   const float* __restrict__ betaB,
                                                   float* __restrict__ Tg) {
    const int chunk = blockIdx.x;
    const int tid = threadIdx.x;
    const int wave = tid >> 6, lane = tid & 63;
    const int quad = lane >> 4, l16 = lane & 15;
    const int wm = wave * 16;
    __shared__ unsigned short BhR[64 * 72], BlR[64 * 72];  // B rows   [i][j]
    __shared__ unsigned short BhT[64 * 72], BlT[64 * 72];  // B^T rows [j][i]
    __shared__ unsigned short PhR[64 * 72], PlR[64 * 72];  // P rows   [i][j]
    __shared__ float Pf[64 * 73];                          // P master copy (f32)
    __shared__ float betS[256];
    betS[tid] = betaB[(size_t)chunk * 256 + tid];
    __syncthreads();
    const float* gg = Gg + (size_t)chunk * 4 * 4096;
    // setup: B = A (strictly lower), P = I
#pragma unroll
    for (int s = 0; s < 16; ++s) {
        int idx = tid + 256 * s;
        int i = idx >> 6, j = idx & 63;
        float a = 0.f;
        if (i > j) {
            a = -(betS[i * 4 + 0] * gg[idx] + betS[i * 4 + 1] * gg[4096 + idx] +
                  betS[i * 4 + 2] * gg[2 * 4096 + idx] + betS[i * 4 + 3] * gg[3 * 4096 + idx]);
        }
        unsigned short ah = f2bu(a);
        unsigned short al = f2bu(a - bu2f(ah));
        BhR[i * 72 + j] = ah;
        BlR[i * 72 + j] = al;
        BhT[j * 72 + i] = ah;
        BlT[j * 72 + i] = al;
        float p = (i == j) ? 1.f : 0.f;
        Pf[i * 73 + j] = p;
        PhR[i * 72 + j] = f2bu(p);
        PlR[i * 72 + j] = 0;
    }
    __syncthreads();

    for (int st = 0; st < 6; ++st) {
        // load all fragments from OLD state (each wave owns rows [wm, wm+16))
        v8s aBh[2], aBl[2], aPh[2], aPl[2];
        v8s bTh[2][4], bTl[2][4];
#pragma unroll
        for (int kk = 0; kk < 2; ++kk) {
            aBh[kk] = *(const v8s*)&BhR[(wm + l16) * 72 + kk * 32 + quad * 8];
            aBl[kk] = *(const v8s*)&BlR[(wm + l16) * 72 + kk * 32 + quad * 8];
            aPh[kk] = *(const v8s*)&PhR[(wm + l16) * 72 + kk * 32 + quad * 8];
            aPl[kk] = *(const v8s*)&PlR[(wm + l16) * 72 + kk * 32 + quad * 8];
#pragma unroll
            for (int nt = 0; nt < 4; ++nt) {
                bTh[kk][nt] = *(const v8s*)&BhT[(nt * 16 + l16) * 72 + kk * 32 + quad * 8];
                bTl[kk][nt] = *(const v8s*)&BlT[(nt * 16 + l16) * 72 + kk * 32 + quad * 8];
            }
        }
        v4f accP[4], accB[4];
#pragma unroll
        for (int nt = 0; nt < 4; ++nt) {
#pragma unroll
            for (int r = 0; r < 4; ++r)
                accP[nt][r] = Pf[(wm + quad * 4 + r) * 73 + nt * 16 + l16];
            v4f z = {0.f, 0.f, 0.f, 0.f};
            accB[nt] = z;
        }
        __syncthreads();  // all reads done before anyone writes
        // P' = P + P*B (split-bf16: hi*hi + hi*lo + lo*hi)
#pragma unroll
        for (int kk = 0; kk < 2; ++kk)
#pragma unroll
            for (int nt = 0; nt < 4; ++nt) {
                accP[nt] = __builtin_amdgcn_mfma_f32_16x16x32_bf16(aPh[kk], bTh[kk][nt], accP[nt], 0, 0, 0);
                accP[nt] = __builtin_amdgcn_mfma_f32_16x16x32_bf16(aPh[kk], bTl[kk][nt], accP[nt], 0, 0, 0);
                accP[nt] = __builtin_amdgcn_mfma_f32_16x16x32_bf16(aPl[kk], bTh[kk][nt], accP[nt], 0, 0, 0);
            }
        if (st < 5) {
            // B' = B*B (last stage would be A^64 = 0 -> skip)
#pragma unroll
            for (int kk = 0; kk < 2; ++kk)
#pragma unroll
                for (int nt = 0; nt < 4; ++nt) {
                    accB[nt] = __builtin_amdgcn_mfma_f32_16x16x32_bf16(aBh[kk], bTh[kk][nt], accB[nt], 0, 0, 0);
                    accB[nt] = __builtin_amdgcn_mfma_f32_16x16x32_bf16(aBh[kk], bTl[kk][nt], accB[nt], 0, 0, 0);
                    accB[nt] = __builtin_amdgcn_mfma_f32_16x16x32_bf16(aBl[kk], bTh[kk][nt], accB[nt], 0, 0, 0);
                }
        }
        // write back new state
#pragma unroll
        for (int nt = 0; nt < 4; ++nt)
#pragma unroll
            for (int r = 0; r < 4; ++r) {
                int row = wm + quad * 4 + r;
                int col = nt * 16 + l16;
                float pv = accP[nt][r];
                Pf[row * 73 + col] = pv;
                unsigned short ph = f2bu(pv);
                PhR[row * 72 + col] = ph;
                PlR[row * 72 + col] = f2bu(pv - bu2f(ph));
                if (st < 5) {
                    float bv = accB[nt][r];
                    unsigned short bh2 = f2bu(bv);
                    unsigned short bl2 = f2bu(bv - bu2f(bh2));
                    BhR[row * 72 + col] = bh2;
                    BlR[row * 72 + col] = bl2;
                    BhT[col * 72 + row] = bh2;
                    BlT[col * 72 + row] = bl2;
                }
            }
        __syncthreads();
    }
    // T = 3P - 2I
#pragma unroll
    for (int s = 0; s < 16; ++s) {
        int idx = tid + 256 * s;
        int i = idx >> 6, j = idx & 63;
        float t = (i == j) ? 1.f : 3.f * Pf[i * 73 + j];
        Tg[(size_t)chunk * 4096 + idx] = t;
    }
}

// ---------------- W = T'·K, U = T'·V via MFMA (T' = T·diag(beta)); fused kw/ku ----------------
__global__ __launch_bounds__(256) void wu_mfma_kernel(const float* __restrict__ Tg,
                                                      const unsigned short* __restrict__ Khi,
                                                      const unsigned short* __restrict__ Vhi,
                                                      const float* __restrict__ betaB,
                                                      unsigned short* __restrict__ Wb,
                                                      unsigned short* __restrict__ Ub,
                                                      float* __restrict__ kw, float* __restrict__ ku) {
    const int chunk = blockIdx.x;  // 128
    const int h = blockIdx.y;      // 4
    const int half = blockIdx.z;   // 2
    const int tid = threadIdx.x;
    const int wave = tid >> 6, lane = tid & 63;
    const int quad = lane >> 4, l16 = lane & 15;
    const size_t l0 = (size_t)chunk * 64;
    const int f0 = h * 256 + half * 128;
    __shared__ unsigned short Th[64 * 72], Tl[64 * 72];
    __shared__ unsigned short KT[128 * 72], VT[128 * 72];
    __shared__ float betS[64];
    if (tid < 64) betS[tid] = betaB[(l0 + tid) * 4 + h];
    __syncthreads();
#pragma unroll
    for (int s = 0; s < 16; ++s) {
        int idx = tid + 256 * s;
        int c = idx >> 6, j = idx & 63;
        float v = Tg[(size_t)chunk * 4096 + idx] * betS[j];
        unsigned short hv = f2bu(v);
        Th[c * 72 + j] = hv;
        Tl[c * 72 + j] = f2bu(v - bu2f(hv));
    }
#pragma unroll
    for (int pass = 0; pass < 4; ++pass) {
        int j = pass * 16 + (tid >> 4);
        int fc = (tid & 15) * 8;
        v8u kv = *(const v8u*)(Khi + (l0 + j) * HID + f0 + fc);
        v8u vv = *(const v8u*)(Vhi + (l0 + j) * HID + f0 + fc);
#pragma unroll
        for (int i = 0; i < 8; ++i) {
            KT[(fc + i) * 72 + j] = kv[i];
            VT[(fc + i) * 72 + j] = vv[i];
        }
    }
    __syncthreads();

    const int nf = wave * 32;
    const int bb = chunk >> 6, nn = chunk & 63;
    const size_t obase = (((size_t)bb * 4 + h) * 64 + nn) * 256 + half * 128;

#pragma unroll
    for (int phase = 0; phase < 2; ++phase) {
        const unsigned short* BT = phase ? VT : KT;
        v4f acc[4][2];
#pragma unroll
        for (int mt = 0; mt < 4; ++mt)
#pragma unroll
            for (int nt = 0; nt < 2; ++nt) { v4f z = {0.f, 0.f, 0.f, 0.f}; acc[mt][nt] = z; }
#pragma unroll
        for (int k0 = 0; k0 < 64; k0 += 32) {
            v8s ah[4], al[4], bf[2];
#pragma unroll
            for (int mt = 0; mt < 4; ++mt) {
                ah[mt] = *(const v8s*)&Th[(mt * 16 + l16) * 72 + k0 + quad * 8];
                al[mt] = *(const v8s*)&Tl[(mt * 16 + l16) * 72 + k0 + quad * 8];
            }
#pragma unroll
            for (int nt = 0; nt < 2; ++nt)
                bf[nt] = *(const v8s*)&BT[(nf + nt * 16 + l16) * 72 + k0 + quad * 8];
#pragma unroll
            for (int mt = 0; mt < 4; ++mt)
#pragma unroll
                for (int nt = 0; nt < 2; ++nt) {
                    acc[mt][nt] = __builtin_amdgcn_mfma_f32_16x16x32_bf16(ah[mt], bf[nt], acc[mt][nt], 0, 0, 0);
                    acc[mt][nt] = __builtin_amdgcn_mfma_f32_16x16x32_bf16(al[mt], bf[nt], acc[mt][nt], 0, 0, 0);
                }
        }
        unsigned short* Out = phase ? Ub : Wb;
        float* kk = phase ? ku : kw;
#pragma unroll
        for (int nt = 0; nt < 2; ++nt) {
            const int fl = nf + nt * 16 + l16;
            float dot = 0.f;
#pragma unroll
            for (int mt = 0; mt < 4; ++mt)
#pragma unroll
                for (int r = 0; r < 4; ++r) {
                    const int c = mt * 16 + quad * 4 + r;
                    float wv = acc[mt][nt][r];
                    Out[(l0 + c) * HID + f0 + fl] = f2bu(wv);
                    dot += bu2f(KT[fl * 72 + c]) * wv;
                }
            dot += __shfl_xor(dot, 16);
            dot += __shfl_xor(dot, 32);
            if (quad == 0) kk[obase + fl] = dot;
        }
    }
}

// ---------------- diagonal scan over chunks ----------------
__global__ __launch_bounds__(256) void scan_kernel(const float* __restrict__ kw,
                                                   const float* __restrict__ ku,
                                                   float* __restrict__ dsA) {
    const int bh = blockIdx.x;
    const int e = threadIdx.x;
    float ds = 0.f;
    for (int n = 0; n < 64; ++n) {
        size_t idx = ((size_t)bh * 64 + n) * 256 + e;
        dsA[idx] = ds;
        ds = ds * (1.f - kw[idx]) + ku[idx];
    }
}

__device__ __forceinline__ float block_sum(float v, float* red) {
#pragma unroll
    for (int off = 32; off; off >>= 1) v += __shfl_down(v, off);
    const int wave = threadIdx.x >> 6;
    if ((threadIdx.x & 63) == 0) red[wave] = v;
    __syncthreads();
    float t = red[0] + red[1] + red[2] + red[3];
    __syncthreads();
    return t;
}

// ---------------- o = q*ds + [c<=b]*A*(u - w*ds); fused RMSNorm + bf16 cast ----------------
__global__ __launch_bounds__(256) void o_kernel(const __hip_bfloat16* __restrict__ Qb,
                                                const unsigned short* __restrict__ Khi,
                                                const unsigned short* __restrict__ Wb,
                                                const unsigned short* __restrict__ Ub,
                                                const float* __restrict__ dsA,
                                                const float* __restrict__ rmsw,
                                                __hip_bfloat16* __restrict__ ob,
                                                unsigned short* __restrict__ ub) {
    const int bl = blockIdx.x;
    const int b = bl >> 12, l = bl & (L_SEQ - 1);
    const int n = l >> 6, cpos = l & 63;
    const int tid = threadIdx.x;
    __shared__ float red[4];
    const size_t rowb = (size_t)bl * HID;
    float dsv[4], qv[4], ov[4];
#pragma unroll
    for (int h = 0; h < 4; ++h) {
        dsv[h] = dsA[(((size_t)b * 4 + h) * 64 + n) * 256 + tid];
        qv[h] = __bfloat162float(Qb[rowb + tid + 256 * h]);
    }
    const bool doA = (cpos <= b);
    float Aval = 0.f;
    if (doA) {
        float s = 0.f;
#pragma unroll
        for (int h = 0; h < 4; ++h) s += qv[h] * bu2f(Khi[rowb + tid + 256 * h]);
        Aval = block_sum(s, red);
    }
    float ss = 0.f;
#pragma unroll
    for (int h = 0; h < 4; ++h) {
        int c = tid + 256 * h;
        float u = bu2f(Ub[rowb + c]) - bu2f(Wb[rowb + c]) * dsv[h];
        ub[rowb + c] = f2bu(u);
        float o = qv[h] * dsv[h];
        if (doA) o += Aval * u;
        ov[h] = o;
        ss += o * o;
    }
    float tot = block_sum(ss, red);
    float scale = rsqrtf(tot * (1.f / 1024.f) + 1e-5f);
#pragma unroll
    for (int h = 0; h < 4; ++h) {
        int c = tid + 256 * h;
        ob[rowb + c] = __float2bfloat16(ov[h] * scale * rmsw[c]);
    }
}

// ---------------- state S = K^T u'  via MFMA (n-split partials) ----------------
#define SNS 16
__global__ __launch_bounds__(256) void s_mfma_kernel(const unsigned short* __restrict__ Khi,
                                                     const unsigned short* __restrict__ Ub,
                                                     float* __restrict__ Spart) {
    const int bh = blockIdx.x;
    const int b = bh >> 2, h = bh & 3;
    const int dt = blockIdx.y;
    const int et = blockIdx.z & 1;
    const int ns = blockIdx.z >> 1;
    const int tid = threadIdx.x;
    const int wave = tid >> 6, lane = tid & 63;
    const int quad = lane >> 4, l16 = lane & 15;
    const int wm = (wave >> 1) * 64, wn = (wave & 1) * 64;
    __shared__ unsigned short Kt[128 * 40];
    __shared__ unsigned short Ut[128 * 40];
    const int cc = tid >> 3;
    const int dcol = (tid & 7) * 16;
    const size_t rowbase = (size_t)b * 4096 + (size_t)ns * 256;
    const int ck = h * 256 + dt * 128;
    const int ce = h * 256 + et * 128;
    v4f acc[4][4];
#pragma unroll
    for (int a = 0; a < 4; ++a)
#pragma unroll
        for (int c2 = 0; c2 < 4; ++c2) { v4f z = {0.f, 0.f, 0.f, 0.f}; acc[a][c2] = z; }

    for (int kt = 0; kt < 8; ++kt) {
        size_t row = rowbase + kt * 32 + cc;
        v8u k0 = *(const v8u*)(Khi + row * HID + ck + dcol);
        v8u k1 = *(const v8u*)(Khi + row * HID + ck + dcol + 8);
        v8u u0 = *(const v8u*)(Ub + row * HID + ce + dcol);
        v8u u1 = *(const v8u*)(Ub + row * HID + ce + dcol + 8);
        __syncthreads();
#pragma unroll
        for (int j = 0; j < 8; ++j) {
            Kt[(dcol + j) * 40 + cc] = k0[j];
            Kt[(dcol + 8 + j) * 40 + cc] = k1[j];
            Ut[(dcol + j) * 40 + cc] = u0[j];
            Ut[(dcol + 8 + j) * 40 + cc] = u1[j];
        }
        __syncthreads();
        v8s af[4], bf[4];
#pragma unroll
        for (int mt = 0; mt < 4; ++mt) af[mt] = *(const v8s*)&Kt[(wm + mt * 16 + l16) * 40 + quad * 8];
#pragma unroll
        for (int nt = 0; nt < 4; ++nt) bf[nt] = *(const v8s*)&Ut[(wn + nt * 16 + l16) * 40 + quad * 8];
#pragma unroll
        for (int mt = 0; mt < 4; ++mt)
#pragma unroll
            for (int nt = 0; nt < 4; ++nt)
                acc[mt][nt] = __builtin_amdgcn_mfma_f32_16x16x32_bf16(af[mt], bf[nt], acc[mt][nt], 0, 0, 0);
    }
    float* out = Spart + (size_t)ns * (8 * 256 * 256);
#pragma unroll
    for (int mt = 0; mt < 4; ++mt)
#pragma unroll
        for (int nt = 0; nt < 4; ++nt) {
            int row = dt * 128 + wm + mt * 16 + quad * 4;
            int col = et * 128 + wn + nt * 16 + l16;
#pragma unroll
            for (int r = 0; r < 4; ++r)
                out[((size_t)bh * 256 + row + r) * 256 + col] = acc[mt][nt][r];
        }
}

// ---------------- reduce SNS partials -> out1 ----------------
__global__ __launch_bounds__(256) void sreduce_kernel(const float* __restrict__ Spart,
                                                      float* __restrict__ out) {
    int i = blockIdx.x * 256 + threadIdx.x;
    float s = 0.f;
#pragma unroll
    for (int ns = 0; ns < SNS; ++ns) s += Spart[(size_t)ns * (8 * 256 * 256) + i];
    out[i] = s;
}

extern "C" void kernel_launch(void* const* d_in, const int* in_sizes, int n_in,
                              void* d_out, int out_size, void* d_ws, size_t ws_size,
                              hipStream_t stream) {
    const float* x     = (const float*)d_in[0];
    const float* Wq    = (const float*)d_in[1];
    const float* Wk    = (const float*)d_in[2];
    const float* Wv    = (const float*)d_in[3];
    const float* convq = (const float*)d_in[4];
    const float* convk = (const float*)d_in[5];
    const float* convv = (const float*)d_in[6];
    const float* Wbeta = (const float*)d_in[7];
    const float* rmsw  = (const float*)d_in[8];
    const float* Wo    = (const float*)d_in[9];

    // ---- workspace map (~130 MiB; aliases documented) ----
    char* ws = (char*)d_ws;
    size_t off = 0;
    auto alloc = [&](size_t bytes) {
        char* p = ws + off;
        off += (bytes + 255) & ~(size_t)255;
        return (void*)p;
    };
    unsigned short* xhi  = (unsigned short*)alloc((size_t)BL_TOT * HID * 2);  // later Qm/ob
    unsigned short* Khi  = (unsigned short*)alloc((size_t)BL_TOT * HID * 2);  // conv_k -> s_mfma
    unsigned short* wbV  = (unsigned short*)alloc((size_t)HID * HID * 2);
    unsigned short* wbK  = (unsigned short*)alloc((size_t)HID * HID * 2);
    unsigned short* wbQ  = (unsigned short*)alloc((size_t)HID * HID * 2);
    unsigned short* wbO  = (unsigned short*)alloc((size_t)HID * HID * 2);
    float*          Gt   = (float*)alloc((size_t)BL_TOT * HID * 4);  // gemm out; later Spart
    unsigned short* Vhi  = (unsigned short*)alloc((size_t)BL_TOT * HID * 2);
    unsigned short* Wb16 = (unsigned short*)alloc((size_t)BL_TOT * HID * 2);
    unsigned short* Ub16 = (unsigned short*)alloc((size_t)BL_TOT * HID * 2);
    float* Tg    = (float*)alloc((size_t)128 * 4096 * 4);
    float* betaB = (float*)alloc((size_t)BL_TOT * 4 * 4);
    float* kwB   = (float*)alloc((size_t)8 * 64 * 256 * 4);
    float* kuB   = (float*)alloc((size_t)8 * 64 * 256 * 4);
    float* dsA   = (float*)alloc((size_t)8 * 64 * 256 * 4);
    __hip_bfloat16* Qm = (__hip_bfloat16*)xhi;  // xhi dead after Q GEMM (last x-GEMM)
    __hip_bfloat16* ob = Qm;                    // q dead after o_kernel reads its own row
    float* Spart = Gt;                          // Gt dead after conv_q

    float* out0 = (float*)d_out;
    float* out1 = out0 + (size_t)BL_TOT * HID;
    // d_out as pre-final scratch (validated only after launch):
    unsigned short* Klo = (unsigned short*)out0;            // bytes 0..16.78M
    unsigned short* ubf = (unsigned short*)out0 + 8388608;  // bytes 16.78M..33.55M
    float* Gg = out0 + (size_t)4400000;                     // gram scratch; dead before o_kernel

    dim3 blk(256);
    dim3 ggrid(BL_TOT / 128, HID / 128);

    wcvt_kernel<<<dim3(256, 4), blk, 0, stream>>>(Wv, Wk, Wq, Wo, wbV, wbK, wbQ, wbO);
    beta_kernel<<<BL_TOT, blk, 0, stream>>>(x, Wbeta, betaB, xhi);

    // V path (plain bf16)
    gemm_mfma<<<ggrid, blk, 0, stream>>>(xhi, wbV, Gt, BL_TOT, HID, HID);
    conv_kernel<__hip_bfloat16><<<BL_TOT, blk, 0, stream>>>(Gt, convv, (__hip_bfloat16*)Vhi, 0, nullptr, nullptr);
    // K path (plain bf16 GEMM; conv emits bf16 hi/lo — gram stays faithful to the K actually used)
    gemm_mfma<<<ggrid, blk, 0, stream>>>(xhi, wbK, Gt, BL_TOT, HID, HID);
    conv_kernel<float><<<BL_TOT, blk, 0, stream>>>(Gt, convk, (float*)nullptr, 1, Khi, Klo);
    // gram + T recurrence
    gram_kernel<<<dim3(128, 4), blk, 0, stream>>>(Khi, Klo, Gg);
    trec_kernel<<<128, blk, 0, stream>>>(Gg, betaB, Tg);
    // Q path (plain bf16). Last x-GEMM: frees xhi.
    gemm_mfma<<<ggrid, blk, 0, stream>>>(xhi, wbQ, Gt, BL_TOT, HID, HID);
    conv_kernel<__hip_bfloat16><<<BL_TOT, blk, 0, stream>>>(Gt, convq, Qm, 1, nullptr, nullptr);

    // chunked delta rule
    wu_mfma_kernel<<<dim3(128, 4, 2), blk, 0, stream>>>(Tg, Khi, Vhi, betaB, Wb16, Ub16, kwB, kuB);
    scan_kernel<<<8, blk, 0, stream>>>(kwB, kuB, dsA);
    o_kernel<<<BL_TOT, blk, 0, stream>>>(Qm, Khi, Wb16, Ub16, dsA, rmsw, ob, ubf);
    s_mfma_kernel<<<dim3(8, 2, 2 * SNS), blk, 0, stream>>>(Khi, ubf, Spart);
    sreduce_kernel<<<2048, blk, 0, stream>>>(Spart, out1);

    // final projection: o(bf16) @ Wo^T -> f32 out0 (overwrites Klo/ubf scratch)
    gemm_mfma<<<ggrid, blk, 0, stream>>>((const unsigned short*)ob, wbO, out0, BL_TOT, HID, HID);
}

// Round 3
// 392.917 us; speedup vs baseline: 1.1506x; 1.0940x over previous
//
#include <hip/hip_runtime.h>
#include <hip/hip_bf16.h>

#define L_SEQ 4096
#define HID 1024
#define NH 4
#define DH 256
#define CK 64
#define BL_TOT 8192   // B*L

typedef short v8s __attribute__((ext_vector_type(8)));
typedef unsigned short v8u __attribute__((ext_vector_type(8)));
typedef unsigned short v4us __attribute__((ext_vector_type(4)));
typedef float v4f __attribute__((ext_vector_type(4)));

typedef __attribute__((address_space(1))) const void* as1cv;
typedef __attribute__((address_space(3))) void* as3v;

__device__ __forceinline__ unsigned short f2bu(float f) {
    __hip_bfloat16 h = __float2bfloat16(f);
    return *(unsigned short*)&h;
}
__device__ __forceinline__ float bu2f(unsigned short u) {
    __hip_bfloat16 h = *(__hip_bfloat16*)&u;
    return __bfloat162float(h);
}

// ---------------- all-weights f32 -> bf16 in one dispatch ----------------
__global__ __launch_bounds__(256) void wcvt_kernel(const float* __restrict__ s0, const float* __restrict__ s1,
                                                   const float* __restrict__ s2, const float* __restrict__ s3,
                                                   unsigned short* __restrict__ d0, unsigned short* __restrict__ d1,
                                                   unsigned short* __restrict__ d2, unsigned short* __restrict__ d3) {
    const float* s = blockIdx.y == 0 ? s0 : blockIdx.y == 1 ? s1 : blockIdx.y == 2 ? s2 : s3;
    unsigned short* d = blockIdx.y == 0 ? d0 : blockIdx.y == 1 ? d1 : blockIdx.y == 2 ? d2 : d3;
    int i = blockIdx.x * 256 + threadIdx.x;
    int stride = gridDim.x * 256;
    for (; i < HID * HID; i += stride) d[i] = f2bu(s[i]);
}

// ---------------- MFMA bf16 GEMM: C[M,N] = A[M,K] * B[N,K]^T  (f32 out) ----------------
// m97-structure: global_load_lds width=16 direct staging, linear [128][32] LDS tiles.
__global__ __launch_bounds__(256) void gemm_mfma(const unsigned short* __restrict__ Ah,
                                                 const unsigned short* __restrict__ Bh,
                                                 float* __restrict__ C, int M, int N, int K) {
    __shared__ unsigned short AsH[128 * 32];
    __shared__ unsigned short BsH[128 * 32];
    const int tid = threadIdx.x;
    const int wave = tid >> 6, lane = tid & 63;
    const int quad = lane >> 4, l16 = lane & 15;
    const int m0 = blockIdx.x * 128, n0 = blockIdx.y * 128;
    const int wm = (wave >> 1) * 64, wn = (wave & 1) * 64;

    // staging geometry: one issue = 256 thr * 16B = 4 KB = 64 rows * 64 B
    const int srow = wave * 16 + (lane >> 2);  // 0..63
    const int scol = (lane & 3) * 8;           // shorts (16 B)
    const unsigned short* Ag = Ah + (size_t)(m0 + srow) * K + scol;
    const unsigned short* Bg = Bh + (size_t)(n0 + srow) * K + scol;
    char* lA = (char*)AsH;
    char* lB = (char*)BsH;
    const int lbase = wave * 1024;

    v4f acc[4][4];
#pragma unroll
    for (int a = 0; a < 4; ++a)
#pragma unroll
        for (int b = 0; b < 4; ++b) { v4f z = {0.f, 0.f, 0.f, 0.f}; acc[a][b] = z; }

    for (int k0 = 0; k0 < K; k0 += 32) {
        __syncthreads();  // previous tile's ds_reads complete
        __builtin_amdgcn_global_load_lds((as1cv)(Ag + k0), (as3v)(lA + lbase), 16, 0, 0);
        __builtin_amdgcn_global_load_lds((as1cv)(Ag + (size_t)64 * K + k0), (as3v)(lA + 4096 + lbase), 16, 0, 0);
        __builtin_amdgcn_global_load_lds((as1cv)(Bg + k0), (as3v)(lB + lbase), 16, 0, 0);
        __builtin_amdgcn_global_load_lds((as1cv)(Bg + (size_t)64 * K + k0), (as3v)(lB + 4096 + lbase), 16, 0, 0);
        __syncthreads();  // drains vmcnt -> LDS tile ready
        v8s afh[4], bfh[4];
#pragma unroll
        for (int mt = 0; mt < 4; ++mt) afh[mt] = *(const v8s*)&AsH[(wm + mt * 16 + l16) * 32 + quad * 8];
#pragma unroll
        for (int nt = 0; nt < 4; ++nt) bfh[nt] = *(const v8s*)&BsH[(wn + nt * 16 + l16) * 32 + quad * 8];
#pragma unroll
        for (int mt = 0; mt < 4; ++mt)
#pragma unroll
            for (int nt = 0; nt < 4; ++nt)
                acc[mt][nt] = __builtin_amdgcn_mfma_f32_16x16x32_bf16(afh[mt], bfh[nt], acc[mt][nt], 0, 0, 0);
    }
#pragma unroll
    for (int mt = 0; mt < 4; ++mt)
#pragma unroll
        for (int nt = 0; nt < 4; ++nt) {
            int row = m0 + wm + mt * 16 + quad * 4;
            int col = n0 + wn + nt * 16 + l16;
#pragma unroll
            for (int r = 0; r < 4; ++r)
                C[(size_t)(row + r) * N + col] = acc[mt][nt][r];
        }
}

// ---------------- beta = sigmoid(x @ Wbeta^T); fused x -> bf16 (float4 single-pass) ----------------
__global__ __launch_bounds__(256) void beta_kernel(const float* __restrict__ x,
                                                   const float* __restrict__ Wb,
                                                   float* __restrict__ betaB,
                                                   unsigned short* __restrict__ xh) {
    const int t = blockIdx.x;
    const int tid = threadIdx.x;
    const int wave = tid >> 6, lane = tid & 63;
    const float* xr = x + (size_t)t * HID;
    v4f xv = *(const v4f*)(xr + tid * 4);
    v4us xp;
#pragma unroll
    for (int i = 0; i < 4; ++i) xp[i] = f2bu(xv[i]);
    *(v4us*)&xh[(size_t)t * HID + tid * 4] = xp;
    float s[4];
#pragma unroll
    for (int h = 0; h < 4; ++h) {
        v4f wv = *(const v4f*)(Wb + (size_t)h * HID + tid * 4);
        s[h] = xv[0] * wv[0] + xv[1] * wv[1] + xv[2] * wv[2] + xv[3] * wv[3];
    }
#pragma unroll
    for (int off = 32; off; off >>= 1)
#pragma unroll
        for (int h = 0; h < 4; ++h) s[h] += __shfl_down(s[h], off);
    __shared__ float red[4][4];
    if (lane == 0)
#pragma unroll
        for (int h = 0; h < 4; ++h) red[wave][h] = s[h];
    __syncthreads();
    if (tid < 4) {
        float tot = red[0][tid] + red[1][tid] + red[2][tid] + red[3][tid];
        betaB[(size_t)t * 4 + tid] = 1.f / (1.f + expf(-tot));
    }
}

// ---------------- causal depthwise conv (KS=4) + silu + silu (+ per-head l2norm) ----------------
// Vectorized: thread owns 4 contiguous channels of head (tid>>6); l2norm = pure wave shuffle.
// path p: 0=V (bf16 out, no norm), 1=K (hi/lo out, norm), 2=Q (bf16 out, norm).
__global__ __launch_bounds__(256) void conv_kernel(const float* __restrict__ G, int gstride, int pathArg,
                                                   const float* __restrict__ wq, const float* __restrict__ wk,
                                                   const float* __restrict__ wv,
                                                   unsigned short* __restrict__ Vout,
                                                   unsigned short* __restrict__ KhiO, unsigned short* __restrict__ KloO,
                                                   unsigned short* __restrict__ Qout) {
    const int p = pathArg < 0 ? (int)blockIdx.y : pathArg;
    const int yoff = pathArg < 0 ? p * 1024 : 0;
    const float* __restrict__ w = p == 0 ? wv : p == 1 ? wk : wq;
    const int bl = blockIdx.x;
    const int l = bl & (L_SEQ - 1);
    const int tid = threadIdx.x;
    const int lane = tid & 63;
    const int c4 = (tid >> 6) * 256 + lane * 4;  // 4 contiguous channels in head (tid>>6)
    v4f wrow[4];
#pragma unroll
    for (int cc = 0; cc < 4; ++cc) wrow[cc] = *(const v4f*)&w[(c4 + cc) * 4];
    v4f acc = {0.f, 0.f, 0.f, 0.f};
#pragma unroll
    for (int j = 0; j < 4; ++j) {
        int ls = l - 3 + j;
        if (ls >= 0) {
            v4f g = *(const v4f*)&G[(size_t)(bl - 3 + j) * gstride + yoff + c4];
#pragma unroll
            for (int cc = 0; cc < 4; ++cc) acc[cc] += g[cc] * wrow[cc][j];
        }
    }
    float vals[4];
#pragma unroll
    for (int cc = 0; cc < 4; ++cc) {
        float a = acc[cc];
        float s1 = a / (1.f + expf(-a));
        vals[cc] = s1 / (1.f + expf(-s1));
    }
    if (p >= 1) {
        float sq = vals[0] * vals[0] + vals[1] * vals[1] + vals[2] * vals[2] + vals[3] * vals[3];
#pragma unroll
        for (int off = 32; off; off >>= 1) sq += __shfl_xor(sq, off);
        float nrm = 1.f / fmaxf(sqrtf(sq), 1e-12f);
#pragma unroll
        for (int cc = 0; cc < 4; ++cc) vals[cc] *= nrm;
    }
    const size_t ob = (size_t)bl * HID + c4;
    if (p == 1) {
        v4us hv, lv;
#pragma unroll
        for (int cc = 0; cc < 4; ++cc) {
            unsigned short h = f2bu(vals[cc]);
            hv[cc] = h;
            lv[cc] = f2bu(vals[cc] - bu2f(h));
        }
        *(v4us*)&KhiO[ob] = hv;
        *(v4us*)&KloO[ob] = lv;
    } else {
        unsigned short* O = p == 0 ? Vout : Qout;
        v4us hv;
#pragma unroll
        for (int cc = 0; cc < 4; ++cc) hv[cc] = f2bu(vals[cc]);
        *(v4us*)&O[ob] = hv;
    }
}

// ---------------- per-chunk per-head gram: G_h = K_h * K_h^T (split-bf16 MFMA) ----------------
__global__ __launch_bounds__(256) void gram_kernel(const unsigned short* __restrict__ Khi,
                                                   const unsigned short* __restrict__ Klo,
                                                   float* __restrict__ Gg) {
    const int chunk = blockIdx.x;
    const int h = blockIdx.y;
    const int tid = threadIdx.x;
    const int wave = tid >> 6, lane = tid & 63;
    const int quad = lane >> 4, l16 = lane & 15;
    __shared__ unsigned short Hs[64 * 264];
    __shared__ unsigned short Ls[64 * 264];
    const int l0 = chunk * 64;
    const int cb = h * 256;
#pragma unroll
    for (int p = 0; p < 8; ++p) {
        int row = p * 8 + (tid >> 5);
        int col = (tid & 31) * 8;
        v8u hv = *(const v8u*)(Khi + (size_t)(l0 + row) * HID + cb + col);
        v8u lv = *(const v8u*)(Klo + (size_t)(l0 + row) * HID + cb + col);
        *(v8u*)&Hs[row * 264 + col] = hv;
        *(v8u*)&Ls[row * 264 + col] = lv;
    }
    __syncthreads();
    const int wm = wave * 16;
    v4f acc[4];
#pragma unroll
    for (int nt = 0; nt < 4; ++nt) { v4f z = {0.f, 0.f, 0.f, 0.f}; acc[nt] = z; }
#pragma unroll
    for (int ks = 0; ks < 8; ++ks) {
        v8s ah = *(const v8s*)&Hs[(wm + l16) * 264 + ks * 32 + quad * 8];
        v8s al = *(const v8s*)&Ls[(wm + l16) * 264 + ks * 32 + quad * 8];
#pragma unroll
        for (int nt = 0; nt < 4; ++nt) {
            v8s bh = *(const v8s*)&Hs[(nt * 16 + l16) * 264 + ks * 32 + quad * 8];
            v8s bl = *(const v8s*)&Ls[(nt * 16 + l16) * 264 + ks * 32 + quad * 8];
            acc[nt] = __builtin_amdgcn_mfma_f32_16x16x32_bf16(ah, bh, acc[nt], 0, 0, 0);
            acc[nt] = __builtin_amdgcn_mfma_f32_16x16x32_bf16(ah, bl, acc[nt], 0, 0, 0);
            acc[nt] = __builtin_amdgcn_mfma_f32_16x16x32_bf16(al, bh, acc[nt], 0, 0, 0);
        }
    }
    float* og = Gg + ((size_t)chunk * 4 + h) * 4096;
#pragma unroll
    for (int nt = 0; nt < 4; ++nt)
#pragma unroll
        for (int r = 0; r < 4; ++r)
            og[(wm + quad * 4 + r) * 64 + nt * 16 + l16] = acc[nt][r];
}

// ---------------- T recurrence per chunk via nilpotent doubling + MFMA ----------------
// T_final = 3*(I-A)^{-1} - 2I, A = -tril(beta*gram, -1); (I-A)^{-1} = prod (I + A^(2^k)).
__global__ __launch_bounds__(256) void trec_kernel(const float* __restrict__ Gg,
                                                   const float* __restrict__ betaB,
                                                   float* __restrict__ Tg) {
    const int chunk = blockIdx.x;
    const int tid = threadIdx.x;
    const int wave = tid >> 6, lane = tid & 63;
    const int quad = lane >> 4, l16 = lane & 15;
    const int wm = wave * 16;
    __shared__ unsigned short BhR[64 * 72], BlR[64 * 72];  // B rows   [i][j]
    __shared__ unsigned short BhT[64 * 72], BlT[64 * 72];  // B^T rows [j][i]
    __shared__ unsigned short PhR[64 * 72], PlR[64 * 72];  // P rows   [i][j]
    __shared__ float Pf[64 * 73];                          // P master copy (f32)
    __shared__ float betS[256];
    betS[tid] = betaB[(size_t)chunk * 256 + tid];
    __syncthreads();
    const float* gg = Gg + (size_t)chunk * 4 * 4096;
#pragma unroll
    for (int s = 0; s < 16; ++s) {
        int idx = tid + 256 * s;
        int i = idx >> 6, j = idx & 63;
        float a = 0.f;
        if (i > j) {
            a = -(betS[i * 4 + 0] * gg[idx] + betS[i * 4 + 1] * gg[4096 + idx] +
                  betS[i * 4 + 2] * gg[2 * 4096 + idx] + betS[i * 4 + 3] * gg[3 * 4096 + idx]);
        }
        unsigned short ah = f2bu(a);
        unsigned short al = f2bu(a - bu2f(ah));
        BhR[i * 72 + j] = ah;
        BlR[i * 72 + j] = al;
        BhT[j * 72 + i] = ah;
        BlT[j * 72 + i] = al;
        float p = (i == j) ? 1.f : 0.f;
        Pf[i * 73 + j] = p;
        PhR[i * 72 + j] = f2bu(p);
        PlR[i * 72 + j] = 0;
    }
    __syncthreads();

    for (int st = 0; st < 6; ++st) {
        v8s aBh[2], aBl[2], aPh[2], aPl[2];
        v8s bTh[2][4], bTl[2][4];
#pragma unroll
        for (int kk = 0; kk < 2; ++kk) {
            aBh[kk] = *(const v8s*)&BhR[(wm + l16) * 72 + kk * 32 + quad * 8];
            aBl[kk] = *(const v8s*)&BlR[(wm + l16) * 72 + kk * 32 + quad * 8];
            aPh[kk] = *(const v8s*)&PhR[(wm + l16) * 72 + kk * 32 + quad * 8];
            aPl[kk] = *(const v8s*)&PlR[(wm + l16) * 72 + kk * 32 + quad * 8];
#pragma unroll
            for (int nt = 0; nt < 4; ++nt) {
                bTh[kk][nt] = *(const v8s*)&BhT[(nt * 16 + l16) * 72 + kk * 32 + quad * 8];
                bTl[kk][nt] = *(const v8s*)&BlT[(nt * 16 + l16) * 72 + kk * 32 + quad * 8];
            }
        }
        v4f accP[4], accB[4];
#pragma unroll
        for (int nt = 0; nt < 4; ++nt) {
#pragma unroll
            for (int r = 0; r < 4; ++r)
                accP[nt][r] = Pf[(wm + quad * 4 + r) * 73 + nt * 16 + l16];
            v4f z = {0.f, 0.f, 0.f, 0.f};
            accB[nt] = z;
        }
        __syncthreads();  // all reads done before anyone writes
#pragma unroll
        for (int kk = 0; kk < 2; ++kk)
#pragma unroll
            for (int nt = 0; nt < 4; ++nt) {
                accP[nt] = __builtin_amdgcn_mfma_f32_16x16x32_bf16(aPh[kk], bTh[kk][nt], accP[nt], 0, 0, 0);
                accP[nt] = __builtin_amdgcn_mfma_f32_16x16x32_bf16(aPh[kk], bTl[kk][nt], accP[nt], 0, 0, 0);
                accP[nt] = __builtin_amdgcn_mfma_f32_16x16x32_bf16(aPl[kk], bTh[kk][nt], accP[nt], 0, 0, 0);
            }
        if (st < 5) {
#pragma unroll
            for (int kk = 0; kk < 2; ++kk)
#pragma unroll
                for (int nt = 0; nt < 4; ++nt) {
                    accB[nt] = __builtin_amdgcn_mfma_f32_16x16x32_bf16(aBh[kk], bTh[kk][nt], accB[nt], 0, 0, 0);
                    accB[nt] = __builtin_amdgcn_mfma_f32_16x16x32_bf16(aBh[kk], bTl[kk][nt], accB[nt], 0, 0, 0);
                    accB[nt] = __builtin_amdgcn_mfma_f32_16x16x32_bf16(aBl[kk], bTh[kk][nt], accB[nt], 0, 0, 0);
                }
        }
#pragma unroll
        for (int nt = 0; nt < 4; ++nt)
#pragma unroll
            for (int r = 0; r < 4; ++r) {
                int row = wm + quad * 4 + r;
                int col = nt * 16 + l16;
                float pv = accP[nt][r];
                Pf[row * 73 + col] = pv;
                unsigned short ph = f2bu(pv);
                PhR[row * 72 + col] = ph;
                PlR[row * 72 + col] = f2bu(pv - bu2f(ph));
                if (st < 5) {
                    float bv = accB[nt][r];
                    unsigned short bh2 = f2bu(bv);
                    unsigned short bl2 = f2bu(bv - bu2f(bh2));
                    BhR[row * 72 + col] = bh2;
                    BlR[row * 72 + col] = bl2;
                    BhT[col * 72 + row] = bh2;
                    BlT[col * 72 + row] = bl2;
                }
            }
        __syncthreads();
    }
#pragma unroll
    for (int s = 0; s < 16; ++s) {
        int idx = tid + 256 * s;
        int i = idx >> 6, j = idx & 63;
        float t = (i == j) ? 1.f : 3.f * Pf[i * 73 + j];
        Tg[(size_t)chunk * 4096 + idx] = t;
    }
}

// ---------------- W = T'·K, U = T'·V via MFMA (T' = T·diag(beta)); fused kw/ku ----------------
__global__ __launch_bounds__(256) void wu_mfma_kernel(const float* __restrict__ Tg,
                                                      const unsigned short* __restrict__ Khi,
                                                      const unsigned short* __restrict__ Vhi,
                                                      const float* __restrict__ betaB,
                                                      unsigned short* __restrict__ Wb,
                                                      unsigned short* __restrict__ Ub,
                                                      float* __restrict__ kw, float* __restrict__ ku) {
    const int chunk = blockIdx.x;  // 128
    const int h = blockIdx.y;      // 4
    const int half = blockIdx.z;   // 2
    const int tid = threadIdx.x;
    const int wave = tid >> 6, lane = tid & 63;
    const int quad = lane >> 4, l16 = lane & 15;
    const size_t l0 = (size_t)chunk * 64;
    const int f0 = h * 256 + half * 128;
    __shared__ unsigned short Th[64 * 72], Tl[64 * 72];
    __shared__ unsigned short KT[128 * 72], VT[128 * 72];
    __shared__ float betS[64];
    if (tid < 64) betS[tid] = betaB[(l0 + tid) * 4 + h];
    __syncthreads();
#pragma unroll
    for (int s = 0; s < 16; ++s) {
        int idx = tid + 256 * s;
        int c = idx >> 6, j = idx & 63;
        float v = Tg[(size_t)chunk * 4096 + idx] * betS[j];
        unsigned short hv = f2bu(v);
        Th[c * 72 + j] = hv;
        Tl[c * 72 + j] = f2bu(v - bu2f(hv));
    }
#pragma unroll
    for (int pass = 0; pass < 4; ++pass) {
        int j = pass * 16 + (tid >> 4);
        int fc = (tid & 15) * 8;
        v8u kv = *(const v8u*)(Khi + (l0 + j) * HID + f0 + fc);
        v8u vv = *(const v8u*)(Vhi + (l0 + j) * HID + f0 + fc);
#pragma unroll
        for (int i = 0; i < 8; ++i) {
            KT[(fc + i) * 72 + j] = kv[i];
            VT[(fc + i) * 72 + j] = vv[i];
        }
    }
    __syncthreads();

    const int nf = wave * 32;
    const int bb = chunk >> 6, nn = chunk & 63;
    const size_t obase = (((size_t)bb * 4 + h) * 64 + nn) * 256 + half * 128;

#pragma unroll
    for (int phase = 0; phase < 2; ++phase) {
        const unsigned short* BT = phase ? VT : KT;
        v4f acc[4][2];
#pragma unroll
        for (int mt = 0; mt < 4; ++mt)
#pragma unroll
            for (int nt = 0; nt < 2; ++nt) { v4f z = {0.f, 0.f, 0.f, 0.f}; acc[mt][nt] = z; }
#pragma unroll
        for (int k0 = 0; k0 < 64; k0 += 32) {
            v8s ah[4], al[4], bf[2];
#pragma unroll
            for (int mt = 0; mt < 4; ++mt) {
                ah[mt] = *(const v8s*)&Th[(mt * 16 + l16) * 72 + k0 + quad * 8];
                al[mt] = *(const v8s*)&Tl[(mt * 16 + l16) * 72 + k0 + quad * 8];
            }
#pragma unroll
            for (int nt = 0; nt < 2; ++nt)
                bf[nt] = *(const v8s*)&BT[(nf + nt * 16 + l16) * 72 + k0 + quad * 8];
#pragma unroll
            for (int mt = 0; mt < 4; ++mt)
#pragma unroll
                for (int nt = 0; nt < 2; ++nt) {
                    acc[mt][nt] = __builtin_amdgcn_mfma_f32_16x16x32_bf16(ah[mt], bf[nt], acc[mt][nt], 0, 0, 0);
                    acc[mt][nt] = __builtin_amdgcn_mfma_f32_16x16x32_bf16(al[mt], bf[nt], acc[mt][nt], 0, 0, 0);
                }
        }
        unsigned short* Out = phase ? Ub : Wb;
        float* kk = phase ? ku : kw;
#pragma unroll
        for (int nt = 0; nt < 2; ++nt) {
            const int fl = nf + nt * 16 + l16;
            float dot = 0.f;
#pragma unroll
            for (int mt = 0; mt < 4; ++mt)
#pragma unroll
                for (int r = 0; r < 4; ++r) {
                    const int c = mt * 16 + quad * 4 + r;
                    float wv = acc[mt][nt][r];
                    Out[(l0 + c) * HID + f0 + fl] = f2bu(wv);
                    dot += bu2f(KT[fl * 72 + c]) * wv;
                }
            dot += __shfl_xor(dot, 16);
            dot += __shfl_xor(dot, 32);
            if (quad == 0) kk[obase + fl] = dot;
        }
    }
}

// ---------------- diagonal scan over chunks ----------------
__global__ __launch_bounds__(256) void scan_kernel(const float* __restrict__ kw,
                                                   const float* __restrict__ ku,
                                                   float* __restrict__ dsA) {
    const int bh = blockIdx.x;
    const int e = threadIdx.x;
    float ds = 0.f;
    for (int n = 0; n < 64; ++n) {
        size_t idx = ((size_t)bh * 64 + n) * 256 + e;
        dsA[idx] = ds;
        ds = ds * (1.f - kw[idx]) + ku[idx];
    }
}

__device__ __forceinline__ float block_sum(float v, float* red) {
#pragma unroll
    for (int off = 32; off; off >>= 1) v += __shfl_down(v, off);
    const int wave = threadIdx.x >> 6;
    if ((threadIdx.x & 63) == 0) red[wave] = v;
    __syncthreads();
    float t = red[0] + red[1] + red[2] + red[3];
    __syncthreads();
    return t;
}

// ---------------- o = q*ds + [c<=b]*A*(u - w*ds); fused RMSNorm + bf16 cast (vectorized) ----------------
__global__ __launch_bounds__(256) void o_kernel(const unsigned short* __restrict__ Qb,
                                                const unsigned short* __restrict__ Khi,
                                                const unsigned short* __restrict__ Wb,
                                                const unsigned short* __restrict__ Ub,
                                                const float* __restrict__ dsA,
                                                const float* __restrict__ rmsw,
                                                unsigned short* __restrict__ ob,
                                                unsigned short* __restrict__ ub) {
    const int bl = blockIdx.x;
    const int b = bl >> 12, l = bl & (L_SEQ - 1);
    const int n = l >> 6, cpos = l & 63;
    const int tid = threadIdx.x;
    const int hh = tid >> 6, le = (tid & 63) * 4;
    const int c4 = hh * 256 + le;
    __shared__ float red[4];
    const size_t rowb = (size_t)bl * HID;
    v4f dsv = *(const v4f*)&dsA[(((size_t)b * 4 + hh) * 64 + n) * 256 + le];
    v4us qu = *(const v4us*)&Qb[rowb + c4];
    float qv[4];
#pragma unroll
    for (int i = 0; i < 4; ++i) qv[i] = bu2f(qu[i]);
    const bool doA = (cpos <= b);
    float Aval = 0.f;
    if (doA) {
        v4us kq = *(const v4us*)&Khi[rowb + c4];
        float s = 0.f;
#pragma unroll
        for (int i = 0; i < 4; ++i) s += qv[i] * bu2f(kq[i]);
        Aval = block_sum(s, red);
    }
    v4us uu = *(const v4us*)&Ub[rowb + c4];
    v4us wu4 = *(const v4us*)&Wb[rowb + c4];
    float ss = 0.f, ov[4];
    v4us up;
#pragma unroll
    for (int i = 0; i < 4; ++i) {
        float u = bu2f(uu[i]) - bu2f(wu4[i]) * dsv[i];
        up[i] = f2bu(u);
        float o = qv[i] * dsv[i];
        if (doA) o += Aval * u;
        ov[i] = o;
        ss += o * o;
    }
    *(v4us*)&ub[rowb + c4] = up;
    float tot = block_sum(ss, red);
    float scale = rsqrtf(tot * (1.f / 1024.f) + 1e-5f);
    v4f rw = *(const v4f*)&rmsw[c4];
    v4us op;
#pragma unroll
    for (int i = 0; i < 4; ++i) op[i] = f2bu(ov[i] * scale * rw[i]);
    *(v4us*)&ob[rowb + c4] = op;
}

// ---------------- state S = K^T u'  via MFMA (n-split partials) ----------------
#define SNS 8
__global__ __launch_bounds__(256) void s_mfma_kernel(const unsigned short* __restrict__ Khi,
                                                     const unsigned short* __restrict__ Ub,
                                                     float* __restrict__ Spart) {
    const int bh = blockIdx.x;
    const int b = bh >> 2, h = bh & 3;
    const int dt = blockIdx.y;
    const int et = blockIdx.z & 1;
    const int ns = blockIdx.z >> 1;
    const int tid = threadIdx.x;
    const int wave = tid >> 6, lane = tid & 63;
    const int quad = lane >> 4, l16 = lane & 15;
    const int wm = (wave >> 1) * 64, wn = (wave & 1) * 64;
    __shared__ unsigned short Kt[128 * 40];
    __shared__ unsigned short Ut[128 * 40];
    const int cc = tid >> 3;
    const int dcol = (tid & 7) * 16;
    const size_t rowbase = (size_t)b * 4096 + (size_t)ns * 512;
    const int ck = h * 256 + dt * 128;
    const int ce = h * 256 + et * 128;
    v4f acc[4][4];
#pragma unroll
    for (int a = 0; a < 4; ++a)
#pragma unroll
        for (int c2 = 0; c2 < 4; ++c2) { v4f z = {0.f, 0.f, 0.f, 0.f}; acc[a][c2] = z; }

    for (int kt = 0; kt < 16; ++kt) {
        size_t row = rowbase + kt * 32 + cc;
        v8u k0 = *(const v8u*)(Khi + row * HID + ck + dcol);
        v8u k1 = *(const v8u*)(Khi + row * HID + ck + dcol + 8);
        v8u u0 = *(const v8u*)(Ub + row * HID + ce + dcol);
        v8u u1 = *(const v8u*)(Ub + row * HID + ce + dcol + 8);
        __syncthreads();
#pragma unroll
        for (int j = 0; j < 8; ++j) {
            Kt[(dcol + j) * 40 + cc] = k0[j];
            Kt[(dcol + 8 + j) * 40 + cc] = k1[j];
            Ut[(dcol + j) * 40 + cc] = u0[j];
            Ut[(dcol + 8 + j) * 40 + cc] = u1[j];
        }
        __syncthreads();
        v8s af[4], bf[4];
#pragma unroll
        for (int mt = 0; mt < 4; ++mt) af[mt] = *(const v8s*)&Kt[(wm + mt * 16 + l16) * 40 + quad * 8];
#pragma unroll
        for (int nt = 0; nt < 4; ++nt) bf[nt] = *(const v8s*)&Ut[(wn + nt * 16 + l16) * 40 + quad * 8];
#pragma unroll
        for (int mt = 0; mt < 4; ++mt)
#pragma unroll
            for (int nt = 0; nt < 4; ++nt)
                acc[mt][nt] = __builtin_amdgcn_mfma_f32_16x16x32_bf16(af[mt], bf[nt], acc[mt][nt], 0, 0, 0);
    }
    float* out = Spart + (size_t)ns * (8 * 256 * 256);
#pragma unroll
    for (int mt = 0; mt < 4; ++mt)
#pragma unroll
        for (int nt = 0; nt < 4; ++nt) {
            int row = dt * 128 + wm + mt * 16 + quad * 4;
            int col = et * 128 + wn + nt * 16 + l16;
#pragma unroll
            for (int r = 0; r < 4; ++r)
                out[((size_t)bh * 256 + row + r) * 256 + col] = acc[mt][nt][r];
        }
}

// ---------------- reduce SNS partials -> out1 ----------------
__global__ __launch_bounds__(256) void sreduce_kernel(const float* __restrict__ Spart,
                                                      float* __restrict__ out) {
    int i = blockIdx.x * 256 + threadIdx.x;
    float s = 0.f;
#pragma unroll
    for (int ns = 0; ns < SNS; ++ns) s += Spart[(size_t)ns * (8 * 256 * 256) + i];
    out[i] = s;
}

extern "C" void kernel_launch(void* const* d_in, const int* in_sizes, int n_in,
                              void* d_out, int out_size, void* d_ws, size_t ws_size,
                              hipStream_t stream) {
    const float* x     = (const float*)d_in[0];
    const float* Wq    = (const float*)d_in[1];
    const float* Wk    = (const float*)d_in[2];
    const float* Wv    = (const float*)d_in[3];
    const float* convq = (const float*)d_in[4];
    const float* convk = (const float*)d_in[5];
    const float* convv = (const float*)d_in[6];
    const float* Wbeta = (const float*)d_in[7];
    const float* rmsw  = (const float*)d_in[8];
    const float* Wo    = (const float*)d_in[9];

    // ---- workspace map (aliases documented) ----
    char* ws = (char*)d_ws;
    size_t off = 0;
    auto alloc = [&](size_t bytes) {
        char* p = ws + off;
        off += (bytes + 255) & ~(size_t)255;
        return (void*)p;
    };
    const size_t MM = (size_t)HID * HID;
    unsigned short* xhi   = (unsigned short*)alloc((size_t)BL_TOT * HID * 2);  // later Qm/ob
    unsigned short* Khi   = (unsigned short*)alloc((size_t)BL_TOT * HID * 2);  // conv_k -> s_mfma
    unsigned short* wbQKV = (unsigned short*)alloc(3 * MM * 2);                // [V|K|Q] packed
    unsigned short* wbO   = (unsigned short*)alloc(MM * 2);
    unsigned short* Vhi   = (unsigned short*)alloc((size_t)BL_TOT * HID * 2);
    unsigned short* Wb16  = (unsigned short*)alloc((size_t)BL_TOT * HID * 2);
    unsigned short* Ub16  = (unsigned short*)alloc((size_t)BL_TOT * HID * 2);
    float* Tg    = (float*)alloc((size_t)128 * 4096 * 4);
    float* betaB = (float*)alloc((size_t)BL_TOT * 4 * 4);
    float* kwB   = (float*)alloc((size_t)8 * 64 * 256 * 4);
    float* kuB   = (float*)alloc((size_t)8 * 64 * 256 * 4);
    float* dsA   = (float*)alloc((size_t)8 * 64 * 256 * 4);
    // Gt last: big (8192x3072 f32, merged QKV) if workspace allows, else 8192x1024 sequential.
    const size_t gt_big = (size_t)BL_TOT * 3 * HID * 4;
    const size_t gt_small = (size_t)BL_TOT * HID * 4;
    const bool big = (off + gt_big) <= ws_size;
    float* Gt = (float*)alloc(big ? gt_big : gt_small);

    unsigned short* Qm = xhi;   // xhi dead after (last) x-GEMM
    unsigned short* ob = Qm;    // q dead after o_kernel reads its own row
    float* Spart = Gt;          // Gt dead after conv

    float* out0 = (float*)d_out;
    float* out1 = out0 + (size_t)BL_TOT * HID;
    // d_out as pre-final scratch (validated only after launch):
    unsigned short* Klo = (unsigned short*)out0;            // bytes 0..16.78M
    unsigned short* ubf = (unsigned short*)out0 + 8388608;  // bytes 16.78M..33.55M
    float* Gg = out0 + (size_t)4400000;                     // gram scratch; dead before o_kernel

    dim3 blk(256);
    dim3 ggrid(BL_TOT / 128, HID / 128);

    wcvt_kernel<<<dim3(256, 4), blk, 0, stream>>>(Wv, Wk, Wq, Wo, wbQKV, wbQKV + MM, wbQKV + 2 * MM, wbO);
    beta_kernel<<<BL_TOT, blk, 0, stream>>>(x, Wbeta, betaB, xhi);

    if (big) {
        // one QKV GEMM (N=3072) + one merged conv dispatch
        gemm_mfma<<<dim3(BL_TOT / 128, 3 * HID / 128), blk, 0, stream>>>(xhi, wbQKV, Gt, BL_TOT, 3 * HID, HID);
        conv_kernel<<<dim3(BL_TOT, 3), blk, 0, stream>>>(Gt, 3 * HID, -1, convq, convk, convv,
                                                         Vhi, Khi, Klo, Qm);
        gram_kernel<<<dim3(128, 4), blk, 0, stream>>>(Khi, Klo, Gg);
        trec_kernel<<<128, blk, 0, stream>>>(Gg, betaB, Tg);
    } else {
        // sequential fallback (Gt reused; Q GEMM last so Qm alias of xhi stays safe)
        gemm_mfma<<<ggrid, blk, 0, stream>>>(xhi, wbQKV, Gt, BL_TOT, HID, HID);
        conv_kernel<<<dim3(BL_TOT, 1), blk, 0, stream>>>(Gt, HID, 0, convq, convk, convv, Vhi, Khi, Klo, Qm);
        gemm_mfma<<<ggrid, blk, 0, stream>>>(xhi, wbQKV + MM, Gt, BL_TOT, HID, HID);
        conv_kernel<<<dim3(BL_TOT, 1), blk, 0, stream>>>(Gt, HID, 1, convq, convk, convv, Vhi, Khi, Klo, Qm);
        gram_kernel<<<dim3(128, 4), blk, 0, stream>>>(Khi, Klo, Gg);
        trec_kernel<<<128, blk, 0, stream>>>(Gg, betaB, Tg);
        gemm_mfma<<<ggrid, blk, 0, stream>>>(xhi, wbQKV + 2 * MM, Gt, BL_TOT, HID, HID);
        conv_kernel<<<dim3(BL_TOT, 1), blk, 0, stream>>>(Gt, HID, 2, convq, convk, convv, Vhi, Khi, Klo, Qm);
    }

    // chunked delta rule
    wu_mfma_kernel<<<dim3(128, 4, 2), blk, 0, stream>>>(Tg, Khi, Vhi, betaB, Wb16, Ub16, kwB, kuB);
    scan_kernel<<<8, blk, 0, stream>>>(kwB, kuB, dsA);
    o_kernel<<<BL_TOT, blk, 0, stream>>>(Qm, Khi, Wb16, Ub16, dsA, rmsw, ob, ubf);
    s_mfma_kernel<<<dim3(8, 2, 2 * SNS), blk, 0, stream>>>(Khi, ubf, Spart);
    sreduce_kernel<<<2048, blk, 0, stream>>>(Spart, out1);

    // final projection: o(bf16) @ Wo^T -> f32 out0 (overwrites Klo/ubf scratch)
    gemm_mfma<<<ggrid, blk, 0, stream>>>(ob, wbO, out0, BL_TOT, HID, HID);
}

// Round 4
// 369.897 us; speedup vs baseline: 1.2222x; 1.0622x over previous
//
#include <hip/hip_runtime.h>
#include <hip/hip_bf16.h>

#define L_SEQ 4096
#define HID 1024
#define NH 4
#define DH 256
#define CK 64
#define BL_TOT 8192   // B*L

typedef short v8s __attribute__((ext_vector_type(8)));
typedef unsigned short v8u __attribute__((ext_vector_type(8)));
typedef unsigned short v4us __attribute__((ext_vector_type(4)));
typedef float v4f __attribute__((ext_vector_type(4)));

typedef __attribute__((address_space(1))) const void* as1cv;
typedef __attribute__((address_space(3))) void* as3v;

__device__ __forceinline__ unsigned short f2bu(float f) {
    __hip_bfloat16 h = __float2bfloat16(f);
    return *(unsigned short*)&h;
}
__device__ __forceinline__ float bu2f(unsigned short u) {
    __hip_bfloat16 h = *(__hip_bfloat16*)&u;
    return __bfloat162float(h);
}
__device__ __forceinline__ void storec(float* p, float v) { *p = v; }
__device__ __forceinline__ void storec(unsigned short* p, float v) { *p = f2bu(v); }

// ---------------- all-weights f32 -> bf16 in one dispatch ----------------
__global__ __launch_bounds__(256) void wcvt_kernel(const float* __restrict__ s0, const float* __restrict__ s1,
                                                   const float* __restrict__ s2, const float* __restrict__ s3,
                                                   unsigned short* __restrict__ d0, unsigned short* __restrict__ d1,
                                                   unsigned short* __restrict__ d2, unsigned short* __restrict__ d3) {
    const float* s = blockIdx.y == 0 ? s0 : blockIdx.y == 1 ? s1 : blockIdx.y == 2 ? s2 : s3;
    unsigned short* d = blockIdx.y == 0 ? d0 : blockIdx.y == 1 ? d1 : blockIdx.y == 2 ? d2 : d3;
    int i = blockIdx.x * 256 + threadIdx.x;
    int stride = gridDim.x * 256;
    for (; i < HID * HID; i += stride) d[i] = f2bu(s[i]);
}

// ---------------- MFMA bf16 GEMM: C[M,N] = A[M,K] * B[N,K]^T ----------------
// m97-structure: global_load_lds width=16 direct staging, linear [128][32] LDS tiles.
// Bank-deconflict: 16B-chunk XOR swizzle with (row>>1)&3 applied on BOTH the global
// source address (staging) and the ds_read address (rule: both-sides-or-neither).
// After swizzle a 16-lane fragment read covers 8 bank-groups -> 2-way (free).
template <typename OT>
__global__ __launch_bounds__(256) void gemm_mfma(const unsigned short* __restrict__ Ah,
                                                 const unsigned short* __restrict__ Bh,
                                                 OT* __restrict__ C, int M, int N, int K) {
    __shared__ unsigned short AsH[128 * 32];
    __shared__ unsigned short BsH[128 * 32];
    const int tid = threadIdx.x;
    const int wave = tid >> 6, lane = tid & 63;
    const int quad = lane >> 4, l16 = lane & 15;
    const int m0 = blockIdx.x * 128, n0 = blockIdx.y * 128;
    const int wm = (wave >> 1) * 64, wn = (wave & 1) * 64;

    // staging geometry: one issue = 256 thr * 16B = 4 KB = 64 rows * 64 B
    const int srow = wave * 16 + (lane >> 2);                   // 0..63
    const int scol = (((lane & 3) ^ ((srow >> 1) & 3)) * 8);    // swizzled source chunk (shorts)
    const unsigned short* Ag = Ah + (size_t)(m0 + srow) * K + scol;
    const unsigned short* Bg = Bh + (size_t)(n0 + srow) * K + scol;
    char* lA = (char*)AsH;
    char* lB = (char*)BsH;
    const int lbase = wave * 1024;
    const int qsw = (quad ^ ((l16 >> 1) & 3)) * 8;              // read-side inverse swizzle

    v4f acc[4][4];
#pragma unroll
    for (int a = 0; a < 4; ++a)
#pragma unroll
        for (int b = 0; b < 4; ++b) { v4f z = {0.f, 0.f, 0.f, 0.f}; acc[a][b] = z; }

    for (int k0 = 0; k0 < K; k0 += 32) {
        __syncthreads();  // previous tile's ds_reads complete
        __builtin_amdgcn_global_load_lds((as1cv)(Ag + k0), (as3v)(lA + lbase), 16, 0, 0);
        __builtin_amdgcn_global_load_lds((as1cv)(Ag + (size_t)64 * K + k0), (as3v)(lA + 4096 + lbase), 16, 0, 0);
        __builtin_amdgcn_global_load_lds((as1cv)(Bg + k0), (as3v)(lB + lbase), 16, 0, 0);
        __builtin_amdgcn_global_load_lds((as1cv)(Bg + (size_t)64 * K + k0), (as3v)(lB + 4096 + lbase), 16, 0, 0);
        __syncthreads();  // drains vmcnt -> LDS tile ready
        v8s afh[4], bfh[4];
#pragma unroll
        for (int mt = 0; mt < 4; ++mt) afh[mt] = *(const v8s*)&AsH[(wm + mt * 16 + l16) * 32 + qsw];
#pragma unroll
        for (int nt = 0; nt < 4; ++nt) bfh[nt] = *(const v8s*)&BsH[(wn + nt * 16 + l16) * 32 + qsw];
#pragma unroll
        for (int mt = 0; mt < 4; ++mt)
#pragma unroll
            for (int nt = 0; nt < 4; ++nt)
                acc[mt][nt] = __builtin_amdgcn_mfma_f32_16x16x32_bf16(afh[mt], bfh[nt], acc[mt][nt], 0, 0, 0);
    }
#pragma unroll
    for (int mt = 0; mt < 4; ++mt)
#pragma unroll
        for (int nt = 0; nt < 4; ++nt) {
            int row = m0 + wm + mt * 16 + quad * 4;
            int col = n0 + wn + nt * 16 + l16;
#pragma unroll
            for (int r = 0; r < 4; ++r)
                storec(&C[(size_t)(row + r) * N + col], acc[mt][nt][r]);
        }
}

// ---------------- beta = sigmoid(x @ Wbeta^T); fused x -> bf16 (float4 single-pass) ----------------
__global__ __launch_bounds__(256) void beta_kernel(const float* __restrict__ x,
                                                   const float* __restrict__ Wb,
                                                   float* __restrict__ betaB,
                                                   unsigned short* __restrict__ xh) {
    const int t = blockIdx.x;
    const int tid = threadIdx.x;
    const int wave = tid >> 6, lane = tid & 63;
    const float* xr = x + (size_t)t * HID;
    v4f xv = *(const v4f*)(xr + tid * 4);
    v4us xp;
#pragma unroll
    for (int i = 0; i < 4; ++i) xp[i] = f2bu(xv[i]);
    *(v4us*)&xh[(size_t)t * HID + tid * 4] = xp;
    float s[4];
#pragma unroll
    for (int h = 0; h < 4; ++h) {
        v4f wv = *(const v4f*)(Wb + (size_t)h * HID + tid * 4);
        s[h] = xv[0] * wv[0] + xv[1] * wv[1] + xv[2] * wv[2] + xv[3] * wv[3];
    }
#pragma unroll
    for (int off = 32; off; off >>= 1)
#pragma unroll
        for (int h = 0; h < 4; ++h) s[h] += __shfl_down(s[h], off);
    __shared__ float red[4][4];
    if (lane == 0)
#pragma unroll
        for (int h = 0; h < 4; ++h) red[wave][h] = s[h];
    __syncthreads();
    if (tid < 4) {
        float tot = red[0][tid] + red[1][tid] + red[2][tid] + red[3][tid];
        betaB[(size_t)t * 4 + tid] = 1.f / (1.f + expf(-tot));
    }
}

// ---------------- causal depthwise conv (KS=4) + silu + silu (+ per-head l2norm) ----------------
// Input G is bf16 (GEMM emits bf16). Thread owns 4 contiguous channels; l2norm = wave shuffle.
// path p: 0=V (bf16 out, no norm), 1=K (hi/lo out, norm), 2=Q (bf16 out, norm).
__global__ __launch_bounds__(256) void conv_kernel(const unsigned short* __restrict__ G, int gstride, int pathArg,
                                                   const float* __restrict__ wq, const float* __restrict__ wk,
                                                   const float* __restrict__ wv,
                                                   unsigned short* __restrict__ Vout,
                                                   unsigned short* __restrict__ KhiO, unsigned short* __restrict__ KloO,
                                                   unsigned short* __restrict__ Qout) {
    const int p = pathArg < 0 ? (int)blockIdx.y : pathArg;
    const int yoff = pathArg < 0 ? p * 1024 : 0;
    const float* __restrict__ w = p == 0 ? wv : p == 1 ? wk : wq;
    const int bl = blockIdx.x;
    const int l = bl & (L_SEQ - 1);
    const int tid = threadIdx.x;
    const int lane = tid & 63;
    const int c4 = (tid >> 6) * 256 + lane * 4;  // 4 contiguous channels in head (tid>>6)
    v4f wrow[4];
#pragma unroll
    for (int cc = 0; cc < 4; ++cc) wrow[cc] = *(const v4f*)&w[(c4 + cc) * 4];
    v4f acc = {0.f, 0.f, 0.f, 0.f};
#pragma unroll
    for (int j = 0; j < 4; ++j) {
        int ls = l - 3 + j;
        if (ls >= 0) {
            v4us g = *(const v4us*)&G[(size_t)(bl - 3 + j) * gstride + yoff + c4];
#pragma unroll
            for (int cc = 0; cc < 4; ++cc) acc[cc] += bu2f(g[cc]) * wrow[cc][j];
        }
    }
    float vals[4];
#pragma unroll
    for (int cc = 0; cc < 4; ++cc) {
        float a = acc[cc];
        float s1 = a / (1.f + expf(-a));
        vals[cc] = s1 / (1.f + expf(-s1));
    }
    if (p >= 1) {
        float sq = vals[0] * vals[0] + vals[1] * vals[1] + vals[2] * vals[2] + vals[3] * vals[3];
#pragma unroll
        for (int off = 32; off; off >>= 1) sq += __shfl_xor(sq, off);
        float nrm = 1.f / fmaxf(sqrtf(sq), 1e-12f);
#pragma unroll
        for (int cc = 0; cc < 4; ++cc) vals[cc] *= nrm;
    }
    const size_t ob = (size_t)bl * HID + c4;
    if (p == 1) {
        v4us hv, lv;
#pragma unroll
        for (int cc = 0; cc < 4; ++cc) {
            unsigned short h = f2bu(vals[cc]);
            hv[cc] = h;
            lv[cc] = f2bu(vals[cc] - bu2f(h));
        }
        *(v4us*)&KhiO[ob] = hv;
        *(v4us*)&KloO[ob] = lv;
    } else {
        unsigned short* O = p == 0 ? Vout : Qout;
        v4us hv;
#pragma unroll
        for (int cc = 0; cc < 4; ++cc) hv[cc] = f2bu(vals[cc]);
        *(v4us*)&O[ob] = hv;
    }
}

// ---------------- per-chunk per-head gram: G_h = K_h * K_h^T (split-bf16 MFMA) ----------------
__global__ __launch_bounds__(256) void gram_kernel(const unsigned short* __restrict__ Khi,
                                                   const unsigned short* __restrict__ Klo,
                                                   float* __restrict__ Gg) {
    const int chunk = blockIdx.x;
    const int h = blockIdx.y;
    const int tid = threadIdx.x;
    const int wave = tid >> 6, lane = tid & 63;
    const int quad = lane >> 4, l16 = lane & 15;
    __shared__ unsigned short Hs[64 * 264];
    __shared__ unsigned short Ls[64 * 264];
    const int l0 = chunk * 64;
    const int cb = h * 256;
#pragma unroll
    for (int p = 0; p < 8; ++p) {
        int row = p * 8 + (tid >> 5);
        int col = (tid & 31) * 8;
        v8u hv = *(const v8u*)(Khi + (size_t)(l0 + row) * HID + cb + col);
        v8u lv = *(const v8u*)(Klo + (size_t)(l0 + row) * HID + cb + col);
        *(v8u*)&Hs[row * 264 + col] = hv;
        *(v8u*)&Ls[row * 264 + col] = lv;
    }
    __syncthreads();
    const int wm = wave * 16;
    v4f acc[4];
#pragma unroll
    for (int nt = 0; nt < 4; ++nt) { v4f z = {0.f, 0.f, 0.f, 0.f}; acc[nt] = z; }
#pragma unroll
    for (int ks = 0; ks < 8; ++ks) {
        v8s ah = *(const v8s*)&Hs[(wm + l16) * 264 + ks * 32 + quad * 8];
        v8s al = *(const v8s*)&Ls[(wm + l16) * 264 + ks * 32 + quad * 8];
#pragma unroll
        for (int nt = 0; nt < 4; ++nt) {
            v8s bh = *(const v8s*)&Hs[(nt * 16 + l16) * 264 + ks * 32 + quad * 8];
            v8s bl = *(const v8s*)&Ls[(nt * 16 + l16) * 264 + ks * 32 + quad * 8];
            acc[nt] = __builtin_amdgcn_mfma_f32_16x16x32_bf16(ah, bh, acc[nt], 0, 0, 0);
            acc[nt] = __builtin_amdgcn_mfma_f32_16x16x32_bf16(ah, bl, acc[nt], 0, 0, 0);
            acc[nt] = __builtin_amdgcn_mfma_f32_16x16x32_bf16(al, bh, acc[nt], 0, 0, 0);
        }
    }
    float* og = Gg + ((size_t)chunk * 4 + h) * 4096;
#pragma unroll
    for (int nt = 0; nt < 4; ++nt)
#pragma unroll
        for (int r = 0; r < 4; ++r)
            og[(wm + quad * 4 + r) * 64 + nt * 16 + l16] = acc[nt][r];
}

// ---------------- T recurrence per chunk via nilpotent doubling + MFMA ----------------
// T_final = 3*(I-A)^{-1} - 2I, A = -tril(beta*gram, -1); (I-A)^{-1} = prod (I + A^(2^k)).
__global__ __launch_bounds__(256) void trec_kernel(const float* __restrict__ Gg,
                                                   const float* __restrict__ betaB,
                                                   float* __restrict__ Tg) {
    const int chunk = blockIdx.x;
    const int tid = threadIdx.x;
    const int wave = tid >> 6, lane = tid & 63;
    const int quad = lane >> 4, l16 = lane & 15;
    const int wm = wave * 16;
    __shared__ unsigned short BhR[64 * 72], BlR[64 * 72];  // B rows   [i][j]
    __shared__ unsigned short BhT[64 * 72], BlT[64 * 72];  // B^T rows [j][i]
    __shared__ unsigned short PhR[64 * 72], PlR[64 * 72];  // P rows   [i][j]
    __shared__ float Pf[64 * 73];                          // P master copy (f32)
    __shared__ float betS[256];
    betS[tid] = betaB[(size_t)chunk * 256 + tid];
    __syncthreads();
    const float* gg = Gg + (size_t)chunk * 4 * 4096;
#pragma unroll
    for (int s = 0; s < 16; ++s) {
        int idx = tid + 256 * s;
        int i = idx >> 6, j = idx & 63;
        float a = 0.f;
        if (i > j) {
            a = -(betS[i * 4 + 0] * gg[idx] + betS[i * 4 + 1] * gg[4096 + idx] +
                  betS[i * 4 + 2] * gg[2 * 4096 + idx] + betS[i * 4 + 3] * gg[3 * 4096 + idx]);
        }
        unsigned short ah = f2bu(a);
        unsigned short al = f2bu(a - bu2f(ah));
        BhR[i * 72 + j] = ah;
        BlR[i * 72 + j] = al;
        BhT[j * 72 + i] = ah;
        BlT[j * 72 + i] = al;
        float p = (i == j) ? 1.f : 0.f;
        Pf[i * 73 + j] = p;
        PhR[i * 72 + j] = f2bu(p);
        PlR[i * 72 + j] = 0;
    }
    __syncthreads();

    for (int st = 0; st < 6; ++st) {
        v8s aBh[2], aBl[2], aPh[2], aPl[2];
        v8s bTh[2][4], bTl[2][4];
#pragma unroll
        for (int kk = 0; kk < 2; ++kk) {
            aBh[kk] = *(const v8s*)&BhR[(wm + l16) * 72 + kk * 32 + quad * 8];
            aBl[kk] = *(const v8s*)&BlR[(wm + l16) * 72 + kk * 32 + quad * 8];
            aPh[kk] = *(const v8s*)&PhR[(wm + l16) * 72 + kk * 32 + quad * 8];
            aPl[kk] = *(const v8s*)&PlR[(wm + l16) * 72 + kk * 32 + quad * 8];
#pragma unroll
            for (int nt = 0; nt < 4; ++nt) {
                bTh[kk][nt] = *(const v8s*)&BhT[(nt * 16 + l16) * 72 + kk * 32 + quad * 8];
                bTl[kk][nt] = *(const v8s*)&BlT[(nt * 16 + l16) * 72 + kk * 32 + quad * 8];
            }
        }
        v4f accP[4], accB[4];
#pragma unroll
        for (int nt = 0; nt < 4; ++nt) {
#pragma unroll
            for (int r = 0; r < 4; ++r)
                accP[nt][r] = Pf[(wm + quad * 4 + r) * 73 + nt * 16 + l16];
            v4f z = {0.f, 0.f, 0.f, 0.f};
            accB[nt] = z;
        }
        __syncthreads();  // all reads done before anyone writes
#pragma unroll
        for (int kk = 0; kk < 2; ++kk)
#pragma unroll
            for (int nt = 0; nt < 4; ++nt) {
                accP[nt] = __builtin_amdgcn_mfma_f32_16x16x32_bf16(aPh[kk], bTh[kk][nt], accP[nt], 0, 0, 0);
                accP[nt] = __builtin_amdgcn_mfma_f32_16x16x32_bf16(aPh[kk], bTl[kk][nt], accP[nt], 0, 0, 0);
                accP[nt] = __builtin_amdgcn_mfma_f32_16x16x32_bf16(aPl[kk], bTh[kk][nt], accP[nt], 0, 0, 0);
            }
        if (st < 5) {
#pragma unroll
            for (int kk = 0; kk < 2; ++kk)
#pragma unroll
                for (int nt = 0; nt < 4; ++nt) {
                    accB[nt] = __builtin_amdgcn_mfma_f32_16x16x32_bf16(aBh[kk], bTh[kk][nt], accB[nt], 0, 0, 0);
                    accB[nt] = __builtin_amdgcn_mfma_f32_16x16x32_bf16(aBh[kk], bTl[kk][nt], accB[nt], 0, 0, 0);
                    accB[nt] = __builtin_amdgcn_mfma_f32_16x16x32_bf16(aBl[kk], bTh[kk][nt], accB[nt], 0, 0, 0);
                }
        }
#pragma unroll
        for (int nt = 0; nt < 4; ++nt)
#pragma unroll
            for (int r = 0; r < 4; ++r) {
                int row = wm + quad * 4 + r;
                int col = nt * 16 + l16;
                float pv = accP[nt][r];
                Pf[row * 73 + col] = pv;
                unsigned short ph = f2bu(pv);
                PhR[row * 72 + col] = ph;
                PlR[row * 72 + col] = f2bu(pv - bu2f(ph));
                if (st < 5) {
                    float bv = accB[nt][r];
                    unsigned short bh2 = f2bu(bv);
                    unsigned short bl2 = f2bu(bv - bu2f(bh2));
                    BhR[row * 72 + col] = bh2;
                    BlR[row * 72 + col] = bl2;
                    BhT[col * 72 + row] = bh2;
                    BlT[col * 72 + row] = bl2;
                }
            }
        __syncthreads();
    }
#pragma unroll
    for (int s = 0; s < 16; ++s) {
        int idx = tid + 256 * s;
        int i = idx >> 6, j = idx & 63;
        float t = (i == j) ? 1.f : 3.f * Pf[i * 73 + j];
        Tg[(size_t)chunk * 4096 + idx] = t;
    }
}

// ---------------- W = T'·K, U = T'·V via MFMA (T' = T·diag(beta)); fused kw/ku ----------------
__global__ __launch_bounds__(256) void wu_mfma_kernel(const float* __restrict__ Tg,
                                                      const unsigned short* __restrict__ Khi,
                                                      const unsigned short* __restrict__ Vhi,
                                                      const float* __restrict__ betaB,
                                                      unsigned short* __restrict__ Wb,
                                                      unsigned short* __restrict__ Ub,
                                                      float* __restrict__ kw, float* __restrict__ ku) {
    const int chunk = blockIdx.x;  // 128
    const int h = blockIdx.y;      // 4
    const int half = blockIdx.z;   // 2
    const int tid = threadIdx.x;
    const int wave = tid >> 6, lane = tid & 63;
    const int quad = lane >> 4, l16 = lane & 15;
    const size_t l0 = (size_t)chunk * 64;
    const int f0 = h * 256 + half * 128;
    __shared__ unsigned short Th[64 * 72], Tl[64 * 72];
    __shared__ unsigned short KT[128 * 72], VT[128 * 72];
    __shared__ float betS[64];
    if (tid < 64) betS[tid] = betaB[(l0 + tid) * 4 + h];
    __syncthreads();
#pragma unroll
    for (int s = 0; s < 16; ++s) {
        int idx = tid + 256 * s;
        int c = idx >> 6, j = idx & 63;
        float v = Tg[(size_t)chunk * 4096 + idx] * betS[j];
        unsigned short hv = f2bu(v);
        Th[c * 72 + j] = hv;
        Tl[c * 72 + j] = f2bu(v - bu2f(hv));
    }
#pragma unroll
    for (int pass = 0; pass < 4; ++pass) {
        int j = pass * 16 + (tid >> 4);
        int fc = (tid & 15) * 8;
        v8u kv = *(const v8u*)(Khi + (l0 + j) * HID + f0 + fc);
        v8u vv = *(const v8u*)(Vhi + (l0 + j) * HID + f0 + fc);
#pragma unroll
        for (int i = 0; i < 8; ++i) {
            KT[(fc + i) * 72 + j] = kv[i];
            VT[(fc + i) * 72 + j] = vv[i];
        }
    }
    __syncthreads();

    const int nf = wave * 32;
    const int bb = chunk >> 6, nn = chunk & 63;
    const size_t obase = (((size_t)bb * 4 + h) * 64 + nn) * 256 + half * 128;

#pragma unroll
    for (int phase = 0; phase < 2; ++phase) {
        const unsigned short* BT = phase ? VT : KT;
        v4f acc[4][2];
#pragma unroll
        for (int mt = 0; mt < 4; ++mt)
#pragma unroll
            for (int nt = 0; nt < 2; ++nt) { v4f z = {0.f, 0.f, 0.f, 0.f}; acc[mt][nt] = z; }
#pragma unroll
        for (int k0 = 0; k0 < 64; k0 += 32) {
            v8s ah[4], al[4], bf[2];
#pragma unroll
            for (int mt = 0; mt < 4; ++mt) {
                ah[mt] = *(const v8s*)&Th[(mt * 16 + l16) * 72 + k0 + quad * 8];
                al[mt] = *(const v8s*)&Tl[(mt * 16 + l16) * 72 + k0 + quad * 8];
            }
#pragma unroll
            for (int nt = 0; nt < 2; ++nt)
                bf[nt] = *(const v8s*)&BT[(nf + nt * 16 + l16) * 72 + k0 + quad * 8];
#pragma unroll
            for (int mt = 0; mt < 4; ++mt)
#pragma unroll
                for (int nt = 0; nt < 2; ++nt) {
                    acc[mt][nt] = __builtin_amdgcn_mfma_f32_16x16x32_bf16(ah[mt], bf[nt], acc[mt][nt], 0, 0, 0);
                    acc[mt][nt] = __builtin_amdgcn_mfma_f32_16x16x32_bf16(al[mt], bf[nt], acc[mt][nt], 0, 0, 0);
                }
        }
        unsigned short* Out = phase ? Ub : Wb;
        float* kk = phase ? ku : kw;
#pragma unroll
        for (int nt = 0; nt < 2; ++nt) {
            const int fl = nf + nt * 16 + l16;
            float dot = 0.f;
#pragma unroll
            for (int mt = 0; mt < 4; ++mt)
#pragma unroll
                for (int r = 0; r < 4; ++r) {
                    const int c = mt * 16 + quad * 4 + r;
                    float wv = acc[mt][nt][r];
                    Out[(l0 + c) * HID + f0 + fl] = f2bu(wv);
                    dot += bu2f(KT[fl * 72 + c]) * wv;
                }
            dot += __shfl_xor(dot, 16);
            dot += __shfl_xor(dot, 32);
            if (quad == 0) kk[obase + fl] = dot;
        }
    }
}

// ---------------- diagonal scan over chunks ----------------
__global__ __launch_bounds__(256) void scan_kernel(const float* __restrict__ kw,
                                                   const float* __restrict__ ku,
                                                   float* __restrict__ dsA) {
    const int bh = blockIdx.x;
    const int e = threadIdx.x;
    float ds = 0.f;
    for (int n = 0; n < 64; ++n) {
        size_t idx = ((size_t)bh * 64 + n) * 256 + e;
        dsA[idx] = ds;
        ds = ds * (1.f - kw[idx]) + ku[idx];
    }
}

__device__ __forceinline__ float block_sum(float v, float* red) {
#pragma unroll
    for (int off = 32; off; off >>= 1) v += __shfl_down(v, off);
    const int wave = threadIdx.x >> 6;
    if ((threadIdx.x & 63) == 0) red[wave] = v;
    __syncthreads();
    float t = red[0] + red[1] + red[2] + red[3];
    __syncthreads();
    return t;
}

// ---------------- o = q*ds + [c<=b]*A*(u - w*ds); fused RMSNorm + bf16 cast (vectorized) ----------------
__global__ __launch_bounds__(256) void o_kernel(const unsigned short* __restrict__ Qb,
                                                const unsigned short* __restrict__ Khi,
                                                const unsigned short* __restrict__ Wb,
                                                const unsigned short* __restrict__ Ub,
                                                const float* __restrict__ dsA,
                                                const float* __restrict__ rmsw,
                                                unsigned short* __restrict__ ob,
                                                unsigned short* __restrict__ ub) {
    const int bl = blockIdx.x;
    const int b = bl >> 12, l = bl & (L_SEQ - 1);
    const int n = l >> 6, cpos = l & 63;
    const int tid = threadIdx.x;
    const int hh = tid >> 6, le = (tid & 63) * 4;
    const int c4 = hh * 256 + le;
    __shared__ float red[4];
    const size_t rowb = (size_t)bl * HID;
    v4f dsv = *(const v4f*)&dsA[(((size_t)b * 4 + hh) * 64 + n) * 256 + le];
    v4us qu = *(const v4us*)&Qb[rowb + c4];
    float qv[4];
#pragma unroll
    for (int i = 0; i < 4; ++i) qv[i] = bu2f(qu[i]);
    const bool doA = (cpos <= b);
    float Aval = 0.f;
    if (doA) {
        v4us kq = *(const v4us*)&Khi[rowb + c4];
        float s = 0.f;
#pragma unroll
        for (int i = 0; i < 4; ++i) s += qv[i] * bu2f(kq[i]);
        Aval = block_sum(s, red);
    }
    v4us uu = *(const v4us*)&Ub[rowb + c4];
    v4us wu4 = *(const v4us*)&Wb[rowb + c4];
    float ss = 0.f, ov[4];
    v4us up;
#pragma unroll
    for (int i = 0; i < 4; ++i) {
        float u = bu2f(uu[i]) - bu2f(wu4[i]) * dsv[i];
        up[i] = f2bu(u);
        float o = qv[i] * dsv[i];
        if (doA) o += Aval * u;
        ov[i] = o;
        ss += o * o;
    }
    *(v4us*)&ub[rowb + c4] = up;
    float tot = block_sum(ss, red);
    float scale = rsqrtf(tot * (1.f / 1024.f) + 1e-5f);
    v4f rw = *(const v4f*)&rmsw[c4];
    v4us op;
#pragma unroll
    for (int i = 0; i < 4; ++i) op[i] = f2bu(ov[i] * scale * rw[i]);
    *(v4us*)&ob[rowb + c4] = op;
}

// ---------------- state S = K^T u'  via MFMA (n-split partials) ----------------
#define SNS 8
__global__ __launch_bounds__(256) void s_mfma_kernel(const unsigned short* __restrict__ Khi,
                                                     const unsigned short* __restrict__ Ub,
                                                     float* __restrict__ Spart) {
    const int bh = blockIdx.x;
    const int b = bh >> 2, h = bh & 3;
    const int dt = blockIdx.y;
    const int et = blockIdx.z & 1;
    const int ns = blockIdx.z >> 1;
    const int tid = threadIdx.x;
    const int wave = tid >> 6, lane = tid & 63;
    const int quad = lane >> 4, l16 = lane & 15;
    const int wm = (wave >> 1) * 64, wn = (wave & 1) * 64;
    __shared__ unsigned short Kt[128 * 40];
    __shared__ unsigned short Ut[128 * 40];
    const int cc = tid >> 3;
    const int dcol = (tid & 7) * 16;
    const size_t rowbase = (size_t)b * 4096 + (size_t)ns * 512;
    const int ck = h * 256 + dt * 128;
    const int ce = h * 256 + et * 128;
    v4f acc[4][4];
#pragma unroll
    for (int a = 0; a < 4; ++a)
#pragma unroll
        for (int c2 = 0; c2 < 4; ++c2) { v4f z = {0.f, 0.f, 0.f, 0.f}; acc[a][c2] = z; }

    for (int kt = 0; kt < 16; ++kt) {
        size_t row = rowbase + kt * 32 + cc;
        v8u k0 = *(const v8u*)(Khi + row * HID + ck + dcol);
        v8u k1 = *(const v8u*)(Khi + row * HID + ck + dcol + 8);
        v8u u0 = *(const v8u*)(Ub + row * HID + ce + dcol);
        v8u u1 = *(const v8u*)(Ub + row * HID + ce + dcol + 8);
        __syncthreads();
#pragma unroll
        for (int j = 0; j < 8; ++j) {
            Kt[(dcol + j) * 40 + cc] = k0[j];
            Kt[(dcol + 8 + j) * 40 + cc] = k1[j];
            Ut[(dcol + j) * 40 + cc] = u0[j];
            Ut[(dcol + 8 + j) * 40 + cc] = u1[j];
        }
        __syncthreads();
        v8s af[4], bf[4];
#pragma unroll
        for (int mt = 0; mt < 4; ++mt) af[mt] = *(const v8s*)&Kt[(wm + mt * 16 + l16) * 40 + quad * 8];
#pragma unroll
        for (int nt = 0; nt < 4; ++nt) bf[nt] = *(const v8s*)&Ut[(wn + nt * 16 + l16) * 40 + quad * 8];
#pragma unroll
        for (int mt = 0; mt < 4; ++mt)
#pragma unroll
            for (int nt = 0; nt < 4; ++nt)
                acc[mt][nt] = __builtin_amdgcn_mfma_f32_16x16x32_bf16(af[mt], bf[nt], acc[mt][nt], 0, 0, 0);
    }
    float* out = Spart + (size_t)ns * (8 * 256 * 256);
#pragma unroll
    for (int mt = 0; mt < 4; ++mt)
#pragma unroll
        for (int nt = 0; nt < 4; ++nt) {
            int row = dt * 128 + wm + mt * 16 + quad * 4;
            int col = et * 128 + wn + nt * 16 + l16;
#pragma unroll
            for (int r = 0; r < 4; ++r)
                out[((size_t)bh * 256 + row + r) * 256 + col] = acc[mt][nt][r];
        }
}

// ---------------- reduce SNS partials -> out1 ----------------
__global__ __launch_bounds__(256) void sreduce_kernel(const float* __restrict__ Spart,
                                                      float* __restrict__ out) {
    int i = blockIdx.x * 256 + threadIdx.x;
    float s = 0.f;
#pragma unroll
    for (int ns = 0; ns < SNS; ++ns) s += Spart[(size_t)ns * (8 * 256 * 256) + i];
    out[i] = s;
}

extern "C" void kernel_launch(void* const* d_in, const int* in_sizes, int n_in,
                              void* d_out, int out_size, void* d_ws, size_t ws_size,
                              hipStream_t stream) {
    const float* x     = (const float*)d_in[0];
    const float* Wq    = (const float*)d_in[1];
    const float* Wk    = (const float*)d_in[2];
    const float* Wv    = (const float*)d_in[3];
    const float* convq = (const float*)d_in[4];
    const float* convk = (const float*)d_in[5];
    const float* convv = (const float*)d_in[6];
    const float* Wbeta = (const float*)d_in[7];
    const float* rmsw  = (const float*)d_in[8];
    const float* Wo    = (const float*)d_in[9];

    // ---- workspace map (aliases documented) ----
    char* ws = (char*)d_ws;
    size_t off = 0;
    auto alloc = [&](size_t bytes) {
        char* p = ws + off;
        off += (bytes + 255) & ~(size_t)255;
        return (void*)p;
    };
    const size_t MM = (size_t)HID * HID;
    unsigned short* xhi   = (unsigned short*)alloc((size_t)BL_TOT * HID * 2);  // later Qm/ob
    unsigned short* Khi   = (unsigned short*)alloc((size_t)BL_TOT * HID * 2);  // conv_k -> s_mfma
    unsigned short* wbQKV = (unsigned short*)alloc(3 * MM * 2);                // [V|K|Q] packed
    unsigned short* wbO   = (unsigned short*)alloc(MM * 2);
    unsigned short* Vhi   = (unsigned short*)alloc((size_t)BL_TOT * HID * 2);
    unsigned short* Wb16  = (unsigned short*)alloc((size_t)BL_TOT * HID * 2);
    unsigned short* Ub16  = (unsigned short*)alloc((size_t)BL_TOT * HID * 2);
    float* Tg    = (float*)alloc((size_t)128 * 4096 * 4);
    float* betaB = (float*)alloc((size_t)BL_TOT * 4 * 4);
    float* kwB   = (float*)alloc((size_t)8 * 64 * 256 * 4);
    float* kuB   = (float*)alloc((size_t)8 * 64 * 256 * 4);
    float* dsA   = (float*)alloc((size_t)8 * 64 * 256 * 4);
    // Gt last: bf16 GEMM output. big = 8192x3072 (merged QKV) if workspace allows.
    const size_t gt_big = (size_t)BL_TOT * 3 * HID * 2;
    const size_t gt_small = (size_t)BL_TOT * HID * 2;
    // Spart (16 MB f32) aliases Gt; ensure allocation covers it in either path.
    const size_t spart_bytes = (size_t)SNS * 8 * 256 * 256 * 4;
    const bool big = (off + (gt_big > spart_bytes ? gt_big : spart_bytes)) <= ws_size;
    unsigned short* Gt = (unsigned short*)alloc(big ? (gt_big > spart_bytes ? gt_big : spart_bytes)
                                                    : (gt_small > spart_bytes ? gt_small : spart_bytes));

    unsigned short* Qm = xhi;   // xhi dead after (last) x-GEMM
    unsigned short* ob = Qm;    // q dead after o_kernel reads its own row
    float* Spart = (float*)Gt;  // Gt dead after conv

    float* out0 = (float*)d_out;
    float* out1 = out0 + (size_t)BL_TOT * HID;
    // d_out as pre-final scratch (validated only after launch):
    unsigned short* Klo = (unsigned short*)out0;            // bytes 0..16.78M
    unsigned short* ubf = (unsigned short*)out0 + 8388608;  // bytes 16.78M..33.55M
    float* Gg = out0 + (size_t)4400000;                     // gram scratch; dead before o_kernel

    dim3 blk(256);
    dim3 ggrid(BL_TOT / 128, HID / 128);

    wcvt_kernel<<<dim3(256, 4), blk, 0, stream>>>(Wv, Wk, Wq, Wo, wbQKV, wbQKV + MM, wbQKV + 2 * MM, wbO);
    beta_kernel<<<BL_TOT, blk, 0, stream>>>(x, Wbeta, betaB, xhi);

    if (big) {
        // one QKV GEMM (N=3072, bf16 out) + one merged conv dispatch
        gemm_mfma<unsigned short><<<dim3(BL_TOT / 128, 3 * HID / 128), blk, 0, stream>>>(
            xhi, wbQKV, Gt, BL_TOT, 3 * HID, HID);
        conv_kernel<<<dim3(BL_TOT, 3), blk, 0, stream>>>(Gt, 3 * HID, -1, convq, convk, convv,
                                                         Vhi, Khi, Klo, Qm);
        gram_kernel<<<dim3(128, 4), blk, 0, stream>>>(Khi, Klo, Gg);
        trec_kernel<<<128, blk, 0, stream>>>(Gg, betaB, Tg);
    } else {
        // sequential fallback (Gt reused; Q GEMM last so Qm alias of xhi stays safe)
        gemm_mfma<unsigned short><<<ggrid, blk, 0, stream>>>(xhi, wbQKV, Gt, BL_TOT, HID, HID);
        conv_kernel<<<dim3(BL_TOT, 1), blk, 0, stream>>>(Gt, HID, 0, convq, convk, convv, Vhi, Khi, Klo, Qm);
        gemm_mfma<unsigned short><<<ggrid, blk, 0, stream>>>(xhi, wbQKV + MM, Gt, BL_TOT, HID, HID);
        conv_kernel<<<dim3(BL_TOT, 1), blk, 0, stream>>>(Gt, HID, 1, convq, convk, convv, Vhi, Khi, Klo, Qm);
        gram_kernel<<<dim3(128, 4), blk, 0, stream>>>(Khi, Klo, Gg);
        trec_kernel<<<128, blk, 0, stream>>>(Gg, betaB, Tg);
        gemm_mfma<unsigned short><<<ggrid, blk, 0, stream>>>(xhi, wbQKV + 2 * MM, Gt, BL_TOT, HID, HID);
        conv_kernel<<<dim3(BL_TOT, 1), blk, 0, stream>>>(Gt, HID, 2, convq, convk, convv, Vhi, Khi, Klo, Qm);
    }

    // chunked delta rule
    wu_mfma_kernel<<<dim3(128, 4, 2), blk, 0, stream>>>(Tg, Khi, Vhi, betaB, Wb16, Ub16, kwB, kuB);
    scan_kernel<<<8, blk, 0, stream>>>(kwB, kuB, dsA);
    o_kernel<<<BL_TOT, blk, 0, stream>>>(Qm, Khi, Wb16, Ub16, dsA, rmsw, ob, ubf);
    s_mfma_kernel<<<dim3(8, 2, 2 * SNS), blk, 0, stream>>>(Khi, ubf, Spart);
    sreduce_kernel<<<2048, blk, 0, stream>>>(Spart, out1);

    // final projection: o(bf16) @ Wo^T -> f32 out0 (overwrites Klo/ubf scratch)
    gemm_mfma<float><<<ggrid, blk, 0, stream>>>(ob, wbO, out0, BL_TOT, HID, HID);
}

// Round 5
// 366.446 us; speedup vs baseline: 1.2337x; 1.0094x over previous
//
#include <hip/hip_runtime.h>
#include <hip/hip_bf16.h>

#define L_SEQ 4096
#define HID 1024
#define NH 4
#define DH 256
#define CK 64
#define BL_TOT 8192   // B*L

typedef short v8s __attribute__((ext_vector_type(8)));
typedef unsigned short v8u __attribute__((ext_vector_type(8)));
typedef unsigned short v4us __attribute__((ext_vector_type(4)));
typedef float v4f __attribute__((ext_vector_type(4)));

typedef __attribute__((address_space(1))) const void* as1cv;
typedef __attribute__((address_space(3))) void* as3v;

__device__ __forceinline__ unsigned short f2bu(float f) {
    __hip_bfloat16 h = __float2bfloat16(f);
    return *(unsigned short*)&h;
}
__device__ __forceinline__ float bu2f(unsigned short u) {
    __hip_bfloat16 h = *(__hip_bfloat16*)&u;
    return __bfloat162float(h);
}
__device__ __forceinline__ void storec(float* p, float v) { *p = v; }
__device__ __forceinline__ void storec(unsigned short* p, float v) { *p = f2bu(v); }

// ---------------- all-weights f32 -> bf16 in one dispatch ----------------
__global__ __launch_bounds__(256) void wcvt_kernel(const float* __restrict__ s0, const float* __restrict__ s1,
                                                   const float* __restrict__ s2, const float* __restrict__ s3,
                                                   unsigned short* __restrict__ d0, unsigned short* __restrict__ d1,
                                                   unsigned short* __restrict__ d2, unsigned short* __restrict__ d3) {
    const float* s = blockIdx.y == 0 ? s0 : blockIdx.y == 1 ? s1 : blockIdx.y == 2 ? s2 : s3;
    unsigned short* d = blockIdx.y == 0 ? d0 : blockIdx.y == 1 ? d1 : blockIdx.y == 2 ? d2 : d3;
    int i = blockIdx.x * 256 + threadIdx.x;
    int stride = gridDim.x * 256;
    for (; i < HID * HID; i += stride) d[i] = f2bu(s[i]);
}

// ---------------- MFMA bf16 GEMM: C[M,N] = A[M,K] * B[N,K]^T ----------------
// 128^2 tile, BK=64 (halves barrier-drain events vs BK=32), global_load_lds width=16.
// Both-sides XOR swizzle for 128-B LDS rows: source chunk (lane&7)^(lane>>3),
// read chunk (quad+4kk)^(row&7) -> wave read is 2-way (free). LDS 2x16 KB.
template <typename OT>
__global__ __launch_bounds__(256) void gemm_mfma(const unsigned short* __restrict__ Ah,
                                                 const unsigned short* __restrict__ Bh,
                                                 OT* __restrict__ C, int M, int N, int K) {
    __shared__ unsigned short AsH[128 * 64];
    __shared__ unsigned short BsH[128 * 64];
    const int tid = threadIdx.x;
    const int wave = tid >> 6, lane = tid & 63;
    const int quad = lane >> 4, l16 = lane & 15;
    const int m0 = blockIdx.x * 128, n0 = blockIdx.y * 128;
    const int wm = (wave >> 1) * 64, wn = (wave & 1) * 64;

    // staging: one issue = 256 thr * 16 B = 4 KB = 32 rows * 128 B; 4 issues per 128-row tile
    const int srow = wave * 8 + (lane >> 3);              // 0..31 within issue stripe
    const int scol = (((lane & 7) ^ (lane >> 3)) * 8);    // pre-swizzled source chunk (shorts)
    const unsigned short* Ag = Ah + (size_t)(m0 + srow) * K + scol;
    const unsigned short* Bg = Bh + (size_t)(n0 + srow) * K + scol;
    char* lA = (char*)AsH;
    char* lB = (char*)BsH;
    const int lbase = wave * 1024;

    v4f acc[4][4];
#pragma unroll
    for (int a = 0; a < 4; ++a)
#pragma unroll
        for (int b = 0; b < 4; ++b) { v4f z = {0.f, 0.f, 0.f, 0.f}; acc[a][b] = z; }

    for (int k0 = 0; k0 < K; k0 += 64) {
        __syncthreads();  // previous tile's ds_reads complete
#pragma unroll
        for (int i = 0; i < 4; ++i)
            __builtin_amdgcn_global_load_lds((as1cv)(Ag + (size_t)(i * 32) * K + k0),
                                             (as3v)(lA + i * 4096 + lbase), 16, 0, 0);
#pragma unroll
        for (int i = 0; i < 4; ++i)
            __builtin_amdgcn_global_load_lds((as1cv)(Bg + (size_t)(i * 32) * K + k0),
                                             (as3v)(lB + i * 4096 + lbase), 16, 0, 0);
        __syncthreads();  // drains vmcnt -> LDS tile ready
#pragma unroll
        for (int kk = 0; kk < 2; ++kk) {
            v8s afh[4], bfh[4];
#pragma unroll
            for (int mt = 0; mt < 4; ++mt) {
                const int row = wm + mt * 16 + l16;
                afh[mt] = *(const v8s*)&AsH[row * 64 + (((quad + 4 * kk) ^ (row & 7)) * 8)];
            }
#pragma unroll
            for (int nt = 0; nt < 4; ++nt) {
                const int row = wn + nt * 16 + l16;
                bfh[nt] = *(const v8s*)&BsH[row * 64 + (((quad + 4 * kk) ^ (row & 7)) * 8)];
            }
#pragma unroll
            for (int mt = 0; mt < 4; ++mt)
#pragma unroll
                for (int nt = 0; nt < 4; ++nt)
                    acc[mt][nt] = __builtin_amdgcn_mfma_f32_16x16x32_bf16(afh[mt], bfh[nt], acc[mt][nt], 0, 0, 0);
        }
    }
#pragma unroll
    for (int mt = 0; mt < 4; ++mt)
#pragma unroll
        for (int nt = 0; nt < 4; ++nt) {
            int row = m0 + wm + mt * 16 + quad * 4;
            int col = n0 + wn + nt * 16 + l16;
#pragma unroll
            for (int r = 0; r < 4; ++r)
                storec(&C[(size_t)(row + r) * N + col], acc[mt][nt][r]);
        }
}

// ---------------- beta = sigmoid(x @ Wbeta^T); fused x -> bf16 (wave-per-row) ----------------
__global__ __launch_bounds__(256) void beta_kernel(const float* __restrict__ x,
                                                   const float* __restrict__ Wb,
                                                   float* __restrict__ betaB,
                                                   unsigned short* __restrict__ xh) {
    const int t = blockIdx.x * 4 + (threadIdx.x >> 6);
    const int lane = threadIdx.x & 63;
    const float* xr = x + (size_t)t * HID;
    float s[4] = {0.f, 0.f, 0.f, 0.f};
    v4f xv[4];
#pragma unroll
    for (int c = 0; c < 4; ++c) {
        const int i4 = c * 256 + lane * 4;
        xv[c] = *(const v4f*)(xr + i4);
        v4us xp;
#pragma unroll
        for (int i = 0; i < 4; ++i) xp[i] = f2bu(xv[c][i]);
        *(v4us*)&xh[(size_t)t * HID + i4] = xp;
    }
#pragma unroll
    for (int h = 0; h < 4; ++h)
#pragma unroll
        for (int c = 0; c < 4; ++c) {
            v4f wv = *(const v4f*)(Wb + (size_t)h * HID + c * 256 + lane * 4);
            s[h] += xv[c][0] * wv[0] + xv[c][1] * wv[1] + xv[c][2] * wv[2] + xv[c][3] * wv[3];
        }
#pragma unroll
    for (int off = 32; off; off >>= 1)
#pragma unroll
        for (int h = 0; h < 4; ++h) s[h] += __shfl_xor(s[h], off);
    if (lane < 4) betaB[(size_t)t * 4 + lane] = 1.f / (1.f + expf(-s[lane]));
}

// ---------------- causal depthwise conv (KS=4) + silu + silu (+ per-head l2norm) ----------------
// Input G is bf16 (GEMM emits bf16). Thread owns 4 contiguous channels; l2norm = wave shuffle.
// path p: 0=V (bf16 out, no norm), 1=K (hi/lo out, norm), 2=Q (bf16 out, norm).
__global__ __launch_bounds__(256) void conv_kernel(const unsigned short* __restrict__ G, int gstride, int pathArg,
                                                   const float* __restrict__ wq, const float* __restrict__ wk,
                                                   const float* __restrict__ wv,
                                                   unsigned short* __restrict__ Vout,
                                                   unsigned short* __restrict__ KhiO, unsigned short* __restrict__ KloO,
                                                   unsigned short* __restrict__ Qout) {
    const int p = pathArg < 0 ? (int)blockIdx.y : pathArg;
    const int yoff = pathArg < 0 ? p * 1024 : 0;
    const float* __restrict__ w = p == 0 ? wv : p == 1 ? wk : wq;
    const int bl = blockIdx.x;
    const int l = bl & (L_SEQ - 1);
    const int tid = threadIdx.x;
    const int lane = tid & 63;
    const int c4 = (tid >> 6) * 256 + lane * 4;  // 4 contiguous channels in head (tid>>6)
    v4f wrow[4];
#pragma unroll
    for (int cc = 0; cc < 4; ++cc) wrow[cc] = *(const v4f*)&w[(c4 + cc) * 4];
    v4f acc = {0.f, 0.f, 0.f, 0.f};
#pragma unroll
    for (int j = 0; j < 4; ++j) {
        int ls = l - 3 + j;
        if (ls >= 0) {
            v4us g = *(const v4us*)&G[(size_t)(bl - 3 + j) * gstride + yoff + c4];
#pragma unroll
            for (int cc = 0; cc < 4; ++cc) acc[cc] += bu2f(g[cc]) * wrow[cc][j];
        }
    }
    float vals[4];
#pragma unroll
    for (int cc = 0; cc < 4; ++cc) {
        float a = acc[cc];
        float s1 = a / (1.f + expf(-a));
        vals[cc] = s1 / (1.f + expf(-s1));
    }
    if (p >= 1) {
        float sq = vals[0] * vals[0] + vals[1] * vals[1] + vals[2] * vals[2] + vals[3] * vals[3];
#pragma unroll
        for (int off = 32; off; off >>= 1) sq += __shfl_xor(sq, off);
        float nrm = 1.f / fmaxf(sqrtf(sq), 1e-12f);
#pragma unroll
        for (int cc = 0; cc < 4; ++cc) vals[cc] *= nrm;
    }
    const size_t ob = (size_t)bl * HID + c4;
    if (p == 1) {
        v4us hv, lv;
#pragma unroll
        for (int cc = 0; cc < 4; ++cc) {
            unsigned short h = f2bu(vals[cc]);
            hv[cc] = h;
            lv[cc] = f2bu(vals[cc] - bu2f(h));
        }
        *(v4us*)&KhiO[ob] = hv;
        *(v4us*)&KloO[ob] = lv;
    } else {
        unsigned short* O = p == 0 ? Vout : Qout;
        v4us hv;
#pragma unroll
        for (int cc = 0; cc < 4; ++cc) hv[cc] = f2bu(vals[cc]);
        *(v4us*)&O[ob] = hv;
    }
}

// ---------------- per-chunk per-head gram: G_h = K_h * K_h^T (split-bf16 MFMA) ----------------
__global__ __launch_bounds__(256) void gram_kernel(const unsigned short* __restrict__ Khi,
                                                   const unsigned short* __restrict__ Klo,
                                                   float* __restrict__ Gg) {
    const int chunk = blockIdx.x;
    const int h = blockIdx.y;
    const int tid = threadIdx.x;
    const int wave = tid >> 6, lane = tid & 63;
    const int quad = lane >> 4, l16 = lane & 15;
    __shared__ unsigned short Hs[64 * 264];
    __shared__ unsigned short Ls[64 * 264];
    const int l0 = chunk * 64;
    const int cb = h * 256;
#pragma unroll
    for (int p = 0; p < 8; ++p) {
        int row = p * 8 + (tid >> 5);
        int col = (tid & 31) * 8;
        v8u hv = *(const v8u*)(Khi + (size_t)(l0 + row) * HID + cb + col);
        v8u lv = *(const v8u*)(Klo + (size_t)(l0 + row) * HID + cb + col);
        *(v8u*)&Hs[row * 264 + col] = hv;
        *(v8u*)&Ls[row * 264 + col] = lv;
    }
    __syncthreads();
    const int wm = wave * 16;
    v4f acc[4];
#pragma unroll
    for (int nt = 0; nt < 4; ++nt) { v4f z = {0.f, 0.f, 0.f, 0.f}; acc[nt] = z; }
#pragma unroll
    for (int ks = 0; ks < 8; ++ks) {
        v8s ah = *(const v8s*)&Hs[(wm + l16) * 264 + ks * 32 + quad * 8];
        v8s al = *(const v8s*)&Ls[(wm + l16) * 264 + ks * 32 + quad * 8];
#pragma unroll
        for (int nt = 0; nt < 4; ++nt) {
            v8s bh = *(const v8s*)&Hs[(nt * 16 + l16) * 264 + ks * 32 + quad * 8];
            v8s bl = *(const v8s*)&Ls[(nt * 16 + l16) * 264 + ks * 32 + quad * 8];
            acc[nt] = __builtin_amdgcn_mfma_f32_16x16x32_bf16(ah, bh, acc[nt], 0, 0, 0);
            acc[nt] = __builtin_amdgcn_mfma_f32_16x16x32_bf16(ah, bl, acc[nt], 0, 0, 0);
            acc[nt] = __builtin_amdgcn_mfma_f32_16x16x32_bf16(al, bh, acc[nt], 0, 0, 0);
        }
    }
    float* og = Gg + ((size_t)chunk * 4 + h) * 4096;
#pragma unroll
    for (int nt = 0; nt < 4; ++nt)
#pragma unroll
        for (int r = 0; r < 4; ++r)
            og[(wm + quad * 4 + r) * 64 + nt * 16 + l16] = acc[nt][r];
}

// ---------------- T recurrence per chunk via nilpotent doubling + MFMA ----------------
// T_final = 3*(I-A)^{-1} - 2I, A = -tril(beta*gram, -1); (I-A)^{-1} = prod (I + A^(2^k)).
__global__ __launch_bounds__(256) void trec_kernel(const float* __restrict__ Gg,
                                                   const float* __restrict__ betaB,
                                                   float* __restrict__ Tg) {
    const int chunk = blockIdx.x;
    const int tid = threadIdx.x;
    const int wave = tid >> 6, lane = tid & 63;
    const int quad = lane >> 4, l16 = lane & 15;
    const int wm = wave * 16;
    __shared__ unsigned short BhR[64 * 72], BlR[64 * 72];  // B rows   [i][j]
    __shared__ unsigned short BhT[64 * 72], BlT[64 * 72];  // B^T rows [j][i]
    __shared__ unsigned short PhR[64 * 72], PlR[64 * 72];  // P rows   [i][j]
    __shared__ float Pf[64 * 73];                          // P master copy (f32)
    __shared__ float betS[256];
    betS[tid] = betaB[(size_t)chunk * 256 + tid];
    __syncthreads();
    const float* gg = Gg + (size_t)chunk * 4 * 4096;
#pragma unroll
    for (int s = 0; s < 16; ++s) {
        int idx = tid + 256 * s;
        int i = idx >> 6, j = idx & 63;
        float a = 0.f;
        if (i > j) {
            a = -(betS[i * 4 + 0] * gg[idx] + betS[i * 4 + 1] * gg[4096 + idx] +
                  betS[i * 4 + 2] * gg[2 * 4096 + idx] + betS[i * 4 + 3] * gg[3 * 4096 + idx]);
        }
        unsigned short ah = f2bu(a);
        unsigned short al = f2bu(a - bu2f(ah));
        BhR[i * 72 + j] = ah;
        BlR[i * 72 + j] = al;
        BhT[j * 72 + i] = ah;
        BlT[j * 72 + i] = al;
        float p = (i == j) ? 1.f : 0.f;
        Pf[i * 73 + j] = p;
        PhR[i * 72 + j] = f2bu(p);
        PlR[i * 72 + j] = 0;
    }
    __syncthreads();

    for (int st = 0; st < 6; ++st) {
        v8s aBh[2], aBl[2], aPh[2], aPl[2];
        v8s bTh[2][4], bTl[2][4];
#pragma unroll
        for (int kk = 0; kk < 2; ++kk) {
            aBh[kk] = *(const v8s*)&BhR[(wm + l16) * 72 + kk * 32 + quad * 8];
            aBl[kk] = *(const v8s*)&BlR[(wm + l16) * 72 + kk * 32 + quad * 8];
            aPh[kk] = *(const v8s*)&PhR[(wm + l16) * 72 + kk * 32 + quad * 8];
            aPl[kk] = *(const v8s*)&PlR[(wm + l16) * 72 + kk * 32 + quad * 8];
#pragma unroll
            for (int nt = 0; nt < 4; ++nt) {
                bTh[kk][nt] = *(const v8s*)&BhT[(nt * 16 + l16) * 72 + kk * 32 + quad * 8];
                bTl[kk][nt] = *(const v8s*)&BlT[(nt * 16 + l16) * 72 + kk * 32 + quad * 8];
            }
        }
        v4f accP[4], accB[4];
#pragma unroll
        for (int nt = 0; nt < 4; ++nt) {
#pragma unroll
            for (int r = 0; r < 4; ++r)
                accP[nt][r] = Pf[(wm + quad * 4 + r) * 73 + nt * 16 + l16];
            v4f z = {0.f, 0.f, 0.f, 0.f};
            accB[nt] = z;
        }
        __syncthreads();  // all reads done before anyone writes
#pragma unroll
        for (int kk = 0; kk < 2; ++kk)
#pragma unroll
            for (int nt = 0; nt < 4; ++nt) {
                accP[nt] = __builtin_amdgcn_mfma_f32_16x16x32_bf16(aPh[kk], bTh[kk][nt], accP[nt], 0, 0, 0);
                accP[nt] = __builtin_amdgcn_mfma_f32_16x16x32_bf16(aPh[kk], bTl[kk][nt], accP[nt], 0, 0, 0);
                accP[nt] = __builtin_amdgcn_mfma_f32_16x16x32_bf16(aPl[kk], bTh[kk][nt], accP[nt], 0, 0, 0);
            }
        if (st < 5) {
#pragma unroll
            for (int kk = 0; kk < 2; ++kk)
#pragma unroll
                for (int nt = 0; nt < 4; ++nt) {
                    accB[nt] = __builtin_amdgcn_mfma_f32_16x16x32_bf16(aBh[kk], bTh[kk][nt], accB[nt], 0, 0, 0);
                    accB[nt] = __builtin_amdgcn_mfma_f32_16x16x32_bf16(aBh[kk], bTl[kk][nt], accB[nt], 0, 0, 0);
                    accB[nt] = __builtin_amdgcn_mfma_f32_16x16x32_bf16(aBl[kk], bTh[kk][nt], accB[nt], 0, 0, 0);
                }
        }
#pragma unroll
        for (int nt = 0; nt < 4; ++nt)
#pragma unroll
            for (int r = 0; r < 4; ++r) {
                int row = wm + quad * 4 + r;
                int col = nt * 16 + l16;
                float pv = accP[nt][r];
                Pf[row * 73 + col] = pv;
                unsigned short ph = f2bu(pv);
                PhR[row * 72 + col] = ph;
                PlR[row * 72 + col] = f2bu(pv - bu2f(ph));
                if (st < 5) {
                    float bv = accB[nt][r];
                    unsigned short bh2 = f2bu(bv);
                    unsigned short bl2 = f2bu(bv - bu2f(bh2));
                    BhR[row * 72 + col] = bh2;
                    BlR[row * 72 + col] = bl2;
                    BhT[col * 72 + row] = bh2;
                    BlT[col * 72 + row] = bl2;
                }
            }
        __syncthreads();
    }
#pragma unroll
    for (int s = 0; s < 16; ++s) {
        int idx = tid + 256 * s;
        int i = idx >> 6, j = idx & 63;
        float t = (i == j) ? 1.f : 3.f * Pf[i * 73 + j];
        Tg[(size_t)chunk * 4096 + idx] = t;
    }
}

// ---------------- W = T'·K, U = T'·V via MFMA (T' = T·diag(beta)); fused kw/ku ----------------
__global__ __launch_bounds__(256) void wu_mfma_kernel(const float* __restrict__ Tg,
                                                      const unsigned short* __restrict__ Khi,
                                                      const unsigned short* __restrict__ Vhi,
                                                      const float* __restrict__ betaB,
                                                      unsigned short* __restrict__ Wb,
                                                      unsigned short* __restrict__ Ub,
                                                      float* __restrict__ kw, float* __restrict__ ku) {
    const int chunk = blockIdx.x;  // 128
    const int h = blockIdx.y;      // 4
    const int half = blockIdx.z;   // 2
    const int tid = threadIdx.x;
    const int wave = tid >> 6, lane = tid & 63;
    const int quad = lane >> 4, l16 = lane & 15;
    const size_t l0 = (size_t)chunk * 64;
    const int f0 = h * 256 + half * 128;
    __shared__ unsigned short Th[64 * 72], Tl[64 * 72];
    __shared__ unsigned short KT[128 * 72], VT[128 * 72];
    __shared__ float betS[64];
    if (tid < 64) betS[tid] = betaB[(l0 + tid) * 4 + h];
    __syncthreads();
#pragma unroll
    for (int s = 0; s < 16; ++s) {
        int idx = tid + 256 * s;
        int c = idx >> 6, j = idx & 63;
        float v = Tg[(size_t)chunk * 4096 + idx] * betS[j];
        unsigned short hv = f2bu(v);
        Th[c * 72 + j] = hv;
        Tl[c * 72 + j] = f2bu(v - bu2f(hv));
    }
#pragma unroll
    for (int pass = 0; pass < 4; ++pass) {
        int j = pass * 16 + (tid >> 4);
        int fc = (tid & 15) * 8;
        v8u kv = *(const v8u*)(Khi + (l0 + j) * HID + f0 + fc);
        v8u vv = *(const v8u*)(Vhi + (l0 + j) * HID + f0 + fc);
#pragma unroll
        for (int i = 0; i < 8; ++i) {
            KT[(fc + i) * 72 + j] = kv[i];
            VT[(fc + i) * 72 + j] = vv[i];
        }
    }
    __syncthreads();

    const int nf = wave * 32;
    const int bb = chunk >> 6, nn = chunk & 63;
    const size_t obase = (((size_t)bb * 4 + h) * 64 + nn) * 256 + half * 128;

#pragma unroll
    for (int phase = 0; phase < 2; ++phase) {
        const unsigned short* BT = phase ? VT : KT;
        v4f acc[4][2];
#pragma unroll
        for (int mt = 0; mt < 4; ++mt)
#pragma unroll
            for (int nt = 0; nt < 2; ++nt) { v4f z = {0.f, 0.f, 0.f, 0.f}; acc[mt][nt] = z; }
#pragma unroll
        for (int k0 = 0; k0 < 64; k0 += 32) {
            v8s ah[4], al[4], bf[2];
#pragma unroll
            for (int mt = 0; mt < 4; ++mt) {
                ah[mt] = *(const v8s*)&Th[(mt * 16 + l16) * 72 + k0 + quad * 8];
                al[mt] = *(const v8s*)&Tl[(mt * 16 + l16) * 72 + k0 + quad * 8];
            }
#pragma unroll
            for (int nt = 0; nt < 2; ++nt)
                bf[nt] = *(const v8s*)&BT[(nf + nt * 16 + l16) * 72 + k0 + quad * 8];
#pragma unroll
            for (int mt = 0; mt < 4; ++mt)
#pragma unroll
                for (int nt = 0; nt < 2; ++nt) {
                    acc[mt][nt] = __builtin_amdgcn_mfma_f32_16x16x32_bf16(ah[mt], bf[nt], acc[mt][nt], 0, 0, 0);
                    acc[mt][nt] = __builtin_amdgcn_mfma_f32_16x16x32_bf16(al[mt], bf[nt], acc[mt][nt], 0, 0, 0);
                }
        }
        unsigned short* Out = phase ? Ub : Wb;
        float* kk = phase ? ku : kw;
#pragma unroll
        for (int nt = 0; nt < 2; ++nt) {
            const int fl = nf + nt * 16 + l16;
            float dot = 0.f;
#pragma unroll
            for (int mt = 0; mt < 4; ++mt)
#pragma unroll
                for (int r = 0; r < 4; ++r) {
                    const int c = mt * 16 + quad * 4 + r;
                    float wv = acc[mt][nt][r];
                    Out[(l0 + c) * HID + f0 + fl] = f2bu(wv);
                    dot += bu2f(KT[fl * 72 + c]) * wv;
                }
            dot += __shfl_xor(dot, 16);
            dot += __shfl_xor(dot, 32);
            if (quad == 0) kk[obase + fl] = dot;
        }
    }
}

// ---------------- diagonal scan over chunks ----------------
__global__ __launch_bounds__(256) void scan_kernel(const float* __restrict__ kw,
                                                   const float* __restrict__ ku,
                                                   float* __restrict__ dsA) {
    const int bh = blockIdx.x;
    const int e = threadIdx.x;
    float ds = 0.f;
    for (int n = 0; n < 64; ++n) {
        size_t idx = ((size_t)bh * 64 + n) * 256 + e;
        dsA[idx] = ds;
        ds = ds * (1.f - kw[idx]) + ku[idx];
    }
}

// ---------------- o = q*ds + [c<=b]*A*(u - w*ds); fused RMSNorm + bf16 cast (wave-per-row) ----------------
__global__ __launch_bounds__(256) void o_kernel(const unsigned short* __restrict__ Qb,
                                                const unsigned short* __restrict__ Khi,
                                                const unsigned short* __restrict__ Wb,
                                                const unsigned short* __restrict__ Ub,
                                                const float* __restrict__ dsA,
                                                const float* __restrict__ rmsw,
                                                unsigned short* __restrict__ ob,
                                                unsigned short* __restrict__ ub) {
    const int r = blockIdx.x * 4 + (threadIdx.x >> 6);
    const int lane = threadIdx.x & 63;
    const int b = r >> 12, l = r & (L_SEQ - 1);
    const int n = l >> 6, cpos = l & 63;
    const size_t rowb = (size_t)r * HID;
    const bool doA = (cpos <= b);
    float qv[4][4];
    v4f dsv[4];
    float As = 0.f;
#pragma unroll
    for (int hh = 0; hh < 4; ++hh) {
        const int c4 = hh * 256 + lane * 4;
        dsv[hh] = *(const v4f*)&dsA[(((size_t)b * 4 + hh) * 64 + n) * 256 + lane * 4];
        v4us qu = *(const v4us*)&Qb[rowb + c4];
#pragma unroll
        for (int i = 0; i < 4; ++i) qv[hh][i] = bu2f(qu[i]);
        if (doA) {
            v4us kq = *(const v4us*)&Khi[rowb + c4];
#pragma unroll
            for (int i = 0; i < 4; ++i) As += qv[hh][i] * bu2f(kq[i]);
        }
    }
    float Aval = 0.f;
    if (doA) {
#pragma unroll
        for (int off = 32; off; off >>= 1) As += __shfl_xor(As, off);
        Aval = As;
    }
    float ss = 0.f;
    float ov[4][4];
#pragma unroll
    for (int hh = 0; hh < 4; ++hh) {
        const int c4 = hh * 256 + lane * 4;
        v4us uu = *(const v4us*)&Ub[rowb + c4];
        v4us wu4 = *(const v4us*)&Wb[rowb + c4];
        v4us up;
#pragma unroll
        for (int i = 0; i < 4; ++i) {
            float u = bu2f(uu[i]) - bu2f(wu4[i]) * dsv[hh][i];
            up[i] = f2bu(u);
            float o = qv[hh][i] * dsv[hh][i];
            if (doA) o += Aval * u;
            ov[hh][i] = o;
            ss += o * o;
        }
        *(v4us*)&ub[rowb + c4] = up;
    }
#pragma unroll
    for (int off = 32; off; off >>= 1) ss += __shfl_xor(ss, off);
    float scale = rsqrtf(ss * (1.f / 1024.f) + 1e-5f);
#pragma unroll
    for (int hh = 0; hh < 4; ++hh) {
        const int c4 = hh * 256 + lane * 4;
        v4f rw = *(const v4f*)&rmsw[c4];
        v4us op;
#pragma unroll
        for (int i = 0; i < 4; ++i) op[i] = f2bu(ov[hh][i] * scale * rw[i]);
        *(v4us*)&ob[rowb + c4] = op;
    }
}

// ---------------- state S = K^T u'  via MFMA (n-split partials) ----------------
#define SNS 8
__global__ __launch_bounds__(256) void s_mfma_kernel(const unsigned short* __restrict__ Khi,
                                                     const unsigned short* __restrict__ Ub,
                                                     float* __restrict__ Spart) {
    const int bh = blockIdx.x;
    const int b = bh >> 2, h = bh & 3;
    const int dt = blockIdx.y;
    const int et = blockIdx.z & 1;
    const int ns = blockIdx.z >> 1;
    const int tid = threadIdx.x;
    const int wave = tid >> 6, lane = tid & 63;
    const int quad = lane >> 4, l16 = lane & 15;
    const int wm = (wave >> 1) * 64, wn = (wave & 1) * 64;
    __shared__ unsigned short Kt[128 * 40];
    __shared__ unsigned short Ut[128 * 40];
    const int cc = tid >> 3;
    const int dcol = (tid & 7) * 16;
    const size_t rowbase = (size_t)b * 4096 + (size_t)ns * 512;
    const int ck = h * 256 + dt * 128;
    const int ce = h * 256 + et * 128;
    v4f acc[4][4];
#pragma unroll
    for (int a = 0; a < 4; ++a)
#pragma unroll
        for (int c2 = 0; c2 < 4; ++c2) { v4f z = {0.f, 0.f, 0.f, 0.f}; acc[a][c2] = z; }

    for (int kt = 0; kt < 16; ++kt) {
        size_t row = rowbase + kt * 32 + cc;
        v8u k0 = *(const v8u*)(Khi + row * HID + ck + dcol);
        v8u k1 = *(const v8u*)(Khi + row * HID + ck + dcol + 8);
        v8u u0 = *(const v8u*)(Ub + row * HID + ce + dcol);
        v8u u1 = *(const v8u*)(Ub + row * HID + ce + dcol + 8);
        __syncthreads();
#pragma unroll
        for (int j = 0; j < 8; ++j) {
            Kt[(dcol + j) * 40 + cc] = k0[j];
            Kt[(dcol + 8 + j) * 40 + cc] = k1[j];
            Ut[(dcol + j) * 40 + cc] = u0[j];
            Ut[(dcol + 8 + j) * 40 + cc] = u1[j];
        }
        __syncthreads();
        v8s af[4], bf[4];
#pragma unroll
        for (int mt = 0; mt < 4; ++mt) af[mt] = *(const v8s*)&Kt[(wm + mt * 16 + l16) * 40 + quad * 8];
#pragma unroll
        for (int nt = 0; nt < 4; ++nt) bf[nt] = *(const v8s*)&Ut[(wn + nt * 16 + l16) * 40 + quad * 8];
#pragma unroll
        for (int mt = 0; mt < 4; ++mt)
#pragma unroll
            for (int nt = 0; nt < 4; ++nt)
                acc[mt][nt] = __builtin_amdgcn_mfma_f32_16x16x32_bf16(af[mt], bf[nt], acc[mt][nt], 0, 0, 0);
    }
    float* out = Spart + (size_t)ns * (8 * 256 * 256);
#pragma unroll
    for (int mt = 0; mt < 4; ++mt)
#pragma unroll
        for (int nt = 0; nt < 4; ++nt) {
            int row = dt * 128 + wm + mt * 16 + quad * 4;
            int col = et * 128 + wn + nt * 16 + l16;
#pragma unroll
            for (int r = 0; r < 4; ++r)
                out[((size_t)bh * 256 + row + r) * 256 + col] = acc[mt][nt][r];
        }
}

// ---------------- reduce SNS partials -> out1 ----------------
__global__ __launch_bounds__(256) void sreduce_kernel(const float* __restrict__ Spart,
                                                      float* __restrict__ out) {
    int i = blockIdx.x * 256 + threadIdx.x;
    float s = 0.f;
#pragma unroll
    for (int ns = 0; ns < SNS; ++ns) s += Spart[(size_t)ns * (8 * 256 * 256) + i];
    out[i] = s;
}

extern "C" void kernel_launch(void* const* d_in, const int* in_sizes, int n_in,
                              void* d_out, int out_size, void* d_ws, size_t ws_size,
                              hipStream_t stream) {
    const float* x     = (const float*)d_in[0];
    const float* Wq    = (const float*)d_in[1];
    const float* Wk    = (const float*)d_in[2];
    const float* Wv    = (const float*)d_in[3];
    const float* convq = (const float*)d_in[4];
    const float* convk = (const float*)d_in[5];
    const float* convv = (const float*)d_in[6];
    const float* Wbeta = (const float*)d_in[7];
    const float* rmsw  = (const float*)d_in[8];
    const float* Wo    = (const float*)d_in[9];

    // ---- workspace map (aliases documented) ----
    char* ws = (char*)d_ws;
    size_t off = 0;
    auto alloc = [&](size_t bytes) {
        char* p = ws + off;
        off += (bytes + 255) & ~(size_t)255;
        return (void*)p;
    };
    const size_t MM = (size_t)HID * HID;
    unsigned short* xhi   = (unsigned short*)alloc((size_t)BL_TOT * HID * 2);  // later Qm/ob
    unsigned short* Khi   = (unsigned short*)alloc((size_t)BL_TOT * HID * 2);  // conv_k -> s_mfma
    unsigned short* wbQKV = (unsigned short*)alloc(3 * MM * 2);                // [V|K|Q] packed
    unsigned short* wbO   = (unsigned short*)alloc(MM * 2);
    unsigned short* Vhi   = (unsigned short*)alloc((size_t)BL_TOT * HID * 2);
    unsigned short* Wb16  = (unsigned short*)alloc((size_t)BL_TOT * HID * 2);
    unsigned short* Ub16  = (unsigned short*)alloc((size_t)BL_TOT * HID * 2);
    float* Tg    = (float*)alloc((size_t)128 * 4096 * 4);
    float* betaB = (float*)alloc((size_t)BL_TOT * 4 * 4);
    float* kwB   = (float*)alloc((size_t)8 * 64 * 256 * 4);
    float* kuB   = (float*)alloc((size_t)8 * 64 * 256 * 4);
    float* dsA   = (float*)alloc((size_t)8 * 64 * 256 * 4);
    // Gt last: bf16 GEMM output. big = 8192x3072 (merged QKV) if workspace allows.
    const size_t gt_big = (size_t)BL_TOT * 3 * HID * 2;
    const size_t gt_small = (size_t)BL_TOT * HID * 2;
    // Spart (16 MB f32) aliases Gt; ensure allocation covers it in either path.
    const size_t spart_bytes = (size_t)SNS * 8 * 256 * 256 * 4;
    const bool big = (off + (gt_big > spart_bytes ? gt_big : spart_bytes)) <= ws_size;
    unsigned short* Gt = (unsigned short*)alloc(big ? (gt_big > spart_bytes ? gt_big : spart_bytes)
                                                    : (gt_small > spart_bytes ? gt_small : spart_bytes));

    unsigned short* Qm = xhi;   // xhi dead after (last) x-GEMM
    unsigned short* ob = Qm;    // q dead after o_kernel reads its own row
    float* Spart = (float*)Gt;  // Gt dead after conv

    float* out0 = (float*)d_out;
    float* out1 = out0 + (size_t)BL_TOT * HID;
    // d_out as pre-final scratch (validated only after launch):
    unsigned short* Klo = (unsigned short*)out0;            // bytes 0..16.78M
    unsigned short* ubf = (unsigned short*)out0 + 8388608;  // bytes 16.78M..33.55M
    float* Gg = out0 + (size_t)4400000;                     // gram scratch; dead before o_kernel

    dim3 blk(256);
    dim3 ggrid(BL_TOT / 128, HID / 128);

    wcvt_kernel<<<dim3(256, 4), blk, 0, stream>>>(Wv, Wk, Wq, Wo, wbQKV, wbQKV + MM, wbQKV + 2 * MM, wbO);
    beta_kernel<<<BL_TOT / 4, blk, 0, stream>>>(x, Wbeta, betaB, xhi);

    if (big) {
        // one QKV GEMM (N=3072, bf16 out) + one merged conv dispatch
        gemm_mfma<unsigned short><<<dim3(BL_TOT / 128, 3 * HID / 128), blk, 0, stream>>>(
            xhi, wbQKV, Gt, BL_TOT, 3 * HID, HID);
        conv_kernel<<<dim3(BL_TOT, 3), blk, 0, stream>>>(Gt, 3 * HID, -1, convq, convk, convv,
                                                         Vhi, Khi, Klo, Qm);
        gram_kernel<<<dim3(128, 4), blk, 0, stream>>>(Khi, Klo, Gg);
        trec_kernel<<<128, blk, 0, stream>>>(Gg, betaB, Tg);
    } else {
        // sequential fallback (Gt reused; Q GEMM last so Qm alias of xhi stays safe)
        gemm_mfma<unsigned short><<<ggrid, blk, 0, stream>>>(xhi, wbQKV, Gt, BL_TOT, HID, HID);
        conv_kernel<<<dim3(BL_TOT, 1), blk, 0, stream>>>(Gt, HID, 0, convq, convk, convv, Vhi, Khi, Klo, Qm);
        gemm_mfma<unsigned short><<<ggrid, blk, 0, stream>>>(xhi, wbQKV + MM, Gt, BL_TOT, HID, HID);
        conv_kernel<<<dim3(BL_TOT, 1), blk, 0, stream>>>(Gt, HID, 1, convq, convk, convv, Vhi, Khi, Klo, Qm);
        gram_kernel<<<dim3(128, 4), blk, 0, stream>>>(Khi, Klo, Gg);
        trec_kernel<<<128, blk, 0, stream>>>(Gg, betaB, Tg);
        gemm_mfma<unsigned short><<<ggrid, blk, 0, stream>>>(xhi, wbQKV + 2 * MM, Gt, BL_TOT, HID, HID);
        conv_kernel<<<dim3(BL_TOT, 1), blk, 0, stream>>>(Gt, HID, 2, convq, convk, convv, Vhi, Khi, Klo, Qm);
    }

    // chunked delta rule
    wu_mfma_kernel<<<dim3(128, 4, 2), blk, 0, stream>>>(Tg, Khi, Vhi, betaB, Wb16, Ub16, kwB, kuB);
    scan_kernel<<<8, blk, 0, stream>>>(kwB, kuB, dsA);
    o_kernel<<<BL_TOT / 4, blk, 0, stream>>>(Qm, Khi, Wb16, Ub16, dsA, rmsw, ob, ubf);
    s_mfma_kernel<<<dim3(8, 2, 2 * SNS), blk, 0, stream>>>(Khi, ubf, Spart);
    sreduce_kernel<<<2048, blk, 0, stream>>>(Spart, out1);

    // final projection: o(bf16) @ Wo^T -> f32 out0 (overwrites Klo/ubf scratch)
    gemm_mfma<float><<<ggrid, blk, 0, stream>>>(ob, wbO, out0, BL_TOT, HID, HID);
}

// Round 6
// 359.803 us; speedup vs baseline: 1.2564x; 1.0185x over previous
//
#include <hip/hip_runtime.h>
#include <hip/hip_bf16.h>

#define L_SEQ 4096
#define HID 1024
#define NH 4
#define DH 256
#define CK 64
#define BL_TOT 8192   // B*L

typedef short v8s __attribute__((ext_vector_type(8)));
typedef unsigned short v8u __attribute__((ext_vector_type(8)));
typedef unsigned short v4us __attribute__((ext_vector_type(4)));
typedef float v4f __attribute__((ext_vector_type(4)));

typedef __attribute__((address_space(1))) const void* as1cv;
typedef __attribute__((address_space(3))) void* as3v;

__device__ __forceinline__ unsigned short f2bu(float f) {
    __hip_bfloat16 h = __float2bfloat16(f);
    return *(unsigned short*)&h;
}
__device__ __forceinline__ float bu2f(unsigned short u) {
    __hip_bfloat16 h = *(__hip_bfloat16*)&u;
    return __bfloat162float(h);
}
__device__ __forceinline__ void storec(float* p, float v) { *p = v; }
__device__ __forceinline__ void storec(unsigned short* p, float v) { *p = f2bu(v); }

// ---------------- all-weights f32 -> bf16 in one dispatch ----------------
__global__ __launch_bounds__(256) void wcvt_kernel(const float* __restrict__ s0, const float* __restrict__ s1,
                                                   const float* __restrict__ s2, const float* __restrict__ s3,
                                                   unsigned short* __restrict__ d0, unsigned short* __restrict__ d1,
                                                   unsigned short* __restrict__ d2, unsigned short* __restrict__ d3) {
    const float* s = blockIdx.y == 0 ? s0 : blockIdx.y == 1 ? s1 : blockIdx.y == 2 ? s2 : s3;
    unsigned short* d = blockIdx.y == 0 ? d0 : blockIdx.y == 1 ? d1 : blockIdx.y == 2 ? d2 : d3;
    int i = blockIdx.x * 256 + threadIdx.x;
    int stride = gridDim.x * 256;
    for (; i < HID * HID; i += stride) d[i] = f2bu(s[i]);
}

// ---------------- MFMA bf16 GEMM: C[M,N] = A[M,K] * B[N,K]^T ----------------
// 128^2 tile, BK=64, global_load_lds width=16, both-sides XOR swizzle (conflict-free).
// 1-D grid, A-panel-major (n fastest) + XCD-chunked bijective swizzle (T1):
// XCD k owns a contiguous wg chunk -> all blocks sharing an A-panel hit one L2.
// Requires gridDim.x % 8 == 0 (1536 / 512 here).
template <typename OT>
__global__ __launch_bounds__(256) void gemm_mfma(const unsigned short* __restrict__ Ah,
                                                 const unsigned short* __restrict__ Bh,
                                                 OT* __restrict__ C, int M, int N, int K) {
    __shared__ unsigned short AsH[128 * 64];
    __shared__ unsigned short BsH[128 * 64];
    const int tid = threadIdx.x;
    const int wave = tid >> 6, lane = tid & 63;
    const int quad = lane >> 4, l16 = lane & 15;
    const int nb = N >> 7;
    const int q8 = gridDim.x >> 3;
    const int wg = (blockIdx.x & 7) * q8 + (blockIdx.x >> 3);
    const int m0 = (wg / nb) * 128, n0 = (wg % nb) * 128;
    const int wm = (wave >> 1) * 64, wn = (wave & 1) * 64;

    // staging: one issue = 256 thr * 16 B = 4 KB = 32 rows * 128 B; 4 issues per 128-row tile
    const int srow = wave * 8 + (lane >> 3);              // 0..31 within issue stripe
    const int scol = (((lane & 7) ^ (lane >> 3)) * 8);    // pre-swizzled source chunk (shorts)
    const unsigned short* Ag = Ah + (size_t)(m0 + srow) * K + scol;
    const unsigned short* Bg = Bh + (size_t)(n0 + srow) * K + scol;
    char* lA = (char*)AsH;
    char* lB = (char*)BsH;
    const int lbase = wave * 1024;

    v4f acc[4][4];
#pragma unroll
    for (int a = 0; a < 4; ++a)
#pragma unroll
        for (int b = 0; b < 4; ++b) { v4f z = {0.f, 0.f, 0.f, 0.f}; acc[a][b] = z; }

    for (int k0 = 0; k0 < K; k0 += 64) {
        __syncthreads();  // previous tile's ds_reads complete
#pragma unroll
        for (int i = 0; i < 4; ++i)
            __builtin_amdgcn_global_load_lds((as1cv)(Ag + (size_t)(i * 32) * K + k0),
                                             (as3v)(lA + i * 4096 + lbase), 16, 0, 0);
#pragma unroll
        for (int i = 0; i < 4; ++i)
            __builtin_amdgcn_global_load_lds((as1cv)(Bg + (size_t)(i * 32) * K + k0),
                                             (as3v)(lB + i * 4096 + lbase), 16, 0, 0);
        __syncthreads();  // drains vmcnt -> LDS tile ready
#pragma unroll
        for (int kk = 0; kk < 2; ++kk) {
            v8s afh[4], bfh[4];
#pragma unroll
            for (int mt = 0; mt < 4; ++mt) {
                const int row = wm + mt * 16 + l16;
                afh[mt] = *(const v8s*)&AsH[row * 64 + (((quad + 4 * kk) ^ (row & 7)) * 8)];
            }
#pragma unroll
            for (int nt = 0; nt < 4; ++nt) {
                const int row = wn + nt * 16 + l16;
                bfh[nt] = *(const v8s*)&BsH[row * 64 + (((quad + 4 * kk) ^ (row & 7)) * 8)];
            }
#pragma unroll
            for (int mt = 0; mt < 4; ++mt)
#pragma unroll
                for (int nt = 0; nt < 4; ++nt)
                    acc[mt][nt] = __builtin_amdgcn_mfma_f32_16x16x32_bf16(afh[mt], bfh[nt], acc[mt][nt], 0, 0, 0);
        }
    }
#pragma unroll
    for (int mt = 0; mt < 4; ++mt)
#pragma unroll
        for (int nt = 0; nt < 4; ++nt) {
            int row = m0 + wm + mt * 16 + quad * 4;
            int col = n0 + wn + nt * 16 + l16;
#pragma unroll
            for (int r = 0; r < 4; ++r)
                storec(&C[(size_t)(row + r) * N + col], acc[mt][nt][r]);
        }
}

// ---------------- beta = sigmoid(x @ Wbeta^T); fused x -> bf16 (wave-per-row) ----------------
__global__ __launch_bounds__(256) void beta_kernel(const float* __restrict__ x,
                                                   const float* __restrict__ Wb,
                                                   float* __restrict__ betaB,
                                                   unsigned short* __restrict__ xh) {
    const int t = blockIdx.x * 4 + (threadIdx.x >> 6);
    const int lane = threadIdx.x & 63;
    const float* xr = x + (size_t)t * HID;
    float s[4] = {0.f, 0.f, 0.f, 0.f};
    v4f xv[4];
#pragma unroll
    for (int c = 0; c < 4; ++c) {
        const int i4 = c * 256 + lane * 4;
        xv[c] = *(const v4f*)(xr + i4);
        v4us xp;
#pragma unroll
        for (int i = 0; i < 4; ++i) xp[i] = f2bu(xv[c][i]);
        *(v4us*)&xh[(size_t)t * HID + i4] = xp;
    }
#pragma unroll
    for (int h = 0; h < 4; ++h)
#pragma unroll
        for (int c = 0; c < 4; ++c) {
            v4f wv = *(const v4f*)(Wb + (size_t)h * HID + c * 256 + lane * 4);
            s[h] += xv[c][0] * wv[0] + xv[c][1] * wv[1] + xv[c][2] * wv[2] + xv[c][3] * wv[3];
        }
#pragma unroll
    for (int off = 32; off; off >>= 1)
#pragma unroll
        for (int h = 0; h < 4; ++h) s[h] += __shfl_xor(s[h], off);
    if (lane < 4) betaB[(size_t)t * 4 + lane] = 1.f / (1.f + expf(-s[lane]));
}

// ---------------- causal depthwise conv (KS=4) + silu + silu (+ per-head l2norm) ----------------
// 4 rows per block: 7 tap-rows loaded for 4 outputs (tap reuse in registers).
// Thread owns 4 contiguous channels of head (tid>>6); l2norm = wave shuffle per row.
// path p: 0=V (bf16 out, no norm), 1=K (hi/lo out, norm), 2=Q (bf16 out, norm).
__global__ __launch_bounds__(256) void conv_kernel(const unsigned short* __restrict__ G, int gstride, int pathArg,
                                                   const float* __restrict__ wq, const float* __restrict__ wk,
                                                   const float* __restrict__ wv,
                                                   unsigned short* __restrict__ Vout,
                                                   unsigned short* __restrict__ KhiO, unsigned short* __restrict__ KloO,
                                                   unsigned short* __restrict__ Qout) {
    const int p = pathArg < 0 ? (int)blockIdx.y : pathArg;
    const int yoff = pathArg < 0 ? p * 1024 : 0;
    const float* __restrict__ w = p == 0 ? wv : p == 1 ? wk : wq;
    const int bl0 = blockIdx.x * 4;           // 4 consecutive rows; never straddles a sequence (4096%4==0)
    const int l0 = bl0 & (L_SEQ - 1);
    const int tid = threadIdx.x;
    const int lane = tid & 63;
    const int c4 = (tid >> 6) * 256 + lane * 4;  // 4 contiguous channels in head (tid>>6)
    v4f wrow[4];
#pragma unroll
    for (int cc = 0; cc < 4; ++cc) wrow[cc] = *(const v4f*)&w[(c4 + cc) * 4];
    v4f g[7];
#pragma unroll
    for (int t = 0; t < 7; ++t) {
        v4f gv = {0.f, 0.f, 0.f, 0.f};
        if (l0 - 3 + t >= 0) {
            v4us gu = *(const v4us*)&G[(size_t)(bl0 - 3 + t) * gstride + yoff + c4];
#pragma unroll
            for (int i = 0; i < 4; ++i) gv[i] = bu2f(gu[i]);
        }
        g[t] = gv;
    }
#pragma unroll
    for (int r = 0; r < 4; ++r) {
        float vals[4];
#pragma unroll
        for (int cc = 0; cc < 4; ++cc) {
            float a = g[r][cc] * wrow[cc][0] + g[r + 1][cc] * wrow[cc][1] +
                      g[r + 2][cc] * wrow[cc][2] + g[r + 3][cc] * wrow[cc][3];
            float s1 = a / (1.f + expf(-a));
            vals[cc] = s1 / (1.f + expf(-s1));
        }
        if (p >= 1) {
            float sq = vals[0] * vals[0] + vals[1] * vals[1] + vals[2] * vals[2] + vals[3] * vals[3];
#pragma unroll
            for (int off = 32; off; off >>= 1) sq += __shfl_xor(sq, off);
            float nrm = 1.f / fmaxf(sqrtf(sq), 1e-12f);
#pragma unroll
            for (int cc = 0; cc < 4; ++cc) vals[cc] *= nrm;
        }
        const size_t ob = (size_t)(bl0 + r) * HID + c4;
        if (p == 1) {
            v4us hv, lv;
#pragma unroll
            for (int cc = 0; cc < 4; ++cc) {
                unsigned short h = f2bu(vals[cc]);
                hv[cc] = h;
                lv[cc] = f2bu(vals[cc] - bu2f(h));
            }
            *(v4us*)&KhiO[ob] = hv;
            *(v4us*)&KloO[ob] = lv;
        } else {
            unsigned short* O = p == 0 ? Vout : Qout;
            v4us hv;
#pragma unroll
            for (int cc = 0; cc < 4; ++cc) hv[cc] = f2bu(vals[cc]);
            *(v4us*)&O[ob] = hv;
        }
    }
}

// ---------------- per-chunk per-head gram: G_h = K_h * K_h^T (split-bf16 MFMA) ----------------
__global__ __launch_bounds__(256) void gram_kernel(const unsigned short* __restrict__ Khi,
                                                   const unsigned short* __restrict__ Klo,
                                                   float* __restrict__ Gg) {
    const int chunk = blockIdx.x;
    const int h = blockIdx.y;
    const int tid = threadIdx.x;
    const int wave = tid >> 6, lane = tid & 63;
    const int quad = lane >> 4, l16 = lane & 15;
    __shared__ unsigned short Hs[64 * 264];
    __shared__ unsigned short Ls[64 * 264];
    const int l0 = chunk * 64;
    const int cb = h * 256;
#pragma unroll
    for (int p = 0; p < 8; ++p) {
        int row = p * 8 + (tid >> 5);
        int col = (tid & 31) * 8;
        v8u hv = *(const v8u*)(Khi + (size_t)(l0 + row) * HID + cb + col);
        v8u lv = *(const v8u*)(Klo + (size_t)(l0 + row) * HID + cb + col);
        *(v8u*)&Hs[row * 264 + col] = hv;
        *(v8u*)&Ls[row * 264 + col] = lv;
    }
    __syncthreads();
    const int wm = wave * 16;
    v4f acc[4];
#pragma unroll
    for (int nt = 0; nt < 4; ++nt) { v4f z = {0.f, 0.f, 0.f, 0.f}; acc[nt] = z; }
#pragma unroll
    for (int ks = 0; ks < 8; ++ks) {
        v8s ah = *(const v8s*)&Hs[(wm + l16) * 264 + ks * 32 + quad * 8];
        v8s al = *(const v8s*)&Ls[(wm + l16) * 264 + ks * 32 + quad * 8];
#pragma unroll
        for (int nt = 0; nt < 4; ++nt) {
            v8s bh = *(const v8s*)&Hs[(nt * 16 + l16) * 264 + ks * 32 + quad * 8];
            v8s bl = *(const v8s*)&Ls[(nt * 16 + l16) * 264 + ks * 32 + quad * 8];
            acc[nt] = __builtin_amdgcn_mfma_f32_16x16x32_bf16(ah, bh, acc[nt], 0, 0, 0);
            acc[nt] = __builtin_amdgcn_mfma_f32_16x16x32_bf16(ah, bl, acc[nt], 0, 0, 0);
            acc[nt] = __builtin_amdgcn_mfma_f32_16x16x32_bf16(al, bh, acc[nt], 0, 0, 0);
        }
    }
    float* og = Gg + ((size_t)chunk * 4 + h) * 4096;
#pragma unroll
    for (int nt = 0; nt < 4; ++nt)
#pragma unroll
        for (int r = 0; r < 4; ++r)
            og[(wm + quad * 4 + r) * 64 + nt * 16 + l16] = acc[nt][r];
}

// ---------------- T recurrence per chunk via nilpotent doubling + MFMA ----------------
// T_final = 3*(I-A)^{-1} - 2I, A = -tril(beta*gram, -1); (I-A)^{-1} = prod (I + A^(2^k)).
__global__ __launch_bounds__(256) void trec_kernel(const float* __restrict__ Gg,
                                                   const float* __restrict__ betaB,
                                                   float* __restrict__ Tg) {
    const int chunk = blockIdx.x;
    const int tid = threadIdx.x;
    const int wave = tid >> 6, lane = tid & 63;
    const int quad = lane >> 4, l16 = lane & 15;
    const int wm = wave * 16;
    __shared__ unsigned short BhR[64 * 72], BlR[64 * 72];  // B rows   [i][j]
    __shared__ unsigned short BhT[64 * 72], BlT[64 * 72];  // B^T rows [j][i]
    __shared__ unsigned short PhR[64 * 72], PlR[64 * 72];  // P rows   [i][j]
    __shared__ float Pf[64 * 73];                          // P master copy (f32)
    __shared__ float betS[256];
    betS[tid] = betaB[(size_t)chunk * 256 + tid];
    __syncthreads();
    const float* gg = Gg + (size_t)chunk * 4 * 4096;
#pragma unroll
    for (int s = 0; s < 16; ++s) {
        int idx = tid + 256 * s;
        int i = idx >> 6, j = idx & 63;
        float a = 0.f;
        if (i > j) {
            a = -(betS[i * 4 + 0] * gg[idx] + betS[i * 4 + 1] * gg[4096 + idx] +
                  betS[i * 4 + 2] * gg[2 * 4096 + idx] + betS[i * 4 + 3] * gg[3 * 4096 + idx]);
        }
        unsigned short ah = f2bu(a);
        unsigned short al = f2bu(a - bu2f(ah));
        BhR[i * 72 + j] = ah;
        BlR[i * 72 + j] = al;
        BhT[j * 72 + i] = ah;
        BlT[j * 72 + i] = al;
        float p = (i == j) ? 1.f : 0.f;
        Pf[i * 73 + j] = p;
        PhR[i * 72 + j] = f2bu(p);
        PlR[i * 72 + j] = 0;
    }
    __syncthreads();

    for (int st = 0; st < 6; ++st) {
        v8s aBh[2], aBl[2], aPh[2], aPl[2];
        v8s bTh[2][4], bTl[2][4];
#pragma unroll
        for (int kk = 0; kk < 2; ++kk) {
            aBh[kk] = *(const v8s*)&BhR[(wm + l16) * 72 + kk * 32 + quad * 8];
            aBl[kk] = *(const v8s*)&BlR[(wm + l16) * 72 + kk * 32 + quad * 8];
            aPh[kk] = *(const v8s*)&PhR[(wm + l16) * 72 + kk * 32 + quad * 8];
            aPl[kk] = *(const v8s*)&PlR[(wm + l16) * 72 + kk * 32 + quad * 8];
#pragma unroll
            for (int nt = 0; nt < 4; ++nt) {
                bTh[kk][nt] = *(const v8s*)&BhT[(nt * 16 + l16) * 72 + kk * 32 + quad * 8];
                bTl[kk][nt] = *(const v8s*)&BlT[(nt * 16 + l16) * 72 + kk * 32 + quad * 8];
            }
        }
        v4f accP[4], accB[4];
#pragma unroll
        for (int nt = 0; nt < 4; ++nt) {
#pragma unroll
            for (int r = 0; r < 4; ++r)
                accP[nt][r] = Pf[(wm + quad * 4 + r) * 73 + nt * 16 + l16];
            v4f z = {0.f, 0.f, 0.f, 0.f};
            accB[nt] = z;
        }
        __syncthreads();  // all reads done before anyone writes
#pragma unroll
        for (int kk = 0; kk < 2; ++kk)
#pragma unroll
            for (int nt = 0; nt < 4; ++nt) {
                accP[nt] = __builtin_amdgcn_mfma_f32_16x16x32_bf16(aPh[kk], bTh[kk][nt], accP[nt], 0, 0, 0);
                accP[nt] = __builtin_amdgcn_mfma_f32_16x16x32_bf16(aPh[kk], bTl[kk][nt], accP[nt], 0, 0, 0);
                accP[nt] = __builtin_amdgcn_mfma_f32_16x16x32_bf16(aPl[kk], bTh[kk][nt], accP[nt], 0, 0, 0);
            }
        if (st < 5) {
#pragma unroll
            for (int kk = 0; kk < 2; ++kk)
#pragma unroll
                for (int nt = 0; nt < 4; ++nt) {
                    accB[nt] = __builtin_amdgcn_mfma_f32_16x16x32_bf16(aBh[kk], bTh[kk][nt], accB[nt], 0, 0, 0);
                    accB[nt] = __builtin_amdgcn_mfma_f32_16x16x32_bf16(aBh[kk], bTl[kk][nt], accB[nt], 0, 0, 0);
                    accB[nt] = __builtin_amdgcn_mfma_f32_16x16x32_bf16(aBl[kk], bTh[kk][nt], accB[nt], 0, 0, 0);
                }
        }
#pragma unroll
        for (int nt = 0; nt < 4; ++nt)
#pragma unroll
            for (int r = 0; r < 4; ++r) {
                int row = wm + quad * 4 + r;
                int col = nt * 16 + l16;
                float pv = accP[nt][r];
                Pf[row * 73 + col] = pv;
                unsigned short ph = f2bu(pv);
                PhR[row * 72 + col] = ph;
                PlR[row * 72 + col] = f2bu(pv - bu2f(ph));
                if (st < 5) {
                    float bv = accB[nt][r];
                    unsigned short bh2 = f2bu(bv);
                    unsigned short bl2 = f2bu(bv - bu2f(bh2));
                    BhR[row * 72 + col] = bh2;
                    BlR[row * 72 + col] = bl2;
                    BhT[col * 72 + row] = bh2;
                    BlT[col * 72 + row] = bl2;
                }
            }
        __syncthreads();
    }
#pragma unroll
    for (int s = 0; s < 16; ++s) {
        int idx = tid + 256 * s;
        int i = idx >> 6, j = idx & 63;
        float t = (i == j) ? 1.f : 3.f * Pf[i * 73 + j];
        Tg[(size_t)chunk * 4096 + idx] = t;
    }
}

// ---------------- W = T'·K, U = T'·V via MFMA (T' = T·diag(beta)); fused kw/ku ----------------
__global__ __launch_bounds__(256) void wu_mfma_kernel(const float* __restrict__ Tg,
                                                      const unsigned short* __restrict__ Khi,
                                                      const unsigned short* __restrict__ Vhi,
                                                      const float* __restrict__ betaB,
                                                      unsigned short* __restrict__ Wb,
                                                      unsigned short* __restrict__ Ub,
                                                      float* __restrict__ kw, float* __restrict__ ku) {
    const int chunk = blockIdx.x;  // 128
    const int h = blockIdx.y;      // 4
    const int half = blockIdx.z;   // 2
    const int tid = threadIdx.x;
    const int wave = tid >> 6, lane = tid & 63;
    const int quad = lane >> 4, l16 = lane & 15;
    const size_t l0 = (size_t)chunk * 64;
    const int f0 = h * 256 + half * 128;
    __shared__ unsigned short Th[64 * 72], Tl[64 * 72];
    __shared__ unsigned short KT[128 * 72], VT[128 * 72];
    __shared__ float betS[64];
    if (tid < 64) betS[tid] = betaB[(l0 + tid) * 4 + h];
    __syncthreads();
#pragma unroll
    for (int s = 0; s < 16; ++s) {
        int idx = tid + 256 * s;
        int c = idx >> 6, j = idx & 63;
        float v = Tg[(size_t)chunk * 4096 + idx] * betS[j];
        unsigned short hv = f2bu(v);
        Th[c * 72 + j] = hv;
        Tl[c * 72 + j] = f2bu(v - bu2f(hv));
    }
#pragma unroll
    for (int pass = 0; pass < 4; ++pass) {
        int j = pass * 16 + (tid >> 4);
        int fc = (tid & 15) * 8;
        v8u kv = *(const v8u*)(Khi + (l0 + j) * HID + f0 + fc);
        v8u vv = *(const v8u*)(Vhi + (l0 + j) * HID + f0 + fc);
#pragma unroll
        for (int i = 0; i < 8; ++i) {
            KT[(fc + i) * 72 + j] = kv[i];
            VT[(fc + i) * 72 + j] = vv[i];
        }
    }
    __syncthreads();

    const int nf = wave * 32;
    const int bb = chunk >> 6, nn = chunk & 63;
    const size_t obase = (((size_t)bb * 4 + h) * 64 + nn) * 256 + half * 128;

#pragma unroll
    for (int phase = 0; phase < 2; ++phase) {
        const unsigned short* BT = phase ? VT : KT;
        v4f acc[4][2];
#pragma unroll
        for (int mt = 0; mt < 4; ++mt)
#pragma unroll
            for (int nt = 0; nt < 2; ++nt) { v4f z = {0.f, 0.f, 0.f, 0.f}; acc[mt][nt] = z; }
#pragma unroll
        for (int k0 = 0; k0 < 64; k0 += 32) {
            v8s ah[4], al[4], bf[2];
#pragma unroll
            for (int mt = 0; mt < 4; ++mt) {
                ah[mt] = *(const v8s*)&Th[(mt * 16 + l16) * 72 + k0 + quad * 8];
                al[mt] = *(const v8s*)&Tl[(mt * 16 + l16) * 72 + k0 + quad * 8];
            }
#pragma unroll
            for (int nt = 0; nt < 2; ++nt)
                bf[nt] = *(const v8s*)&BT[(nf + nt * 16 + l16) * 72 + k0 + quad * 8];
#pragma unroll
            for (int mt = 0; mt < 4; ++mt)
#pragma unroll
                for (int nt = 0; nt < 2; ++nt) {
                    acc[mt][nt] = __builtin_amdgcn_mfma_f32_16x16x32_bf16(ah[mt], bf[nt], acc[mt][nt], 0, 0, 0);
                    acc[mt][nt] = __builtin_amdgcn_mfma_f32_16x16x32_bf16(al[mt], bf[nt], acc[mt][nt], 0, 0, 0);
                }
        }
        unsigned short* Out = phase ? Ub : Wb;
        float* kk = phase ? ku : kw;
#pragma unroll
        for (int nt = 0; nt < 2; ++nt) {
            const int fl = nf + nt * 16 + l16;
            float dot = 0.f;
#pragma unroll
            for (int mt = 0; mt < 4; ++mt)
#pragma unroll
                for (int r = 0; r < 4; ++r) {
                    const int c = mt * 16 + quad * 4 + r;
                    float wv = acc[mt][nt][r];
                    Out[(l0 + c) * HID + f0 + fl] = f2bu(wv);
                    dot += bu2f(KT[fl * 72 + c]) * wv;
                }
            dot += __shfl_xor(dot, 16);
            dot += __shfl_xor(dot, 32);
            if (quad == 0) kk[obase + fl] = dot;
        }
    }
}

// ---------------- diagonal scan over chunks (load-pipelined serial loop) ----------------
__global__ __launch_bounds__(256) void scan_kernel(const float* __restrict__ kw,
                                                   const float* __restrict__ ku,
                                                   float* __restrict__ dsA) {
    const int bh = blockIdx.x;
    size_t idx = (size_t)bh * 64 * 256 + threadIdx.x;
    float ds = 0.f;
    float kwc = kw[idx], kuc = ku[idx];
    for (int n = 0; n < 64; ++n) {
        float kwn = 0.f, kun = 0.f;
        if (n < 63) {  // prefetch next chunk's coeffs off the dependent chain
            kwn = kw[idx + 256];
            kun = ku[idx + 256];
        }
        dsA[idx] = ds;
        ds = ds * (1.f - kwc) + kuc;
        kwc = kwn;
        kuc = kun;
        idx += 256;
    }
}

// ---------------- o = q*ds + [c<=b]*A*(u - w*ds); fused RMSNorm + bf16 cast (wave-per-row) ----------------
__global__ __launch_bounds__(256) void o_kernel(const unsigned short* __restrict__ Qb,
                                                const unsigned short* __restrict__ Khi,
                                                const unsigned short* __restrict__ Wb,
                                                const unsigned short* __restrict__ Ub,
                                                const float* __restrict__ dsA,
                                                const float* __restrict__ rmsw,
                                                unsigned short* __restrict__ ob,
                                                unsigned short* __restrict__ ub) {
    const int r = blockIdx.x * 4 + (threadIdx.x >> 6);
    const int lane = threadIdx.x & 63;
    const int b = r >> 12, l = r & (L_SEQ - 1);
    const int n = l >> 6, cpos = l & 63;
    const size_t rowb = (size_t)r * HID;
    const bool doA = (cpos <= b);
    float qv[4][4];
    v4f dsv[4];
    float As = 0.f;
#pragma unroll
    for (int hh = 0; hh < 4; ++hh) {
        const int c4 = hh * 256 + lane * 4;
        dsv[hh] = *(const v4f*)&dsA[(((size_t)b * 4 + hh) * 64 + n) * 256 + lane * 4];
        v4us qu = *(const v4us*)&Qb[rowb + c4];
#pragma unroll
        for (int i = 0; i < 4; ++i) qv[hh][i] = bu2f(qu[i]);
        if (doA) {
            v4us kq = *(const v4us*)&Khi[rowb + c4];
#pragma unroll
            for (int i = 0; i < 4; ++i) As += qv[hh][i] * bu2f(kq[i]);
        }
    }
    float Aval = 0.f;
    if (doA) {
#pragma unroll
        for (int off = 32; off; off >>= 1) As += __shfl_xor(As, off);
        Aval = As;
    }
    float ss = 0.f;
    float ov[4][4];
#pragma unroll
    for (int hh = 0; hh < 4; ++hh) {
        const int c4 = hh * 256 + lane * 4;
        v4us uu = *(const v4us*)&Ub[rowb + c4];
        v4us wu4 = *(const v4us*)&Wb[rowb + c4];
        v4us up;
#pragma unroll
        for (int i = 0; i < 4; ++i) {
            float u = bu2f(uu[i]) - bu2f(wu4[i]) * dsv[hh][i];
            up[i] = f2bu(u);
            float o = qv[hh][i] * dsv[hh][i];
            if (doA) o += Aval * u;
            ov[hh][i] = o;
            ss += o * o;
        }
        *(v4us*)&ub[rowb + c4] = up;
    }
#pragma unroll
    for (int off = 32; off; off >>= 1) ss += __shfl_xor(ss, off);
    float scale = rsqrtf(ss * (1.f / 1024.f) + 1e-5f);
#pragma unroll
    for (int hh = 0; hh < 4; ++hh) {
        const int c4 = hh * 256 + lane * 4;
        v4f rw = *(const v4f*)&rmsw[c4];
        v4us op;
#pragma unroll
        for (int i = 0; i < 4; ++i) op[i] = f2bu(ov[hh][i] * scale * rw[i]);
        *(v4us*)&ob[rowb + c4] = op;
    }
}

// ---------------- state S = K^T u'  via MFMA (n-split partials) ----------------
#define SNS 8
__global__ __launch_bounds__(256) void s_mfma_kernel(const unsigned short* __restrict__ Khi,
                                                     const unsigned short* __restrict__ Ub,
                                                     float* __restrict__ Spart) {
    const int bh = blockIdx.x;
    const int b = bh >> 2, h = bh & 3;
    const int dt = blockIdx.y;
    const int et = blockIdx.z & 1;
    const int ns = blockIdx.z >> 1;
    const int tid = threadIdx.x;
    const int wave = tid >> 6, lane = tid & 63;
    const int quad = lane >> 4, l16 = lane & 15;
    const int wm = (wave >> 1) * 64, wn = (wave & 1) * 64;
    __shared__ unsigned short Kt[128 * 40];
    __shared__ unsigned short Ut[128 * 40];
    const int cc = tid >> 3;
    const int dcol = (tid & 7) * 16;
    const size_t rowbase = (size_t)b * 4096 + (size_t)ns * 512;
    const int ck = h * 256 + dt * 128;
    const int ce = h * 256 + et * 128;
    v4f acc[4][4];
#pragma unroll
    for (int a = 0; a < 4; ++a)
#pragma unroll
        for (int c2 = 0; c2 < 4; ++c2) { v4f z = {0.f, 0.f, 0.f, 0.f}; acc[a][c2] = z; }

    for (int kt = 0; kt < 16; ++kt) {
        size_t row = rowbase + kt * 32 + cc;
        v8u k0 = *(const v8u*)(Khi + row * HID + ck + dcol);
        v8u k1 = *(const v8u*)(Khi + row * HID + ck + dcol + 8);
        v8u u0 = *(const v8u*)(Ub + row * HID + ce + dcol);
        v8u u1 = *(const v8u*)(Ub + row * HID + ce + dcol + 8);
        __syncthreads();
#pragma unroll
        for (int j = 0; j < 8; ++j) {
            Kt[(dcol + j) * 40 + cc] = k0[j];
            Kt[(dcol + 8 + j) * 40 + cc] = k1[j];
            Ut[(dcol + j) * 40 + cc] = u0[j];
            Ut[(dcol + 8 + j) * 40 + cc] = u1[j];
        }
        __syncthreads();
        v8s af[4], bf[4];
#pragma unroll
        for (int mt = 0; mt < 4; ++mt) af[mt] = *(const v8s*)&Kt[(wm + mt * 16 + l16) * 40 + quad * 8];
#pragma unroll
        for (int nt = 0; nt < 4; ++nt) bf[nt] = *(const v8s*)&Ut[(wn + nt * 16 + l16) * 40 + quad * 8];
#pragma unroll
        for (int mt = 0; mt < 4; ++mt)
#pragma unroll
            for (int nt = 0; nt < 4; ++nt)
                acc[mt][nt] = __builtin_amdgcn_mfma_f32_16x16x32_bf16(af[mt], bf[nt], acc[mt][nt], 0, 0, 0);
    }
    float* out = Spart + (size_t)ns * (8 * 256 * 256);
#pragma unroll
    for (int mt = 0; mt < 4; ++mt)
#pragma unroll
        for (int nt = 0; nt < 4; ++nt) {
            int row = dt * 128 + wm + mt * 16 + quad * 4;
            int col = et * 128 + wn + nt * 16 + l16;
#pragma unroll
            for (int r = 0; r < 4; ++r)
                out[((size_t)bh * 256 + row + r) * 256 + col] = acc[mt][nt][r];
        }
}

// ---------------- reduce SNS partials -> out1 ----------------
__global__ __launch_bounds__(256) void sreduce_kernel(const float* __restrict__ Spart,
                                                      float* __restrict__ out) {
    int i = blockIdx.x * 256 + threadIdx.x;
    float s = 0.f;
#pragma unroll
    for (int ns = 0; ns < SNS; ++ns) s += Spart[(size_t)ns * (8 * 256 * 256) + i];
    out[i] = s;
}

extern "C" void kernel_launch(void* const* d_in, const int* in_sizes, int n_in,
                              void* d_out, int out_size, void* d_ws, size_t ws_size,
                              hipStream_t stream) {
    const float* x     = (const float*)d_in[0];
    const float* Wq    = (const float*)d_in[1];
    const float* Wk    = (const float*)d_in[2];
    const float* Wv    = (const float*)d_in[3];
    const float* convq = (const float*)d_in[4];
    const float* convk = (const float*)d_in[5];
    const float* convv = (const float*)d_in[6];
    const float* Wbeta = (const float*)d_in[7];
    const float* rmsw  = (const float*)d_in[8];
    const float* Wo    = (const float*)d_in[9];

    // ---- workspace map (aliases documented) ----
    char* ws = (char*)d_ws;
    size_t off = 0;
    auto alloc = [&](size_t bytes) {
        char* p = ws + off;
        off += (bytes + 255) & ~(size_t)255;
        return (void*)p;
    };
    const size_t MM = (size_t)HID * HID;
    unsigned short* xhi   = (unsigned short*)alloc((size_t)BL_TOT * HID * 2);  // later Qm/ob
    unsigned short* Khi   = (unsigned short*)alloc((size_t)BL_TOT * HID * 2);  // conv_k -> s_mfma
    unsigned short* wbQKV = (unsigned short*)alloc(3 * MM * 2);                // [V|K|Q] packed
    unsigned short* wbO   = (unsigned short*)alloc(MM * 2);
    unsigned short* Vhi   = (unsigned short*)alloc((size_t)BL_TOT * HID * 2);
    unsigned short* Wb16  = (unsigned short*)alloc((size_t)BL_TOT * HID * 2);
    unsigned short* Ub16  = (unsigned short*)alloc((size_t)BL_TOT * HID * 2);
    float* Tg    = (float*)alloc((size_t)128 * 4096 * 4);
    float* betaB = (float*)alloc((size_t)BL_TOT * 4 * 4);
    float* kwB   = (float*)alloc((size_t)8 * 64 * 256 * 4);
    float* kuB   = (float*)alloc((size_t)8 * 64 * 256 * 4);
    float* dsA   = (float*)alloc((size_t)8 * 64 * 256 * 4);
    // Gt last: bf16 GEMM output. big = 8192x3072 (merged QKV) if workspace allows.
    const size_t gt_big = (size_t)BL_TOT * 3 * HID * 2;
    const size_t gt_small = (size_t)BL_TOT * HID * 2;
    // Spart (16 MB f32) aliases Gt; ensure allocation covers it in either path.
    const size_t spart_bytes = (size_t)SNS * 8 * 256 * 256 * 4;
    const bool big = (off + (gt_big > spart_bytes ? gt_big : spart_bytes)) <= ws_size;
    unsigned short* Gt = (unsigned short*)alloc(big ? (gt_big > spart_bytes ? gt_big : spart_bytes)
                                                    : (gt_small > spart_bytes ? gt_small : spart_bytes));

    unsigned short* Qm = xhi;   // xhi dead after (last) x-GEMM
    unsigned short* ob = Qm;    // q dead after o_kernel reads its own row
    float* Spart = (float*)Gt;  // Gt dead after conv

    float* out0 = (float*)d_out;
    float* out1 = out0 + (size_t)BL_TOT * HID;
    // d_out as pre-final scratch (validated only after launch):
    unsigned short* Klo = (unsigned short*)out0;            // bytes 0..16.78M
    unsigned short* ubf = (unsigned short*)out0 + 8388608;  // bytes 16.78M..33.55M
    float* Gg = out0 + (size_t)4400000;                     // gram scratch; dead before o_kernel

    dim3 blk(256);
    const int gw_full = (BL_TOT / 128) * (HID / 128);          // 512 (%8==0)
    const int gw_qkv  = (BL_TOT / 128) * (3 * HID / 128);      // 1536 (%8==0)

    wcvt_kernel<<<dim3(256, 4), blk, 0, stream>>>(Wv, Wk, Wq, Wo, wbQKV, wbQKV + MM, wbQKV + 2 * MM, wbO);
    beta_kernel<<<BL_TOT / 4, blk, 0, stream>>>(x, Wbeta, betaB, xhi);

    if (big) {
        // one QKV GEMM (N=3072, bf16 out) + one merged conv dispatch
        gemm_mfma<unsigned short><<<gw_qkv, blk, 0, stream>>>(xhi, wbQKV, Gt, BL_TOT, 3 * HID, HID);
        conv_kernel<<<dim3(BL_TOT / 4, 3), blk, 0, stream>>>(Gt, 3 * HID, -1, convq, convk, convv,
                                                             Vhi, Khi, Klo, Qm);
        gram_kernel<<<dim3(128, 4), blk, 0, stream>>>(Khi, Klo, Gg);
        trec_kernel<<<128, blk, 0, stream>>>(Gg, betaB, Tg);
    } else {
        // sequential fallback (Gt reused; Q GEMM last so Qm alias of xhi stays safe)
        gemm_mfma<unsigned short><<<gw_full, blk, 0, stream>>>(xhi, wbQKV, Gt, BL_TOT, HID, HID);
        conv_kernel<<<dim3(BL_TOT / 4, 1), blk, 0, stream>>>(Gt, HID, 0, convq, convk, convv, Vhi, Khi, Klo, Qm);
        gemm_mfma<unsigned short><<<gw_full, blk, 0, stream>>>(xhi, wbQKV + MM, Gt, BL_TOT, HID, HID);
        conv_kernel<<<dim3(BL_TOT / 4, 1), blk, 0, stream>>>(Gt, HID, 1, convq, convk, convv, Vhi, Khi, Klo, Qm);
        gram_kernel<<<dim3(128, 4), blk, 0, stream>>>(Khi, Klo, Gg);
        trec_kernel<<<128, blk, 0, stream>>>(Gg, betaB, Tg);
        gemm_mfma<unsigned short><<<gw_full, blk, 0, stream>>>(xhi, wbQKV + 2 * MM, Gt, BL_TOT, HID, HID);
        conv_kernel<<<dim3(BL_TOT / 4, 1), blk, 0, stream>>>(Gt, HID, 2, convq, convk, convv, Vhi, Khi, Klo, Qm);
    }

    // chunked delta rule
    wu_mfma_kernel<<<dim3(128, 4, 2), blk, 0, stream>>>(Tg, Khi, Vhi, betaB, Wb16, Ub16, kwB, kuB);
    scan_kernel<<<8, blk, 0, stream>>>(kwB, kuB, dsA);
    o_kernel<<<BL_TOT / 4, blk, 0, stream>>>(Qm, Khi, Wb16, Ub16, dsA, rmsw, ob, ubf);
    s_mfma_kernel<<<dim3(8, 2, 2 * SNS), blk, 0, stream>>>(Khi, ubf, Spart);
    sreduce_kernel<<<2048, blk, 0, stream>>>(Spart, out1);

    // final projection: o(bf16) @ Wo^T -> f32 out0 (overwrites Klo/ubf scratch)
    gemm_mfma<float><<<gw_full, blk, 0, stream>>>(ob, wbO, out0, BL_TOT, HID, HID);
}

// Round 7
// 341.872 us; speedup vs baseline: 1.3223x; 1.0524x over previous
//
#include <hip/hip_runtime.h>
#include <hip/hip_bf16.h>

#define L_SEQ 4096
#define HID 1024
#define NH 4
#define DH 256
#define CK 64
#define BL_TOT 8192   // B*L

typedef short v8s __attribute__((ext_vector_type(8)));
typedef unsigned short v8u __attribute__((ext_vector_type(8)));
typedef unsigned short v4us __attribute__((ext_vector_type(4)));
typedef float v4f __attribute__((ext_vector_type(4)));

typedef __attribute__((address_space(1))) const void* as1cv;
typedef __attribute__((address_space(3))) void* as3v;

__device__ __forceinline__ unsigned short f2bu(float f) {
    __hip_bfloat16 h = __float2bfloat16(f);
    return *(unsigned short*)&h;
}
__device__ __forceinline__ float bu2f(unsigned short u) {
    __hip_bfloat16 h = *(__hip_bfloat16*)&u;
    return __bfloat162float(h);
}
__device__ __forceinline__ void storec(float* p, float v) { *p = v; }
__device__ __forceinline__ void storec(unsigned short* p, float v) { *p = f2bu(v); }

// ---------------- fused: all-weight f32->bf16 cvt  +  beta/x-bf16 pass ----------------
// blocks [0,1024): weight convert (4 matrices, grid-stride)
// blocks [1024,3072): beta = sigmoid(x @ Wbeta^T) wave-per-row + x -> bf16
__global__ __launch_bounds__(256) void prep_kernel(const float* __restrict__ s0, const float* __restrict__ s1,
                                                   const float* __restrict__ s2, const float* __restrict__ s3,
                                                   unsigned short* __restrict__ d0, unsigned short* __restrict__ d1,
                                                   unsigned short* __restrict__ d2, unsigned short* __restrict__ d3,
                                                   const float* __restrict__ x, const float* __restrict__ Wb,
                                                   float* __restrict__ betaB, unsigned short* __restrict__ xh) {
    const int bid = blockIdx.x;
    const int tid = threadIdx.x;
    if (bid < 1024) {
        const int m = bid >> 8;
        const float* s = m == 0 ? s0 : m == 1 ? s1 : m == 2 ? s2 : s3;
        unsigned short* d = m == 0 ? d0 : m == 1 ? d1 : m == 2 ? d2 : d3;
        int i = (bid & 255) * 256 + tid;
        for (; i < HID * HID; i += 65536) d[i] = f2bu(s[i]);
        return;
    }
    const int t = (bid - 1024) * 4 + (tid >> 6);
    const int lane = tid & 63;
    const float* xr = x + (size_t)t * HID;
    float s[4] = {0.f, 0.f, 0.f, 0.f};
    v4f xv[4];
#pragma unroll
    for (int c = 0; c < 4; ++c) {
        const int i4 = c * 256 + lane * 4;
        xv[c] = *(const v4f*)(xr + i4);
        v4us xp;
#pragma unroll
        for (int i = 0; i < 4; ++i) xp[i] = f2bu(xv[c][i]);
        *(v4us*)&xh[(size_t)t * HID + i4] = xp;
    }
#pragma unroll
    for (int h = 0; h < 4; ++h)
#pragma unroll
        for (int c = 0; c < 4; ++c) {
            v4f wv = *(const v4f*)(Wb + (size_t)h * HID + c * 256 + lane * 4);
            s[h] += xv[c][0] * wv[0] + xv[c][1] * wv[1] + xv[c][2] * wv[2] + xv[c][3] * wv[3];
        }
#pragma unroll
    for (int off = 32; off; off >>= 1)
#pragma unroll
        for (int h = 0; h < 4; ++h) s[h] += __shfl_xor(s[h], off);
    if (lane < 4) betaB[(size_t)t * 4 + lane] = 1.f / (1.f + expf(-s[lane]));
}

// ---------------- MFMA bf16 GEMM: C[M,N] = A[M,K] * B[N,K]^T ----------------
// 128^2 tile, BK=64, global_load_lds width=16, both-sides XOR swizzle (conflict-free).
// 2D grid, m fastest: consecutive blocks share one B-panel (measured-best L2 behavior;
// round-5's A-major XCD chunking doubled FETCH_SIZE -> reverted).
template <typename OT>
__global__ __launch_bounds__(256) void gemm_mfma(const unsigned short* __restrict__ Ah,
                                                 const unsigned short* __restrict__ Bh,
                                                 OT* __restrict__ C, int M, int N, int K) {
    __shared__ unsigned short AsH[128 * 64];
    __shared__ unsigned short BsH[128 * 64];
    const int tid = threadIdx.x;
    const int wave = tid >> 6, lane = tid & 63;
    const int quad = lane >> 4, l16 = lane & 15;
    const int m0 = blockIdx.x * 128, n0 = blockIdx.y * 128;
    const int wm = (wave >> 1) * 64, wn = (wave & 1) * 64;

    // staging: one issue = 256 thr * 16 B = 4 KB = 32 rows * 128 B; 4 issues per 128-row tile
    const int srow = wave * 8 + (lane >> 3);              // 0..31 within issue stripe
    const int scol = (((lane & 7) ^ (lane >> 3)) * 8);    // pre-swizzled source chunk (shorts)
    const unsigned short* Ag = Ah + (size_t)(m0 + srow) * K + scol;
    const unsigned short* Bg = Bh + (size_t)(n0 + srow) * K + scol;
    char* lA = (char*)AsH;
    char* lB = (char*)BsH;
    const int lbase = wave * 1024;

    v4f acc[4][4];
#pragma unroll
    for (int a = 0; a < 4; ++a)
#pragma unroll
        for (int b = 0; b < 4; ++b) { v4f z = {0.f, 0.f, 0.f, 0.f}; acc[a][b] = z; }

    for (int k0 = 0; k0 < K; k0 += 64) {
        __syncthreads();  // previous tile's ds_reads complete
#pragma unroll
        for (int i = 0; i < 4; ++i)
            __builtin_amdgcn_global_load_lds((as1cv)(Ag + (size_t)(i * 32) * K + k0),
                                             (as3v)(lA + i * 4096 + lbase), 16, 0, 0);
#pragma unroll
        for (int i = 0; i < 4; ++i)
            __builtin_amdgcn_global_load_lds((as1cv)(Bg + (size_t)(i * 32) * K + k0),
                                             (as3v)(lB + i * 4096 + lbase), 16, 0, 0);
        __syncthreads();  // drains vmcnt -> LDS tile ready
#pragma unroll
        for (int kk = 0; kk < 2; ++kk) {
            v8s afh[4], bfh[4];
#pragma unroll
            for (int mt = 0; mt < 4; ++mt) {
                const int row = wm + mt * 16 + l16;
                afh[mt] = *(const v8s*)&AsH[row * 64 + (((quad + 4 * kk) ^ (row & 7)) * 8)];
            }
#pragma unroll
            for (int nt = 0; nt < 4; ++nt) {
                const int row = wn + nt * 16 + l16;
                bfh[nt] = *(const v8s*)&BsH[row * 64 + (((quad + 4 * kk) ^ (row & 7)) * 8)];
            }
#pragma unroll
            for (int mt = 0; mt < 4; ++mt)
#pragma unroll
                for (int nt = 0; nt < 4; ++nt)
                    acc[mt][nt] = __builtin_amdgcn_mfma_f32_16x16x32_bf16(afh[mt], bfh[nt], acc[mt][nt], 0, 0, 0);
        }
    }
#pragma unroll
    for (int mt = 0; mt < 4; ++mt)
#pragma unroll
        for (int nt = 0; nt < 4; ++nt) {
            int row = m0 + wm + mt * 16 + quad * 4;
            int col = n0 + wn + nt * 16 + l16;
#pragma unroll
            for (int r = 0; r < 4; ++r)
                storec(&C[(size_t)(row + r) * N + col], acc[mt][nt][r]);
        }
}

// ---------------- fused: final projection GEMM (out0)  +  Spart reduce (out1) ----------------
#define SNS 8
// blocks [0, 512): 128^2 GEMM blocks, m-fastest (bid & 63 = m-tile, bid >> 6 = n-tile)
// blocks [512, 768): reduce SNS partials -> out1 (8 elems/thread)
__global__ __launch_bounds__(256) void final_kernel(const unsigned short* __restrict__ Ah,
                                                    const unsigned short* __restrict__ Bh,
                                                    float* __restrict__ C,
                                                    const float* __restrict__ Spart,
                                                    float* __restrict__ out1) {
    __shared__ unsigned short AsH[128 * 64];
    __shared__ unsigned short BsH[128 * 64];
    const int bid = blockIdx.x;
    const int tid = threadIdx.x;
    if (bid >= 512) {
        const int base = (bid - 512) * 2048 + tid;
#pragma unroll
        for (int k = 0; k < 8; ++k) {
            const int i = base + k * 256;
            float s = 0.f;
#pragma unroll
            for (int ns = 0; ns < SNS; ++ns) s += Spart[(size_t)ns * (8 * 256 * 256) + i];
            out1[i] = s;
        }
        return;
    }
    const int N = HID, K = HID;
    const int wave = tid >> 6, lane = tid & 63;
    const int quad = lane >> 4, l16 = lane & 15;
    const int m0 = (bid & 63) * 128, n0 = (bid >> 6) * 128;
    const int wm = (wave >> 1) * 64, wn = (wave & 1) * 64;
    const int srow = wave * 8 + (lane >> 3);
    const int scol = (((lane & 7) ^ (lane >> 3)) * 8);
    const unsigned short* Ag = Ah + (size_t)(m0 + srow) * K + scol;
    const unsigned short* Bg = Bh + (size_t)(n0 + srow) * K + scol;
    char* lA = (char*)AsH;
    char* lB = (char*)BsH;
    const int lbase = wave * 1024;

    v4f acc[4][4];
#pragma unroll
    for (int a = 0; a < 4; ++a)
#pragma unroll
        for (int b = 0; b < 4; ++b) { v4f z = {0.f, 0.f, 0.f, 0.f}; acc[a][b] = z; }

    for (int k0 = 0; k0 < K; k0 += 64) {
        __syncthreads();
#pragma unroll
        for (int i = 0; i < 4; ++i)
            __builtin_amdgcn_global_load_lds((as1cv)(Ag + (size_t)(i * 32) * K + k0),
                                             (as3v)(lA + i * 4096 + lbase), 16, 0, 0);
#pragma unroll
        for (int i = 0; i < 4; ++i)
            __builtin_amdgcn_global_load_lds((as1cv)(Bg + (size_t)(i * 32) * K + k0),
                                             (as3v)(lB + i * 4096 + lbase), 16, 0, 0);
        __syncthreads();
#pragma unroll
        for (int kk = 0; kk < 2; ++kk) {
            v8s afh[4], bfh[4];
#pragma unroll
            for (int mt = 0; mt < 4; ++mt) {
                const int row = wm + mt * 16 + l16;
                afh[mt] = *(const v8s*)&AsH[row * 64 + (((quad + 4 * kk) ^ (row & 7)) * 8)];
            }
#pragma unroll
            for (int nt = 0; nt < 4; ++nt) {
                const int row = wn + nt * 16 + l16;
                bfh[nt] = *(const v8s*)&BsH[row * 64 + (((quad + 4 * kk) ^ (row & 7)) * 8)];
            }
#pragma unroll
            for (int mt = 0; mt < 4; ++mt)
#pragma unroll
                for (int nt = 0; nt < 4; ++nt)
                    acc[mt][nt] = __builtin_amdgcn_mfma_f32_16x16x32_bf16(afh[mt], bfh[nt], acc[mt][nt], 0, 0, 0);
        }
    }
#pragma unroll
    for (int mt = 0; mt < 4; ++mt)
#pragma unroll
        for (int nt = 0; nt < 4; ++nt) {
            int row = m0 + wm + mt * 16 + quad * 4;
            int col = n0 + wn + nt * 16 + l16;
#pragma unroll
            for (int r = 0; r < 4; ++r)
                C[(size_t)(row + r) * N + col] = acc[mt][nt][r];
        }
}

// ---------------- causal depthwise conv (KS=4) + silu + silu (+ per-head l2norm) ----------------
// 4 rows per block: 7 tap-rows loaded for 4 outputs (tap reuse in registers).
// Thread owns 4 contiguous channels of head (tid>>6); l2norm = wave shuffle per row.
// path p: 0=V (bf16 out, no norm), 1=K (hi/lo out, norm), 2=Q (bf16 out, norm).
__global__ __launch_bounds__(256) void conv_kernel(const unsigned short* __restrict__ G, int gstride, int pathArg,
                                                   const float* __restrict__ wq, const float* __restrict__ wk,
                                                   const float* __restrict__ wv,
                                                   unsigned short* __restrict__ Vout,
                                                   unsigned short* __restrict__ KhiO, unsigned short* __restrict__ KloO,
                                                   unsigned short* __restrict__ Qout) {
    const int p = pathArg < 0 ? (int)blockIdx.y : pathArg;
    const int yoff = pathArg < 0 ? p * 1024 : 0;
    const float* __restrict__ w = p == 0 ? wv : p == 1 ? wk : wq;
    const int bl0 = blockIdx.x * 4;           // 4 consecutive rows; never straddles a sequence (4096%4==0)
    const int l0 = bl0 & (L_SEQ - 1);
    const int tid = threadIdx.x;
    const int lane = tid & 63;
    const int c4 = (tid >> 6) * 256 + lane * 4;  // 4 contiguous channels in head (tid>>6)
    v4f wrow[4];
#pragma unroll
    for (int cc = 0; cc < 4; ++cc) wrow[cc] = *(const v4f*)&w[(c4 + cc) * 4];
    v4f g[7];
#pragma unroll
    for (int t = 0; t < 7; ++t) {
        v4f gv = {0.f, 0.f, 0.f, 0.f};
        if (l0 - 3 + t >= 0) {
            v4us gu = *(const v4us*)&G[(size_t)(bl0 - 3 + t) * gstride + yoff + c4];
#pragma unroll
            for (int i = 0; i < 4; ++i) gv[i] = bu2f(gu[i]);
        }
        g[t] = gv;
    }
#pragma unroll
    for (int r = 0; r < 4; ++r) {
        float vals[4];
#pragma unroll
        for (int cc = 0; cc < 4; ++cc) {
            float a = g[r][cc] * wrow[cc][0] + g[r + 1][cc] * wrow[cc][1] +
                      g[r + 2][cc] * wrow[cc][2] + g[r + 3][cc] * wrow[cc][3];
            float s1 = a / (1.f + expf(-a));
            vals[cc] = s1 / (1.f + expf(-s1));
        }
        if (p >= 1) {
            float sq = vals[0] * vals[0] + vals[1] * vals[1] + vals[2] * vals[2] + vals[3] * vals[3];
#pragma unroll
            for (int off = 32; off; off >>= 1) sq += __shfl_xor(sq, off);
            float nrm = 1.f / fmaxf(sqrtf(sq), 1e-12f);
#pragma unroll
            for (int cc = 0; cc < 4; ++cc) vals[cc] *= nrm;
        }
        const size_t ob = (size_t)(bl0 + r) * HID + c4;
        if (p == 1) {
            v4us hv, lv;
#pragma unroll
            for (int cc = 0; cc < 4; ++cc) {
                unsigned short h = f2bu(vals[cc]);
                hv[cc] = h;
                lv[cc] = f2bu(vals[cc] - bu2f(h));
            }
            *(v4us*)&KhiO[ob] = hv;
            *(v4us*)&KloO[ob] = lv;
        } else {
            unsigned short* O = p == 0 ? Vout : Qout;
            v4us hv;
#pragma unroll
            for (int cc = 0; cc < 4; ++cc) hv[cc] = f2bu(vals[cc]);
            *(v4us*)&O[ob] = hv;
        }
    }
}

// ---------------- per-chunk per-head gram: G_h = K_h * K_h^T (split-bf16 MFMA) ----------------
__global__ __launch_bounds__(256) void gram_kernel(const unsigned short* __restrict__ Khi,
                                                   const unsigned short* __restrict__ Klo,
                                                   float* __restrict__ Gg) {
    const int chunk = blockIdx.x;
    const int h = blockIdx.y;
    const int tid = threadIdx.x;
    const int wave = tid >> 6, lane = tid & 63;
    const int quad = lane >> 4, l16 = lane & 15;
    __shared__ unsigned short Hs[64 * 264];
    __shared__ unsigned short Ls[64 * 264];
    const int l0 = chunk * 64;
    const int cb = h * 256;
#pragma unroll
    for (int p = 0; p < 8; ++p) {
        int row = p * 8 + (tid >> 5);
        int col = (tid & 31) * 8;
        v8u hv = *(const v8u*)(Khi + (size_t)(l0 + row) * HID + cb + col);
        v8u lv = *(const v8u*)(Klo + (size_t)(l0 + row) * HID + cb + col);
        *(v8u*)&Hs[row * 264 + col] = hv;
        *(v8u*)&Ls[row * 264 + col] = lv;
    }
    __syncthreads();
    const int wm = wave * 16;
    v4f acc[4];
#pragma unroll
    for (int nt = 0; nt < 4; ++nt) { v4f z = {0.f, 0.f, 0.f, 0.f}; acc[nt] = z; }
#pragma unroll
    for (int ks = 0; ks < 8; ++ks) {
        v8s ah = *(const v8s*)&Hs[(wm + l16) * 264 + ks * 32 + quad * 8];
        v8s al = *(const v8s*)&Ls[(wm + l16) * 264 + ks * 32 + quad * 8];
#pragma unroll
        for (int nt = 0; nt < 4; ++nt) {
            v8s bh = *(const v8s*)&Hs[(nt * 16 + l16) * 264 + ks * 32 + quad * 8];
            v8s bl = *(const v8s*)&Ls[(nt * 16 + l16) * 264 + ks * 32 + quad * 8];
            acc[nt] = __builtin_amdgcn_mfma_f32_16x16x32_bf16(ah, bh, acc[nt], 0, 0, 0);
            acc[nt] = __builtin_amdgcn_mfma_f32_16x16x32_bf16(ah, bl, acc[nt], 0, 0, 0);
            acc[nt] = __builtin_amdgcn_mfma_f32_16x16x32_bf16(al, bh, acc[nt], 0, 0, 0);
        }
    }
    float* og = Gg + ((size_t)chunk * 4 + h) * 4096;
#pragma unroll
    for (int nt = 0; nt < 4; ++nt)
#pragma unroll
        for (int r = 0; r < 4; ++r)
            og[(wm + quad * 4 + r) * 64 + nt * 16 + l16] = acc[nt][r];
}

// ---------------- T recurrence per chunk via nilpotent doubling + MFMA ----------------
// T_final = 3*(I-A)^{-1} - 2I, A = -tril(beta*gram, -1); (I-A)^{-1} = prod (I + A^(2^k)).
__global__ __launch_bounds__(256) void trec_kernel(const float* __restrict__ Gg,
                                                   const float* __restrict__ betaB,
                                                   float* __restrict__ Tg) {
    const int chunk = blockIdx.x;
    const int tid = threadIdx.x;
    const int wave = tid >> 6, lane = tid & 63;
    const int quad = lane >> 4, l16 = lane & 15;
    const int wm = wave * 16;
    __shared__ unsigned short BhR[64 * 72], BlR[64 * 72];  // B rows   [i][j]
    __shared__ unsigned short BhT[64 * 72], BlT[64 * 72];  // B^T rows [j][i]
    __shared__ unsigned short PhR[64 * 72], PlR[64 * 72];  // P rows   [i][j]
    __shared__ float Pf[64 * 73];                          // P master copy (f32)
    __shared__ float betS[256];
    betS[tid] = betaB[(size_t)chunk * 256 + tid];
    __syncthreads();
    const float* gg = Gg + (size_t)chunk * 4 * 4096;
#pragma unroll
    for (int s = 0; s < 16; ++s) {
        int idx = tid + 256 * s;
        int i = idx >> 6, j = idx & 63;
        float a = 0.f;
        if (i > j) {
            a = -(betS[i * 4 + 0] * gg[idx] + betS[i * 4 + 1] * gg[4096 + idx] +
                  betS[i * 4 + 2] * gg[2 * 4096 + idx] + betS[i * 4 + 3] * gg[3 * 4096 + idx]);
        }
        unsigned short ah = f2bu(a);
        unsigned short al = f2bu(a - bu2f(ah));
        BhR[i * 72 + j] = ah;
        BlR[i * 72 + j] = al;
        BhT[j * 72 + i] = ah;
        BlT[j * 72 + i] = al;
        float p = (i == j) ? 1.f : 0.f;
        Pf[i * 73 + j] = p;
        PhR[i * 72 + j] = f2bu(p);
        PlR[i * 72 + j] = 0;
    }
    __syncthreads();

    for (int st = 0; st < 6; ++st) {
        v8s aBh[2], aBl[2], aPh[2], aPl[2];
        v8s bTh[2][4], bTl[2][4];
#pragma unroll
        for (int kk = 0; kk < 2; ++kk) {
            aBh[kk] = *(const v8s*)&BhR[(wm + l16) * 72 + kk * 32 + quad * 8];
            aBl[kk] = *(const v8s*)&BlR[(wm + l16) * 72 + kk * 32 + quad * 8];
            aPh[kk] = *(const v8s*)&PhR[(wm + l16) * 72 + kk * 32 + quad * 8];
            aPl[kk] = *(const v8s*)&PlR[(wm + l16) * 72 + kk * 32 + quad * 8];
#pragma unroll
            for (int nt = 0; nt < 4; ++nt) {
                bTh[kk][nt] = *(const v8s*)&BhT[(nt * 16 + l16) * 72 + kk * 32 + quad * 8];
                bTl[kk][nt] = *(const v8s*)&BlT[(nt * 16 + l16) * 72 + kk * 32 + quad * 8];
            }
        }
        v4f accP[4], accB[4];
#pragma unroll
        for (int nt = 0; nt < 4; ++nt) {
#pragma unroll
            for (int r = 0; r < 4; ++r)
                accP[nt][r] = Pf[(wm + quad * 4 + r) * 73 + nt * 16 + l16];
            v4f z = {0.f, 0.f, 0.f, 0.f};
            accB[nt] = z;
        }
        __syncthreads();  // all reads done before anyone writes
#pragma unroll
        for (int kk = 0; kk < 2; ++kk)
#pragma unroll
            for (int nt = 0; nt < 4; ++nt) {
                accP[nt] = __builtin_amdgcn_mfma_f32_16x16x32_bf16(aPh[kk], bTh[kk][nt], accP[nt], 0, 0, 0);
                accP[nt] = __builtin_amdgcn_mfma_f32_16x16x32_bf16(aPh[kk], bTl[kk][nt], accP[nt], 0, 0, 0);
                accP[nt] = __builtin_amdgcn_mfma_f32_16x16x32_bf16(aPl[kk], bTh[kk][nt], accP[nt], 0, 0, 0);
            }
        if (st < 5) {
#pragma unroll
            for (int kk = 0; kk < 2; ++kk)
#pragma unroll
                for (int nt = 0; nt < 4; ++nt) {
                    accB[nt] = __builtin_amdgcn_mfma_f32_16x16x32_bf16(aBh[kk], bTh[kk][nt], accB[nt], 0, 0, 0);
                    accB[nt] = __builtin_amdgcn_mfma_f32_16x16x32_bf16(aBh[kk], bTl[kk][nt], accB[nt], 0, 0, 0);
                    accB[nt] = __builtin_amdgcn_mfma_f32_16x16x32_bf16(aBl[kk], bTh[kk][nt], accB[nt], 0, 0, 0);
                }
        }
#pragma unroll
        for (int nt = 0; nt < 4; ++nt)
#pragma unroll
            for (int r = 0; r < 4; ++r) {
                int row = wm + quad * 4 + r;
                int col = nt * 16 + l16;
                float pv = accP[nt][r];
                Pf[row * 73 + col] = pv;
                unsigned short ph = f2bu(pv);
                PhR[row * 72 + col] = ph;
                PlR[row * 72 + col] = f2bu(pv - bu2f(ph));
                if (st < 5) {
                    float bv = accB[nt][r];
                    unsigned short bh2 = f2bu(bv);
                    unsigned short bl2 = f2bu(bv - bu2f(bh2));
                    BhR[row * 72 + col] = bh2;
                    BlR[row * 72 + col] = bl2;
                    BhT[col * 72 + row] = bh2;
                    BlT[col * 72 + row] = bl2;
                }
            }
        __syncthreads();
    }
#pragma unroll
    for (int s = 0; s < 16; ++s) {
        int idx = tid + 256 * s;
        int i = idx >> 6, j = idx & 63;
        float t = (i == j) ? 1.f : 3.f * Pf[i * 73 + j];
        Tg[(size_t)chunk * 4096 + idx] = t;
    }
}

// ---------------- W = T'·K, U = T'·V via MFMA (T' = T·diag(beta)); fused kw/ku ----------------
__global__ __launch_bounds__(256) void wu_mfma_kernel(const float* __restrict__ Tg,
                                                      const unsigned short* __restrict__ Khi,
                                                      const unsigned short* __restrict__ Vhi,
                                                      const float* __restrict__ betaB,
                                                      unsigned short* __restrict__ Wb,
                                                      unsigned short* __restrict__ Ub,
                                                      float* __restrict__ kw, float* __restrict__ ku) {
    const int chunk = blockIdx.x;  // 128
    const int h = blockIdx.y;      // 4
    const int half = blockIdx.z;   // 2
    const int tid = threadIdx.x;
    const int wave = tid >> 6, lane = tid & 63;
    const int quad = lane >> 4, l16 = lane & 15;
    const size_t l0 = (size_t)chunk * 64;
    const int f0 = h * 256 + half * 128;
    __shared__ unsigned short Th[64 * 72], Tl[64 * 72];
    __shared__ unsigned short KT[128 * 72], VT[128 * 72];
    __shared__ float betS[64];
    if (tid < 64) betS[tid] = betaB[(l0 + tid) * 4 + h];
    __syncthreads();
#pragma unroll
    for (int s = 0; s < 16; ++s) {
        int idx = tid + 256 * s;
        int c = idx >> 6, j = idx & 63;
        float v = Tg[(size_t)chunk * 4096 + idx] * betS[j];
        unsigned short hv = f2bu(v);
        Th[c * 72 + j] = hv;
        Tl[c * 72 + j] = f2bu(v - bu2f(hv));
    }
#pragma unroll
    for (int pass = 0; pass < 4; ++pass) {
        int j = pass * 16 + (tid >> 4);
        int fc = (tid & 15) * 8;
        v8u kv = *(const v8u*)(Khi + (l0 + j) * HID + f0 + fc);
        v8u vv = *(const v8u*)(Vhi + (l0 + j) * HID + f0 + fc);
#pragma unroll
        for (int i = 0; i < 8; ++i) {
            KT[(fc + i) * 72 + j] = kv[i];
            VT[(fc + i) * 72 + j] = vv[i];
        }
    }
    __syncthreads();

    const int nf = wave * 32;
    const int bb = chunk >> 6, nn = chunk & 63;
    const size_t obase = (((size_t)bb * 4 + h) * 64 + nn) * 256 + half * 128;

#pragma unroll
    for (int phase = 0; phase < 2; ++phase) {
        const unsigned short* BT = phase ? VT : KT;
        v4f acc[4][2];
#pragma unroll
        for (int mt = 0; mt < 4; ++mt)
#pragma unroll
            for (int nt = 0; nt < 2; ++nt) { v4f z = {0.f, 0.f, 0.f, 0.f}; acc[mt][nt] = z; }
#pragma unroll
        for (int k0 = 0; k0 < 64; k0 += 32) {
            v8s ah[4], al[4], bf[2];
#pragma unroll
            for (int mt = 0; mt < 4; ++mt) {
                ah[mt] = *(const v8s*)&Th[(mt * 16 + l16) * 72 + k0 + quad * 8];
                al[mt] = *(const v8s*)&Tl[(mt * 16 + l16) * 72 + k0 + quad * 8];
            }
#pragma unroll
            for (int nt = 0; nt < 2; ++nt)
                bf[nt] = *(const v8s*)&BT[(nf + nt * 16 + l16) * 72 + k0 + quad * 8];
#pragma unroll
            for (int mt = 0; mt < 4; ++mt)
#pragma unroll
                for (int nt = 0; nt < 2; ++nt) {
                    acc[mt][nt] = __builtin_amdgcn_mfma_f32_16x16x32_bf16(ah[mt], bf[nt], acc[mt][nt], 0, 0, 0);
                    acc[mt][nt] = __builtin_amdgcn_mfma_f32_16x16x32_bf16(al[mt], bf[nt], acc[mt][nt], 0, 0, 0);
                }
        }
        unsigned short* Out = phase ? Ub : Wb;
        float* kk = phase ? ku : kw;
#pragma unroll
        for (int nt = 0; nt < 2; ++nt) {
            const int fl = nf + nt * 16 + l16;
            float dot = 0.f;
#pragma unroll
            for (int mt = 0; mt < 4; ++mt)
#pragma unroll
                for (int r = 0; r < 4; ++r) {
                    const int c = mt * 16 + quad * 4 + r;
                    float wv = acc[mt][nt][r];
                    Out[(l0 + c) * HID + f0 + fl] = f2bu(wv);
                    dot += bu2f(KT[fl * 72 + c]) * wv;
                }
            dot += __shfl_xor(dot, 16);
            dot += __shfl_xor(dot, 32);
            if (quad == 0) kk[obase + fl] = dot;
        }
    }
}

// ---------------- diagonal scan over chunks (load-pipelined serial loop) ----------------
__global__ __launch_bounds__(256) void scan_kernel(const float* __restrict__ kw,
                                                   const float* __restrict__ ku,
                                                   float* __restrict__ dsA) {
    const int bh = blockIdx.x;
    size_t idx = (size_t)bh * 64 * 256 + threadIdx.x;
    float ds = 0.f;
    float kwc = kw[idx], kuc = ku[idx];
    for (int n = 0; n < 64; ++n) {
        float kwn = 0.f, kun = 0.f;
        if (n < 63) {  // prefetch next chunk's coeffs off the dependent chain
            kwn = kw[idx + 256];
            kun = ku[idx + 256];
        }
        dsA[idx] = ds;
        ds = ds * (1.f - kwc) + kuc;
        kwc = kwn;
        kuc = kun;
        idx += 256;
    }
}

// ---------------- o = q*ds + [c<=b]*A*(u - w*ds); fused RMSNorm + bf16 cast (wave-per-row) ----------------
__global__ __launch_bounds__(256) void o_kernel(const unsigned short* __restrict__ Qb,
                                                const unsigned short* __restrict__ Khi,
                                                const unsigned short* __restrict__ Wb,
                                                const unsigned short* __restrict__ Ub,
                                                const float* __restrict__ dsA,
                                                const float* __restrict__ rmsw,
                                                unsigned short* __restrict__ ob,
                                                unsigned short* __restrict__ ub) {
    const int r = blockIdx.x * 4 + (threadIdx.x >> 6);
    const int lane = threadIdx.x & 63;
    const int b = r >> 12, l = r & (L_SEQ - 1);
    const int n = l >> 6, cpos = l & 63;
    const size_t rowb = (size_t)r * HID;
    const bool doA = (cpos <= b);
    float qv[4][4];
    v4f dsv[4];
    float As = 0.f;
#pragma unroll
    for (int hh = 0; hh < 4; ++hh) {
        const int c4 = hh * 256 + lane * 4;
        dsv[hh] = *(const v4f*)&dsA[(((size_t)b * 4 + hh) * 64 + n) * 256 + lane * 4];
        v4us qu = *(const v4us*)&Qb[rowb + c4];
#pragma unroll
        for (int i = 0; i < 4; ++i) qv[hh][i] = bu2f(qu[i]);
        if (doA) {
            v4us kq = *(const v4us*)&Khi[rowb + c4];
#pragma unroll
            for (int i = 0; i < 4; ++i) As += qv[hh][i] * bu2f(kq[i]);
        }
    }
    float Aval = 0.f;
    if (doA) {
#pragma unroll
        for (int off = 32; off; off >>= 1) As += __shfl_xor(As, off);
        Aval = As;
    }
    float ss = 0.f;
    float ov[4][4];
#pragma unroll
    for (int hh = 0; hh < 4; ++hh) {
        const int c4 = hh * 256 + lane * 4;
        v4us uu = *(const v4us*)&Ub[rowb + c4];
        v4us wu4 = *(const v4us*)&Wb[rowb + c4];
        v4us up;
#pragma unroll
        for (int i = 0; i < 4; ++i) {
            float u = bu2f(uu[i]) - bu2f(wu4[i]) * dsv[hh][i];
            up[i] = f2bu(u);
            float o = qv[hh][i] * dsv[hh][i];
            if (doA) o += Aval * u;
            ov[hh][i] = o;
            ss += o * o;
        }
        *(v4us*)&ub[rowb + c4] = up;
    }
#pragma unroll
    for (int off = 32; off; off >>= 1) ss += __shfl_xor(ss, off);
    float scale = rsqrtf(ss * (1.f / 1024.f) + 1e-5f);
#pragma unroll
    for (int hh = 0; hh < 4; ++hh) {
        const int c4 = hh * 256 + lane * 4;
        v4f rw = *(const v4f*)&rmsw[c4];
        v4us op;
#pragma unroll
        for (int i = 0; i < 4; ++i) op[i] = f2bu(ov[hh][i] * scale * rw[i]);
        *(v4us*)&ob[rowb + c4] = op;
    }
}

// ---------------- state S = K^T u'  via MFMA (n-split partials) ----------------
__global__ __launch_bounds__(256) void s_mfma_kernel(const unsigned short* __restrict__ Khi,
                                                     const unsigned short* __restrict__ Ub,
                                                     float* __restrict__ Spart) {
    const int bh = blockIdx.x;
    const int b = bh >> 2, h = bh & 3;
    const int dt = blockIdx.y;
    const int et = blockIdx.z & 1;
    const int ns = blockIdx.z >> 1;
    const int tid = threadIdx.x;
    const int wave = tid >> 6, lane = tid & 63;
    const int quad = lane >> 4, l16 = lane & 15;
    const int wm = (wave >> 1) * 64, wn = (wave & 1) * 64;
    __shared__ unsigned short Kt[128 * 40];
    __shared__ unsigned short Ut[128 * 40];
    const int cc = tid >> 3;
    const int dcol = (tid & 7) * 16;
    const size_t rowbase = (size_t)b * 4096 + (size_t)ns * 512;
    const int ck = h * 256 + dt * 128;
    const int ce = h * 256 + et * 128;
    v4f acc[4][4];
#pragma unroll
    for (int a = 0; a < 4; ++a)
#pragma unroll
        for (int c2 = 0; c2 < 4; ++c2) { v4f z = {0.f, 0.f, 0.f, 0.f}; acc[a][c2] = z; }

    for (int kt = 0; kt < 16; ++kt) {
        size_t row = rowbase + kt * 32 + cc;
        v8u k0 = *(const v8u*)(Khi + row * HID + ck + dcol);
        v8u k1 = *(const v8u*)(Khi + row * HID + ck + dcol + 8);
        v8u u0 = *(const v8u*)(Ub + row * HID + ce + dcol);
        v8u u1 = *(const v8u*)(Ub + row * HID + ce + dcol + 8);
        __syncthreads();
#pragma unroll
        for (int j = 0; j < 8; ++j) {
            Kt[(dcol + j) * 40 + cc] = k0[j];
            Kt[(dcol + 8 + j) * 40 + cc] = k1[j];
            Ut[(dcol + j) * 40 + cc] = u0[j];
            Ut[(dcol + 8 + j) * 40 + cc] = u1[j];
        }
        __syncthreads();
        v8s af[4], bf[4];
#pragma unroll
        for (int mt = 0; mt < 4; ++mt) af[mt] = *(const v8s*)&Kt[(wm + mt * 16 + l16) * 40 + quad * 8];
#pragma unroll
        for (int nt = 0; nt < 4; ++nt) bf[nt] = *(const v8s*)&Ut[(wn + nt * 16 + l16) * 40 + quad * 8];
#pragma unroll
        for (int mt = 0; mt < 4; ++mt)
#pragma unroll
            for (int nt = 0; nt < 4; ++nt)
                acc[mt][nt] = __builtin_amdgcn_mfma_f32_16x16x32_bf16(af[mt], bf[nt], acc[mt][nt], 0, 0, 0);
    }
    float* out = Spart + (size_t)ns * (8 * 256 * 256);
#pragma unroll
    for (int mt = 0; mt < 4; ++mt)
#pragma unroll
        for (int nt = 0; nt < 4; ++nt) {
            int row = dt * 128 + wm + mt * 16 + quad * 4;
            int col = et * 128 + wn + nt * 16 + l16;
#pragma unroll
            for (int r = 0; r < 4; ++r)
                out[((size_t)bh * 256 + row + r) * 256 + col] = acc[mt][nt][r];
        }
}

extern "C" void kernel_launch(void* const* d_in, const int* in_sizes, int n_in,
                              void* d_out, int out_size, void* d_ws, size_t ws_size,
                              hipStream_t stream) {
    const float* x     = (const float*)d_in[0];
    const float* Wq    = (const float*)d_in[1];
    const float* Wk    = (const float*)d_in[2];
    const float* Wv    = (const float*)d_in[3];
    const float* convq = (const float*)d_in[4];
    const float* convk = (const float*)d_in[5];
    const float* convv = (const float*)d_in[6];
    const float* Wbeta = (const float*)d_in[7];
    const float* rmsw  = (const float*)d_in[8];
    const float* Wo    = (const float*)d_in[9];

    // ---- workspace map (aliases documented) ----
    char* ws = (char*)d_ws;
    size_t off = 0;
    auto alloc = [&](size_t bytes) {
        char* p = ws + off;
        off += (bytes + 255) & ~(size_t)255;
        return (void*)p;
    };
    const size_t MM = (size_t)HID * HID;
    unsigned short* xhi   = (unsigned short*)alloc((size_t)BL_TOT * HID * 2);  // later Qm/ob
    unsigned short* Khi   = (unsigned short*)alloc((size_t)BL_TOT * HID * 2);  // conv_k -> s_mfma
    unsigned short* wbQKV = (unsigned short*)alloc(3 * MM * 2);                // [V|K|Q] packed
    unsigned short* wbO   = (unsigned short*)alloc(MM * 2);
    unsigned short* Vhi   = (unsigned short*)alloc((size_t)BL_TOT * HID * 2);
    unsigned short* Wb16  = (unsigned short*)alloc((size_t)BL_TOT * HID * 2);
    unsigned short* Ub16  = (unsigned short*)alloc((size_t)BL_TOT * HID * 2);
    float* Tg    = (float*)alloc((size_t)128 * 4096 * 4);
    float* betaB = (float*)alloc((size_t)BL_TOT * 4 * 4);
    float* kwB   = (float*)alloc((size_t)8 * 64 * 256 * 4);
    float* kuB   = (float*)alloc((size_t)8 * 64 * 256 * 4);
    float* dsA   = (float*)alloc((size_t)8 * 64 * 256 * 4);
    // Gt last: bf16 GEMM output. big = 8192x3072 (merged QKV) if workspace allows.
    const size_t gt_big = (size_t)BL_TOT * 3 * HID * 2;
    const size_t gt_small = (size_t)BL_TOT * HID * 2;
    // Spart (16 MB f32) aliases Gt; ensure allocation covers it in either path.
    const size_t spart_bytes = (size_t)SNS * 8 * 256 * 256 * 4;
    const bool big = (off + (gt_big > spart_bytes ? gt_big : spart_bytes)) <= ws_size;
    unsigned short* Gt = (unsigned short*)alloc(big ? (gt_big > spart_bytes ? gt_big : spart_bytes)
                                                    : (gt_small > spart_bytes ? gt_small : spart_bytes));

    unsigned short* Qm = xhi;   // xhi dead after (last) x-GEMM
    unsigned short* ob = Qm;    // q dead after o_kernel reads its own row
    float* Spart = (float*)Gt;  // Gt dead after conv

    float* out0 = (float*)d_out;
    float* out1 = out0 + (size_t)BL_TOT * HID;
    // d_out as pre-final scratch (validated only after launch):
    unsigned short* Klo = (unsigned short*)out0;            // bytes 0..16.78M
    unsigned short* ubf = (unsigned short*)out0 + 8388608;  // bytes 16.78M..33.55M
    float* Gg = out0 + (size_t)4400000;                     // gram scratch; dead before o_kernel

    dim3 blk(256);
    dim3 ggrid(BL_TOT / 128, HID / 128);

    // fused weight-cvt + beta (blocks [0,1024) = wcvt, [1024,3072) = beta)
    prep_kernel<<<3072, blk, 0, stream>>>(Wv, Wk, Wq, Wo, wbQKV, wbQKV + MM, wbQKV + 2 * MM, wbO,
                                          x, Wbeta, betaB, xhi);

    if (big) {
        // one QKV GEMM (N=3072, bf16 out) + one merged conv dispatch
        gemm_mfma<unsigned short><<<dim3(BL_TOT / 128, 3 * HID / 128), blk, 0, stream>>>(
            xhi, wbQKV, Gt, BL_TOT, 3 * HID, HID);
        conv_kernel<<<dim3(BL_TOT / 4, 3), blk, 0, stream>>>(Gt, 3 * HID, -1, convq, convk, convv,
                                                             Vhi, Khi, Klo, Qm);
        gram_kernel<<<dim3(128, 4), blk, 0, stream>>>(Khi, Klo, Gg);
        trec_kernel<<<128, blk, 0, stream>>>(Gg, betaB, Tg);
    } else {
        // sequential fallback (Gt reused; Q GEMM last so Qm alias of xhi stays safe)
        gemm_mfma<unsigned short><<<ggrid, blk, 0, stream>>>(xhi, wbQKV, Gt, BL_TOT, HID, HID);
        conv_kernel<<<dim3(BL_TOT / 4, 1), blk, 0, stream>>>(Gt, HID, 0, convq, convk, convv, Vhi, Khi, Klo, Qm);
        gemm_mfma<unsigned short><<<ggrid, blk, 0, stream>>>(xhi, wbQKV + MM, Gt, BL_TOT, HID, HID);
        conv_kernel<<<dim3(BL_TOT / 4, 1), blk, 0, stream>>>(Gt, HID, 1, convq, convk, convv, Vhi, Khi, Klo, Qm);
        gram_kernel<<<dim3(128, 4), blk, 0, stream>>>(Khi, Klo, Gg);
        trec_kernel<<<128, blk, 0, stream>>>(Gg, betaB, Tg);
        gemm_mfma<unsigned short><<<ggrid, blk, 0, stream>>>(xhi, wbQKV + 2 * MM, Gt, BL_TOT, HID, HID);
        conv_kernel<<<dim3(BL_TOT / 4, 1), blk, 0, stream>>>(Gt, HID, 2, convq, convk, convv, Vhi, Khi, Klo, Qm);
    }

    // chunked delta rule
    wu_mfma_kernel<<<dim3(128, 4, 2), blk, 0, stream>>>(Tg, Khi, Vhi, betaB, Wb16, Ub16, kwB, kuB);
    scan_kernel<<<8, blk, 0, stream>>>(kwB, kuB, dsA);
    o_kernel<<<BL_TOT / 4, blk, 0, stream>>>(Qm, Khi, Wb16, Ub16, dsA, rmsw, ob, ubf);
    s_mfma_kernel<<<dim3(8, 2, 2 * SNS), blk, 0, stream>>>(Khi, ubf, Spart);

    // fused final projection (blocks [0,512)) + Spart reduce -> out1 (blocks [512,768))
    final_kernel<<<768, blk, 0, stream>>>(ob, wbO, out0, Spart, out1);
}